// Round 9
// baseline (332.987 us; speedup 1.0000x reference)
//
#include <hip/hip_runtime.h>

typedef __bf16 bf16x8 __attribute__((ext_vector_type(8)));
typedef float f32x4 __attribute__((ext_vector_type(4)));
using u16 = unsigned short;

#define SCALE 0.17677669529663689f  // 32^-0.5

// Direct HBM->LDS DMA, 16B per lane (dest linear: base + lane*16).
#define GLOAD16(lp, gp)                                                        \
    __builtin_amdgcn_global_load_lds(                                          \
        (const __attribute__((address_space(1))) void*)(gp),                   \
        (__attribute__((address_space(3))) void*)(lp), 16, 0, 0)

__device__ __forceinline__ u16 f2bf(float f) {
    union { float f; unsigned u; } x; x.f = f;
    unsigned r = x.u + 0x7fffu + ((x.u >> 16) & 1u);
    return (u16)(r >> 16);
}
__device__ __forceinline__ unsigned pk2(float a, float b) {
    return (unsigned)f2bf(a) | ((unsigned)f2bf(b) << 16);
}
__device__ __forceinline__ float bf2f(u16 h) {
    union { unsigned u; float f; } x; x.u = ((unsigned)h) << 16; return x.f;
}
__device__ __forceinline__ float gelu_t(float x) {
    float u = 0.7978845608028654f * (x + 0.044715f * x * x * x);
    float e = __expf(2.f * u);
    float th = 1.f - 2.f / (e + 1.f);          // tanh(u), overflow-safe
    return 0.5f * x * (1.f + th);
}

// ---------------------------------------------------------------- prep ------
// qwt/kvwt/pwt: Wt[N][K] bf16 (for gemm_k). f1p/f2p: fragment-packed bf16
// (frag (ng,ks): lane l holds W[k=32ks+8(l>>4)+e][n=16ng+(l&15)]).
// biasF: rel-pos bias in swapped C-frag layout.
__global__ __launch_bounds__(256) void prep_k(
    const float* __restrict__ q_w, const float* __restrict__ kv_w,
    const float* __restrict__ p_w, const float* __restrict__ f1w,
    const float* __restrict__ f2w, const float* __restrict__ rel,
    u16* __restrict__ qwt, u16* __restrict__ kvwt, u16* __restrict__ pwt,
    u16* __restrict__ f1p, u16* __restrict__ f2p, float* __restrict__ biasF)
{
    int t = blockIdx.x * 256 + threadIdx.x;
    if (t < 65536) {                                   // q_w  256x256
        int k = t & 255, n = t >> 8;
        qwt[t] = f2bf(q_w[k * 256 + n]);
    } else if (t < 196608) {                           // kv_w 256x512
        int u = t - 65536; int k = u & 255, n = u >> 8;
        kvwt[u] = f2bf(kv_w[k * 512 + n]);
    } else if (t < 262144) {                           // proj_w 256x256
        int u = t - 196608; int k = u & 255, n = u >> 8;
        pwt[u] = f2bf(p_w[k * 256 + n]);
    } else if (t < 524288) {                           // f1p packed frags
        int u = t - 262144;
        int e = u & 7, l = (u >> 3) & 63, ks = (u >> 9) & 7, ng = u >> 12;
        int k = ks * 32 + (l >> 4) * 8 + e;
        int n = ng * 16 + (l & 15);
        f1p[u] = f2bf(f1w[k * 1024 + n]);
    } else if (t < 786432) {                           // f2p packed frags
        int u = t - 524288;
        int e = u & 7, l = (u >> 3) & 63, ks = (u >> 9) & 31, ng = u >> 14;
        int k = ks * 32 + (l >> 4) * 8 + e;
        int n = ng * 16 + (l & 15);
        f2p[u] = f2bf(f2w[k * 256 + n]);
    } else if (t < 819200) {                           // biasF 8*16*64*4
        int u = t - 786432;
        int r = u & 3, l = (u >> 2) & 63, fr = (u >> 8) & 15, h = u >> 12;
        int fi = fr >> 2, fj = fr & 3;
        int m = fi * 16 + (l & 15);
        int n = fj * 16 + 4 * (l >> 4) + r;
        int idx = ((m >> 3) - (n >> 3) + 7) * 15 + ((m & 7) - (n & 7) + 7);
        biasF[u] = rel[idx * 8 + h];
    }
}

// ----------------------------------------------------------- layernorm ------
// One wave per 256-elem row; two streams + window-partition permute.
__global__ __launch_bounds__(256) void ln_k(
    const float* __restrict__ xa, const float* __restrict__ xb,
    const float* __restrict__ gw, const float* __restrict__ bw,
    u16* __restrict__ oa, u16* __restrict__ ob)
{
    int lane = threadIdx.x & 63, wid = threadIdx.x >> 6;
    int r = blockIdx.x * 4 + wid;
    const float* src; u16* dst; int row;
    if (r < 65536) { src = xa; dst = oa; row = r; }
    else           { src = xb; dst = ob; row = r - 65536; }

    float4 v = *(const float4*)(src + (size_t)row * 256 + lane * 4);
    float s = v.x + v.y + v.z + v.w;
    float q = v.x * v.x + v.y * v.y + v.z * v.z + v.w * v.w;
    #pragma unroll
    for (int m = 1; m < 64; m <<= 1) {
        s += __shfl_xor(s, m, 64);
        q += __shfl_xor(q, m, 64);
    }
    float mean = s * (1.0f / 256.0f);
    float var  = q * (1.0f / 256.0f) - mean * mean;
    float rstd = rsqrtf(var + 1e-5f);
    float4 gg = *(const float4*)(gw + lane * 4);
    float4 bb = *(const float4*)(bw + lane * 4);

    int b_ = row >> 12, l = row & 4095;
    int hh = l >> 6, ww = l & 63;
    int wi = (hh >> 3) * 8 + (ww >> 3);
    int n  = (hh & 7) * 8 + (ww & 7);
    int orow = b_ * 4096 + wi * 64 + n;

    ushort4 o;
    o.x = f2bf((v.x - mean) * rstd * gg.x + bb.x);
    o.y = f2bf((v.y - mean) * rstd * gg.y + bb.y);
    o.z = f2bf((v.z - mean) * rstd * gg.z + bb.z);
    o.w = f2bf((v.w - mean) * rstd * gg.w + bb.w);
    *(ushort4*)(dst + (size_t)orow * 256 + lane * 4) = o;
}

// ---------------------------------------------------------------- GEMM ------
// 128x128 tile, BK=64, 2-phase dbuf global_load_lds, swapped mfma(B,A) ->
// wide stores. EPI: 0 bf16 out, 2 proj(+window-rev+resid) -> bf16.
template <int NCOLS, int KD, int EPI>
__global__ __launch_bounds__(256) void gemm_k(
    const u16* __restrict__ A, const u16* __restrict__ Bt,
    const float* __restrict__ bias, u16* __restrict__ obf,
    const float* __restrict__ res)
{
    __shared__ __align__(16) u16 As[2][128 * 64];
    __shared__ __align__(16) u16 Bs[2][128 * 64];
    const int t = threadIdx.x;
    const int lane = t & 63, w = t >> 6;
    const int wm = w >> 1, wn = w & 1;
    const int g = lane >> 4, c = lane & 15;
    const int bm = blockIdx.x * 128;
    const int bn = blockIdx.y * 128;
    const int r_in = lane >> 3;
    const int slot = lane & 7;
    const int gch  = slot ^ r_in;

    const u16* Ab = A  + (size_t)bm * KD + gch * 8;
    const u16* Bb = Bt + (size_t)bn * KD + gch * 8;

    f32x4 acc[4][4];
    #pragma unroll
    for (int i = 0; i < 4; i++)
        #pragma unroll
        for (int j = 0; j < 4; j++) acc[i][j] = (f32x4){0.f, 0.f, 0.f, 0.f};

#define STAGE(buf, k0)                                                        \
    {                                                                         \
        _Pragma("unroll")                                                     \
        for (int i_ = 0; i_ < 4; i_++) {                                      \
            const int rowbase = w * 32 + i_ * 8;                              \
            GLOAD16(&As[buf][rowbase * 64],                                   \
                    Ab + (size_t)(rowbase + r_in) * KD + (k0));               \
            GLOAD16(&Bs[buf][rowbase * 64],                                   \
                    Bb + (size_t)(rowbase + r_in) * KD + (k0));               \
        }                                                                     \
    }

#define COMPUTE(buf)                                                          \
    {                                                                         \
        _Pragma("unroll")                                                     \
        for (int kk = 0; kk < 2; kk++) {                                      \
            bf16x8 af[4], bfr[4];                                             \
            _Pragma("unroll")                                                 \
            for (int i_ = 0; i_ < 4; i_++) {                                  \
                int ra = wm * 64 + i_ * 16 + c;                               \
                af[i_]  = *(const bf16x8*)(&As[buf][ra * 64 + ((kk * 4 + g) ^ (ra & 7)) * 8]); \
                int rb = wn * 64 + i_ * 16 + c;                               \
                bfr[i_] = *(const bf16x8*)(&Bs[buf][rb * 64 + ((kk * 4 + g) ^ (rb & 7)) * 8]); \
            }                                                                 \
            _Pragma("unroll")                                                 \
            for (int i_ = 0; i_ < 4; i_++)                                    \
                _Pragma("unroll")                                             \
                for (int j_ = 0; j_ < 4; j_++)                                \
                    acc[i_][j_] = __builtin_amdgcn_mfma_f32_16x16x32_bf16(    \
                        bfr[j_], af[i_], acc[i_][j_], 0, 0, 0);               \
        }                                                                     \
    }

    STAGE(0, 0);
    __syncthreads();
    for (int k0 = 0; k0 < KD; k0 += 128) {
        STAGE(1, k0 + 64);
        COMPUTE(0);
        __syncthreads();
        if (k0 + 128 < KD) STAGE(0, k0 + 128);
        COMPUTE(1);
        if (k0 + 128 < KD) __syncthreads();
    }
#undef STAGE
#undef COMPUTE

    #pragma unroll
    for (int i = 0; i < 4; i++) {
        int row = bm + wm * 64 + i * 16 + c;
        #pragma unroll
        for (int j = 0; j < 4; j++) {
            int col = bn + wn * 64 + j * 16 + 4 * g;
            float4 b4 = *(const float4*)(bias + col);
            float v0 = acc[i][j][0] + b4.x;
            float v1 = acc[i][j][1] + b4.y;
            float v2 = acc[i][j][2] + b4.z;
            float v3 = acc[i][j][3] + b4.w;
            if constexpr (EPI == 0) {
                uint2 pk = { pk2(v0, v1), pk2(v2, v3) };
                *(uint2*)(obf + (size_t)row * NCOLS + col) = pk;
            } else {  // proj: window-reverse + residual(f32) -> bf16 x
                int b_ = row >> 12, wi = (row >> 6) & 63, n = row & 63;
                int hh = (wi >> 3) * 8 + (n >> 3);
                int ww = (wi & 7) * 8 + (n & 7);
                size_t nrow = (size_t)b_ * 4096 + hh * 64 + ww;
                float4 r4 = *(const float4*)(res + nrow * 256 + col);
                uint2 pk = { pk2(v0 + r4.x, v1 + r4.y), pk2(v2 + r4.z, v3 + r4.w) };
                *(uint2*)(obf + nrow * 256 + col) = pk;
            }
        }
    }
}

// ----------------------------------------------------------- attention ------
__global__ __launch_bounds__(256) void attn_k(
    const u16* __restrict__ Q, const u16* __restrict__ KV,
    const float* __restrict__ biasF, u16* __restrict__ O)
{
    __shared__ __align__(16) u16 Pl[4][64 * 64];
    __shared__ __align__(16) u16 Vt[4][32 * 80];
    const int t = threadIdx.x, lane = t & 63, w = t >> 6;
    const int g = lane >> 4, c = lane & 15;
    const int pair = blockIdx.x * 4 + w;
    const int win = pair >> 3, head = pair & 7;
    const size_t qbase  = (size_t)win * 64 * 256 + head * 32;
    const size_t kvbase = (size_t)win * 64 * 512 + head * 32;

    u16* vt = &Vt[w][0];
    {
        const u16* vp = KV + kvbase + 256 + (size_t)lane * 512;
        uint4 v0 = *(const uint4*)(vp);
        uint4 v1 = *(const uint4*)(vp + 8);
        uint4 v2 = *(const uint4*)(vp + 16);
        uint4 v3 = *(const uint4*)(vp + 24);
#define SCAT(vv, dbase)                                           \
        vt[(dbase + 0) * 80 + lane] = (u16)(vv.x);                \
        vt[(dbase + 1) * 80 + lane] = (u16)(vv.x >> 16);          \
        vt[(dbase + 2) * 80 + lane] = (u16)(vv.y);                \
        vt[(dbase + 3) * 80 + lane] = (u16)(vv.y >> 16);          \
        vt[(dbase + 4) * 80 + lane] = (u16)(vv.z);                \
        vt[(dbase + 5) * 80 + lane] = (u16)(vv.z >> 16);          \
        vt[(dbase + 6) * 80 + lane] = (u16)(vv.w);                \
        vt[(dbase + 7) * 80 + lane] = (u16)(vv.w >> 16);
        SCAT(v0, 0) SCAT(v1, 8) SCAT(v2, 16) SCAT(v3, 24)
#undef SCAT
    }

    bf16x8 qf[4], kf[4];
    #pragma unroll
    for (int i = 0; i < 4; i++) {
        qf[i] = *(const bf16x8*)(Q  + qbase  + (size_t)(i * 16 + c) * 256 + 8 * g);
        kf[i] = *(const bf16x8*)(KV + kvbase + (size_t)(i * 16 + c) * 512 + 8 * g);
    }
    f32x4 s[4][4];
    #pragma unroll
    for (int i = 0; i < 4; i++)
        #pragma unroll
        for (int j = 0; j < 4; j++) {
            s[i][j] = (f32x4){0.f, 0.f, 0.f, 0.f};
            s[i][j] = __builtin_amdgcn_mfma_f32_16x16x32_bf16(kf[j], qf[i], s[i][j], 0, 0, 0);
        }

    #pragma unroll
    for (int i = 0; i < 4; i++)
        #pragma unroll
        for (int j = 0; j < 4; j++) {
            f32x4 bf4 = *(const f32x4*)(biasF + ((size_t)(head * 16 + i * 4 + j) * 64 + lane) * 4);
            #pragma unroll
            for (int r = 0; r < 4; r++) s[i][j][r] = s[i][j][r] * SCALE + bf4[r];
        }

    #pragma unroll
    for (int i = 0; i < 4; i++) {
        float mx = -1e30f;
        #pragma unroll
        for (int j = 0; j < 4; j++)
            #pragma unroll
            for (int r = 0; r < 4; r++) mx = fmaxf(mx, s[i][j][r]);
        mx = fmaxf(mx, __shfl_xor(mx, 16, 64));
        mx = fmaxf(mx, __shfl_xor(mx, 32, 64));
        float sum = 0.f;
        #pragma unroll
        for (int j = 0; j < 4; j++)
            #pragma unroll
            for (int r = 0; r < 4; r++) {
                float e = __expf(s[i][j][r] - mx);
                s[i][j][r] = e; sum += e;
            }
        sum += __shfl_xor(sum, 16, 64);
        sum += __shfl_xor(sum, 32, 64);
        float inv = 1.f / sum;
        #pragma unroll
        for (int j = 0; j < 4; j++)
            #pragma unroll
            for (int r = 0; r < 4; r++) s[i][j][r] *= inv;
    }

    u16* pl = &Pl[w][0];
    #pragma unroll
    for (int i = 0; i < 4; i++) {
        int m = i * 16 + c;
        #pragma unroll
        for (int j = 0; j < 4; j++) {
            int kbyte = 32 * j + 8 * g;
            uint2 pk = { pk2(s[i][j][0], s[i][j][1]), pk2(s[i][j][2], s[i][j][3]) };
            *(uint2*)((char*)pl + m * 128 + (kbyte ^ ((m & 7) << 4))) = pk;
        }
    }

    f32x4 o[4][2];
    #pragma unroll
    for (int i = 0; i < 4; i++) { o[i][0] = (f32x4){0,0,0,0}; o[i][1] = (f32x4){0,0,0,0}; }
    #pragma unroll
    for (int ks = 0; ks < 2; ks++) {
        bf16x8 pa[4], vb[2];
        #pragma unroll
        for (int i = 0; i < 4; i++) {
            int row = i * 16 + c;
            int ch = (ks * 4 + g) ^ (row & 7);
            pa[i] = *(const bf16x8*)((char*)pl + row * 128 + ch * 16);
        }
        #pragma unroll
        for (int j = 0; j < 2; j++) {
            int d = j * 16 + c;
            vb[j] = *(const bf16x8*)(vt + d * 80 + ks * 32 + 8 * g);
        }
        #pragma unroll
        for (int i = 0; i < 4; i++)
            #pragma unroll
            for (int j = 0; j < 2; j++)
                o[i][j] = __builtin_amdgcn_mfma_f32_16x16x32_bf16(vb[j], pa[i], o[i][j], 0, 0, 0);
    }

    #pragma unroll
    for (int i = 0; i < 4; i++) {
        size_t row = (size_t)win * 64 + i * 16 + c;
        #pragma unroll
        for (int j = 0; j < 2; j++) {
            int col = head * 32 + j * 16 + 4 * g;
            uint2 pk = { pk2(o[i][j][0], o[i][j][1]), pk2(o[i][j][2], o[i][j][3]) };
            *(uint2*)(O + row * 256 + col) = pk;
        }
    }
}

// ------------------------------------------------------------ MLP mega ------
// out = x + fc2(gelu(fc1(LN(x)))), x in bf16. 128 rows/block, 8 waves (2x4),
// 512 blocks. Hidden (4 chunks of 256) lives in LDS only. Weights as packed
// fragments from L2 (512MB total, half of R8). Direct global f32 epilogue
// (no LDS bounce). LDS 128KB -> 1 block/CU, 2 waves/SIMD, VGPR free to 256.
__global__ __launch_bounds__(512, 1) void mlp_mega(
    const u16* __restrict__ xb, const float* __restrict__ gw,
    const float* __restrict__ bw, const bf16x8* __restrict__ f1p,
    const bf16x8* __restrict__ f2p, const float* __restrict__ f1b,
    const float* __restrict__ f2b, float* __restrict__ out)
{
    __shared__ __align__(16) u16 Xl[128 * 256];   // 64 KB, swizzled
    __shared__ __align__(16) u16 Hl[128 * 256];   // 64 KB, swizzled
    const int t = threadIdx.x, lane = t & 63, w = t >> 6;
    const int wm = w >> 2, wn = w & 3;
    const int g = lane >> 4, c = lane & 15;
    const int m0 = blockIdx.x * 128;

    // ---- LN inline: wave w handles rows w*16..+15 (bf16 in) ----
    {
        float4 gg = *(const float4*)(gw + lane * 4);
        float4 bb = *(const float4*)(bw + lane * 4);
        for (int it = 0; it < 16; it++) {
            int row = w * 16 + it;
            uint2 rv = *(const uint2*)(xb + (size_t)(m0 + row) * 256 + lane * 4);
            float v0 = bf2f((u16)rv.x), v1 = bf2f((u16)(rv.x >> 16));
            float v2 = bf2f((u16)rv.y), v3 = bf2f((u16)(rv.y >> 16));
            float s = v0 + v1 + v2 + v3;
            float q = v0 * v0 + v1 * v1 + v2 * v2 + v3 * v3;
            #pragma unroll
            for (int m = 1; m < 64; m <<= 1) {
                s += __shfl_xor(s, m, 64);
                q += __shfl_xor(q, m, 64);
            }
            float mean = s * (1.0f / 256.0f);
            float var  = q * (1.0f / 256.0f) - mean * mean;
            float rstd = rsqrtf(var + 1e-5f);
            float n0 = (v0 - mean) * rstd * gg.x + bb.x;
            float n1 = (v1 - mean) * rstd * gg.y + bb.y;
            float n2 = (v2 - mean) * rstd * gg.z + bb.z;
            float n3 = (v3 - mean) * rstd * gg.w + bb.w;
            uint2 pk = { pk2(n0, n1), pk2(n2, n3) };
            *(uint2*)((char*)Xl + row * 512 + (((lane >> 1) ^ (row & 7)) << 4)
                      + ((lane & 1) << 3)) = pk;
        }
    }
    __syncthreads();

    f32x4 acc2[4][4];
    #pragma unroll
    for (int i = 0; i < 4; i++)
        #pragma unroll
        for (int n = 0; n < 4; n++) acc2[i][n] = (f32x4){0, 0, 0, 0};

    #pragma unroll
    for (int hc = 0; hc < 4; hc++) {
        // ---- fc1: rows wm*64..+63, cols (chunk) wn*64..+63 ----
        f32x4 acc1[4][4];
        #pragma unroll
        for (int i = 0; i < 4; i++)
            #pragma unroll
            for (int n = 0; n < 4; n++) acc1[i][n] = (f32x4){0, 0, 0, 0};
        #pragma unroll
        for (int ks = 0; ks < 8; ks++) {
            bf16x8 bfr[4], af[4];
            #pragma unroll
            for (int n = 0; n < 4; n++)
                bfr[n] = f1p[(size_t)((hc * 16 + wn * 4 + n) * 8 + ks) * 64 + lane];
            #pragma unroll
            for (int i = 0; i < 4; i++) {
                int row = wm * 64 + i * 16 + c;
                af[i] = *(const bf16x8*)((char*)Xl + row * 512
                                         + (((4 * ks + g) ^ (row & 7)) << 4));
            }
            #pragma unroll
            for (int i = 0; i < 4; i++)
                #pragma unroll
                for (int n = 0; n < 4; n++)
                    acc1[i][n] = __builtin_amdgcn_mfma_f32_16x16x32_bf16(
                        bfr[n], af[i], acc1[i][n], 0, 0, 0);
        }
        // gelu + bias -> Hl (swizzled)
        #pragma unroll
        for (int i = 0; i < 4; i++) {
            int row = wm * 64 + i * 16 + c;
            #pragma unroll
            for (int n = 0; n < 4; n++) {
                float4 b4 = *(const float4*)(f1b + hc * 256 + wn * 64 + n * 16 + 4 * g);
                float h0 = gelu_t(acc1[i][n][0] + b4.x);
                float h1 = gelu_t(acc1[i][n][1] + b4.y);
                float h2 = gelu_t(acc1[i][n][2] + b4.z);
                float h3 = gelu_t(acc1[i][n][3] + b4.w);
                uint2 pk = { pk2(h0, h1), pk2(h2, h3) };
                int cq = 8 * wn + 2 * n + (g >> 1);
                *(uint2*)((char*)Hl + row * 512 + (((cq ^ (row & 7)) << 4))
                          + ((g & 1) << 3)) = pk;
            }
        }
        __syncthreads();
        // ---- fc2: acc2 += h_chunk @ f2w_chunk ----
        #pragma unroll
        for (int ks = 0; ks < 8; ks++) {
            bf16x8 bfr[4], ah[4];
            #pragma unroll
            for (int n = 0; n < 4; n++)
                bfr[n] = f2p[(size_t)((wn * 4 + n) * 32 + hc * 8 + ks) * 64 + lane];
            #pragma unroll
            for (int i = 0; i < 4; i++) {
                int row = wm * 64 + i * 16 + c;
                ah[i] = *(const bf16x8*)((char*)Hl + row * 512
                                         + (((4 * ks + g) ^ (row & 7)) << 4));
            }
            #pragma unroll
            for (int i = 0; i < 4; i++)
                #pragma unroll
                for (int n = 0; n < 4; n++)
                    acc2[i][n] = __builtin_amdgcn_mfma_f32_16x16x32_bf16(
                        bfr[n], ah[i], acc2[i][n], 0, 0, 0);
        }
        __syncthreads();
    }

    // ---- direct epilogue: out = acc2 + f2b + x (bf16 resid), f32 stores ----
    #pragma unroll
    for (int i = 0; i < 4; i++) {
        int row = m0 + wm * 64 + i * 16 + c;
        #pragma unroll
        for (int n = 0; n < 4; n++) {
            int col = wn * 64 + n * 16 + 4 * g;
            float4 b4 = *(const float4*)(f2b + col);
            uint2 rr = *(const uint2*)(xb + (size_t)row * 256 + col);
            float4 ov = { acc2[i][n][0] + b4.x + bf2f((u16)rr.x),
                          acc2[i][n][1] + b4.y + bf2f((u16)(rr.x >> 16)),
                          acc2[i][n][2] + b4.z + bf2f((u16)rr.y),
                          acc2[i][n][3] + b4.w + bf2f((u16)(rr.y >> 16)) };
            *(float4*)(out + (size_t)row * 256 + col) = ov;
        }
    }
}

// -------------------------------------------------------------- launch ------
// Workspace (peak ~137 MB):
//   [0,       2.10M)  weights: qwt kvwt pwt f1p f2p biasF
//   [2.10M,  35.65M)  x1w -> attn (after Q gemm)
//   [35.65M, 69.21M)  x2w
//   [69.21M,136.31M)  Qb -> xbw bf16 (after attn)
//   [102.76M,169.87M) KVb
extern "C" void kernel_launch(void* const* d_in, const int* in_sizes, int n_in,
                              void* d_out, int out_size, void* d_ws, size_t ws_size,
                              hipStream_t stream)
{
    const float* x1  = (const float*)d_in[0];
    const float* x2  = (const float*)d_in[1];
    const float* n1g = (const float*)d_in[2];
    const float* n1b = (const float*)d_in[3];
    const float* q_w = (const float*)d_in[4];
    const float* q_b = (const float*)d_in[5];
    const float* kv_w= (const float*)d_in[6];
    const float* kv_b= (const float*)d_in[7];
    const float* p_w = (const float*)d_in[8];
    const float* p_b = (const float*)d_in[9];
    const float* rel = (const float*)d_in[10];
    const float* n3g = (const float*)d_in[11];
    const float* n3b = (const float*)d_in[12];
    const float* f1w = (const float*)d_in[13];
    const float* f1b = (const float*)d_in[14];
    const float* f2w = (const float*)d_in[15];
    const float* f2b = (const float*)d_in[16];

    char* ws = (char*)d_ws;
    u16*   qwt   = (u16*)(ws + 0);
    u16*   kvwt  = (u16*)(ws + 131072);
    u16*   pwt   = (u16*)(ws + 393216);
    u16*   f1p   = (u16*)(ws + 524288);
    u16*   f2p   = (u16*)(ws + 1048576);
    float* biasF = (float*)(ws + 1572864);

    u16*   x1w  = (u16*)(ws + 2097152);
    u16*   x2w  = (u16*)(ws + 35651584);
    u16*   Qb   = (u16*)(ws + 69206016);
    u16*   KVb  = (u16*)(ws + 102760448);
    u16*   attn = (u16*)(ws + 2097152);     // overlays x1w (dead after Q gemm)
    u16*   xbw  = (u16*)(ws + 69206016);    // bf16 x, overlays Qb (dead after attn)

    float* out = (float*)d_out;

    prep_k<<<3200, 256, 0, stream>>>(q_w, kv_w, p_w, f1w, f2w, rel,
                                     qwt, kvwt, pwt, f1p, f2p, biasF);
    ln_k<<<32768, 256, 0, stream>>>(x1, x2, n1g, n1b, x1w, x2w);
    gemm_k<256, 256, 0><<<dim3(512, 2), 256, 0, stream>>>(x1w, qwt, q_b, Qb, nullptr);
    gemm_k<512, 256, 0><<<dim3(512, 4), 256, 0, stream>>>(x2w, kvwt, kv_b, KVb, nullptr);
    attn_k<<<2048, 256, 0, stream>>>(Qb, KVb, biasF, attn);
    gemm_k<256, 256, 2><<<dim3(512, 2), 256, 0, stream>>>(attn, pwt, p_b, xbw, x1);
    mlp_mega<<<512, 512, 0, stream>>>(xbw, n3g, n3b, (const bf16x8*)f1p,
                                      (const bf16x8*)f2p, f1b, f2b, out);
}

// Round 10
// 307.334 us; speedup vs baseline: 1.0835x; 1.0835x over previous
//
#include <hip/hip_runtime.h>

typedef __bf16 bf16x8 __attribute__((ext_vector_type(8)));
typedef float f32x4 __attribute__((ext_vector_type(4)));
using u16 = unsigned short;

#define SCALE 0.17677669529663689f  // 32^-0.5

// Direct HBM->LDS DMA, 16B per lane (dest linear: base + lane*16).
#define GLOAD16(lp, gp)                                                        \
    __builtin_amdgcn_global_load_lds(                                          \
        (const __attribute__((address_space(1))) void*)(gp),                   \
        (__attribute__((address_space(3))) void*)(lp), 16, 0, 0)

__device__ __forceinline__ u16 f2bf(float f) {
    union { float f; unsigned u; } x; x.f = f;
    unsigned r = x.u + 0x7fffu + ((x.u >> 16) & 1u);
    return (u16)(r >> 16);
}
__device__ __forceinline__ unsigned pk2(float a, float b) {
    return (unsigned)f2bf(a) | ((unsigned)f2bf(b) << 16);
}
__device__ __forceinline__ float bf2f(u16 h) {
    union { unsigned u; float f; } x; x.u = ((unsigned)h) << 16; return x.f;
}
__device__ __forceinline__ float gelu_t(float x) {
    float u = 0.7978845608028654f * (x + 0.044715f * x * x * x);
    float e = __expf(2.f * u);
    float th = 1.f - 2.f / (e + 1.f);          // tanh(u), overflow-safe
    return 0.5f * x * (1.f + th);
}

// ---------------------------------------------------------------- prep ------
// qwt/kvwt/pwt: Wt[N][K] bf16 (for gemm_k). f1p/f2p: fragment-packed bf16
// (frag (ng,ks): lane l holds W[k=32ks+8(l>>4)+e][n=16ng+(l&15)]).
// biasF: rel-pos bias in swapped C-frag layout.
__global__ __launch_bounds__(256) void prep_k(
    const float* __restrict__ q_w, const float* __restrict__ kv_w,
    const float* __restrict__ p_w, const float* __restrict__ f1w,
    const float* __restrict__ f2w, const float* __restrict__ rel,
    u16* __restrict__ qwt, u16* __restrict__ kvwt, u16* __restrict__ pwt,
    u16* __restrict__ f1p, u16* __restrict__ f2p, float* __restrict__ biasF)
{
    int t = blockIdx.x * 256 + threadIdx.x;
    if (t < 65536) {                                   // q_w  256x256
        int k = t & 255, n = t >> 8;
        qwt[t] = f2bf(q_w[k * 256 + n]);
    } else if (t < 196608) {                           // kv_w 256x512
        int u = t - 65536; int k = u & 255, n = u >> 8;
        kvwt[u] = f2bf(kv_w[k * 512 + n]);
    } else if (t < 262144) {                           // proj_w 256x256
        int u = t - 196608; int k = u & 255, n = u >> 8;
        pwt[u] = f2bf(p_w[k * 256 + n]);
    } else if (t < 524288) {                           // f1p packed frags
        int u = t - 262144;
        int e = u & 7, l = (u >> 3) & 63, ks = (u >> 9) & 7, ng = u >> 12;
        int k = ks * 32 + (l >> 4) * 8 + e;
        int n = ng * 16 + (l & 15);
        f1p[u] = f2bf(f1w[k * 1024 + n]);
    } else if (t < 786432) {                           // f2p packed frags
        int u = t - 524288;
        int e = u & 7, l = (u >> 3) & 63, ks = (u >> 9) & 31, ng = u >> 14;
        int k = ks * 32 + (l >> 4) * 8 + e;
        int n = ng * 16 + (l & 15);
        f2p[u] = f2bf(f2w[k * 256 + n]);
    } else if (t < 819200) {                           // biasF 8*16*64*4
        int u = t - 786432;
        int r = u & 3, l = (u >> 2) & 63, fr = (u >> 8) & 15, h = u >> 12;
        int fi = fr >> 2, fj = fr & 3;
        int m = fi * 16 + (l & 15);
        int n = fj * 16 + 4 * (l >> 4) + r;
        int idx = ((m >> 3) - (n >> 3) + 7) * 15 + ((m & 7) - (n & 7) + 7);
        biasF[u] = rel[idx * 8 + h];
    }
}

// ----------------------------------------------------------- layernorm ------
// One wave per 256-elem row; two streams + window-partition permute.
__global__ __launch_bounds__(256) void ln_k(
    const float* __restrict__ xa, const float* __restrict__ xb,
    const float* __restrict__ gw, const float* __restrict__ bw,
    u16* __restrict__ oa, u16* __restrict__ ob)
{
    int lane = threadIdx.x & 63, wid = threadIdx.x >> 6;
    int r = blockIdx.x * 4 + wid;
    const float* src; u16* dst; int row;
    if (r < 65536) { src = xa; dst = oa; row = r; }
    else           { src = xb; dst = ob; row = r - 65536; }

    float4 v = *(const float4*)(src + (size_t)row * 256 + lane * 4);
    float s = v.x + v.y + v.z + v.w;
    float q = v.x * v.x + v.y * v.y + v.z * v.z + v.w * v.w;
    #pragma unroll
    for (int m = 1; m < 64; m <<= 1) {
        s += __shfl_xor(s, m, 64);
        q += __shfl_xor(q, m, 64);
    }
    float mean = s * (1.0f / 256.0f);
    float var  = q * (1.0f / 256.0f) - mean * mean;
    float rstd = rsqrtf(var + 1e-5f);
    float4 gg = *(const float4*)(gw + lane * 4);
    float4 bb = *(const float4*)(bw + lane * 4);

    int b_ = row >> 12, l = row & 4095;
    int hh = l >> 6, ww = l & 63;
    int wi = (hh >> 3) * 8 + (ww >> 3);
    int n  = (hh & 7) * 8 + (ww & 7);
    int orow = b_ * 4096 + wi * 64 + n;

    ushort4 o;
    o.x = f2bf((v.x - mean) * rstd * gg.x + bb.x);
    o.y = f2bf((v.y - mean) * rstd * gg.y + bb.y);
    o.z = f2bf((v.z - mean) * rstd * gg.z + bb.z);
    o.w = f2bf((v.w - mean) * rstd * gg.w + bb.w);
    *(ushort4*)(dst + (size_t)orow * 256 + lane * 4) = o;
}

// ---------------------------------------------------------------- GEMM ------
// 128x128 tile, BK=64, 2-phase dbuf global_load_lds, swapped mfma(B,A) ->
// wide stores. EPI: 0 bf16 out, 2 proj(+window-rev+resid) -> bf16.
template <int NCOLS, int KD, int EPI>
__global__ __launch_bounds__(256) void gemm_k(
    const u16* __restrict__ A, const u16* __restrict__ Bt,
    const float* __restrict__ bias, u16* __restrict__ obf,
    const float* __restrict__ res)
{
    __shared__ __align__(16) u16 As[2][128 * 64];
    __shared__ __align__(16) u16 Bs[2][128 * 64];
    const int t = threadIdx.x;
    const int lane = t & 63, w = t >> 6;
    const int wm = w >> 1, wn = w & 1;
    const int g = lane >> 4, c = lane & 15;
    const int bm = blockIdx.x * 128;
    const int bn = blockIdx.y * 128;
    const int r_in = lane >> 3;
    const int slot = lane & 7;
    const int gch  = slot ^ r_in;

    const u16* Ab = A  + (size_t)bm * KD + gch * 8;
    const u16* Bb = Bt + (size_t)bn * KD + gch * 8;

    f32x4 acc[4][4];
    #pragma unroll
    for (int i = 0; i < 4; i++)
        #pragma unroll
        for (int j = 0; j < 4; j++) acc[i][j] = (f32x4){0.f, 0.f, 0.f, 0.f};

#define STAGE(buf, k0)                                                        \
    {                                                                         \
        _Pragma("unroll")                                                     \
        for (int i_ = 0; i_ < 4; i_++) {                                      \
            const int rowbase = w * 32 + i_ * 8;                              \
            GLOAD16(&As[buf][rowbase * 64],                                   \
                    Ab + (size_t)(rowbase + r_in) * KD + (k0));               \
            GLOAD16(&Bs[buf][rowbase * 64],                                   \
                    Bb + (size_t)(rowbase + r_in) * KD + (k0));               \
        }                                                                     \
    }

#define COMPUTE(buf)                                                          \
    {                                                                         \
        _Pragma("unroll")                                                     \
        for (int kk = 0; kk < 2; kk++) {                                      \
            bf16x8 af[4], bfr[4];                                             \
            _Pragma("unroll")                                                 \
            for (int i_ = 0; i_ < 4; i_++) {                                  \
                int ra = wm * 64 + i_ * 16 + c;                               \
                af[i_]  = *(const bf16x8*)(&As[buf][ra * 64 + ((kk * 4 + g) ^ (ra & 7)) * 8]); \
                int rb = wn * 64 + i_ * 16 + c;                               \
                bfr[i_] = *(const bf16x8*)(&Bs[buf][rb * 64 + ((kk * 4 + g) ^ (rb & 7)) * 8]); \
            }                                                                 \
            _Pragma("unroll")                                                 \
            for (int i_ = 0; i_ < 4; i_++)                                    \
                _Pragma("unroll")                                             \
                for (int j_ = 0; j_ < 4; j_++)                                \
                    acc[i_][j_] = __builtin_amdgcn_mfma_f32_16x16x32_bf16(    \
                        bfr[j_], af[i_], acc[i_][j_], 0, 0, 0);               \
        }                                                                     \
    }

    STAGE(0, 0);
    __syncthreads();
    for (int k0 = 0; k0 < KD; k0 += 128) {
        STAGE(1, k0 + 64);
        COMPUTE(0);
        __syncthreads();
        if (k0 + 128 < KD) STAGE(0, k0 + 128);
        COMPUTE(1);
        if (k0 + 128 < KD) __syncthreads();
    }
#undef STAGE
#undef COMPUTE

    #pragma unroll
    for (int i = 0; i < 4; i++) {
        int row = bm + wm * 64 + i * 16 + c;
        #pragma unroll
        for (int j = 0; j < 4; j++) {
            int col = bn + wn * 64 + j * 16 + 4 * g;
            float4 b4 = *(const float4*)(bias + col);
            float v0 = acc[i][j][0] + b4.x;
            float v1 = acc[i][j][1] + b4.y;
            float v2 = acc[i][j][2] + b4.z;
            float v3 = acc[i][j][3] + b4.w;
            if constexpr (EPI == 0) {
                uint2 pk = { pk2(v0, v1), pk2(v2, v3) };
                *(uint2*)(obf + (size_t)row * NCOLS + col) = pk;
            } else {  // proj: window-reverse + residual(f32) -> bf16 x
                int b_ = row >> 12, wi = (row >> 6) & 63, n = row & 63;
                int hh = (wi >> 3) * 8 + (n >> 3);
                int ww = (wi & 7) * 8 + (n & 7);
                size_t nrow = (size_t)b_ * 4096 + hh * 64 + ww;
                float4 r4 = *(const float4*)(res + nrow * 256 + col);
                uint2 pk = { pk2(v0 + r4.x, v1 + r4.y), pk2(v2 + r4.z, v3 + r4.w) };
                *(uint2*)(obf + nrow * 256 + col) = pk;
            }
        }
    }
}

// ----------------------------------------------------------- attention ------
__global__ __launch_bounds__(256) void attn_k(
    const u16* __restrict__ Q, const u16* __restrict__ KV,
    const float* __restrict__ biasF, u16* __restrict__ O)
{
    __shared__ __align__(16) u16 Pl[4][64 * 64];
    __shared__ __align__(16) u16 Vt[4][32 * 80];
    const int t = threadIdx.x, lane = t & 63, w = t >> 6;
    const int g = lane >> 4, c = lane & 15;
    const int pair = blockIdx.x * 4 + w;
    const int win = pair >> 3, head = pair & 7;
    const size_t qbase  = (size_t)win * 64 * 256 + head * 32;
    const size_t kvbase = (size_t)win * 64 * 512 + head * 32;

    u16* vt = &Vt[w][0];
    {
        const u16* vp = KV + kvbase + 256 + (size_t)lane * 512;
        uint4 v0 = *(const uint4*)(vp);
        uint4 v1 = *(const uint4*)(vp + 8);
        uint4 v2 = *(const uint4*)(vp + 16);
        uint4 v3 = *(const uint4*)(vp + 24);
#define SCAT(vv, dbase)                                           \
        vt[(dbase + 0) * 80 + lane] = (u16)(vv.x);                \
        vt[(dbase + 1) * 80 + lane] = (u16)(vv.x >> 16);          \
        vt[(dbase + 2) * 80 + lane] = (u16)(vv.y);                \
        vt[(dbase + 3) * 80 + lane] = (u16)(vv.y >> 16);          \
        vt[(dbase + 4) * 80 + lane] = (u16)(vv.z);                \
        vt[(dbase + 5) * 80 + lane] = (u16)(vv.z >> 16);          \
        vt[(dbase + 6) * 80 + lane] = (u16)(vv.w);                \
        vt[(dbase + 7) * 80 + lane] = (u16)(vv.w >> 16);
        SCAT(v0, 0) SCAT(v1, 8) SCAT(v2, 16) SCAT(v3, 24)
#undef SCAT
    }

    bf16x8 qf[4], kf[4];
    #pragma unroll
    for (int i = 0; i < 4; i++) {
        qf[i] = *(const bf16x8*)(Q  + qbase  + (size_t)(i * 16 + c) * 256 + 8 * g);
        kf[i] = *(const bf16x8*)(KV + kvbase + (size_t)(i * 16 + c) * 512 + 8 * g);
    }
    f32x4 s[4][4];
    #pragma unroll
    for (int i = 0; i < 4; i++)
        #pragma unroll
        for (int j = 0; j < 4; j++) {
            s[i][j] = (f32x4){0.f, 0.f, 0.f, 0.f};
            s[i][j] = __builtin_amdgcn_mfma_f32_16x16x32_bf16(kf[j], qf[i], s[i][j], 0, 0, 0);
        }

    #pragma unroll
    for (int i = 0; i < 4; i++)
        #pragma unroll
        for (int j = 0; j < 4; j++) {
            f32x4 bf4 = *(const f32x4*)(biasF + ((size_t)(head * 16 + i * 4 + j) * 64 + lane) * 4);
            #pragma unroll
            for (int r = 0; r < 4; r++) s[i][j][r] = s[i][j][r] * SCALE + bf4[r];
        }

    #pragma unroll
    for (int i = 0; i < 4; i++) {
        float mx = -1e30f;
        #pragma unroll
        for (int j = 0; j < 4; j++)
            #pragma unroll
            for (int r = 0; r < 4; r++) mx = fmaxf(mx, s[i][j][r]);
        mx = fmaxf(mx, __shfl_xor(mx, 16, 64));
        mx = fmaxf(mx, __shfl_xor(mx, 32, 64));
        float sum = 0.f;
        #pragma unroll
        for (int j = 0; j < 4; j++)
            #pragma unroll
            for (int r = 0; r < 4; r++) {
                float e = __expf(s[i][j][r] - mx);
                s[i][j][r] = e; sum += e;
            }
        sum += __shfl_xor(sum, 16, 64);
        sum += __shfl_xor(sum, 32, 64);
        float inv = 1.f / sum;
        #pragma unroll
        for (int j = 0; j < 4; j++)
            #pragma unroll
            for (int r = 0; r < 4; r++) s[i][j][r] *= inv;
    }

    u16* pl = &Pl[w][0];
    #pragma unroll
    for (int i = 0; i < 4; i++) {
        int m = i * 16 + c;
        #pragma unroll
        for (int j = 0; j < 4; j++) {
            int kbyte = 32 * j + 8 * g;
            uint2 pk = { pk2(s[i][j][0], s[i][j][1]), pk2(s[i][j][2], s[i][j][3]) };
            *(uint2*)((char*)pl + m * 128 + (kbyte ^ ((m & 7) << 4))) = pk;
        }
    }

    f32x4 o[4][2];
    #pragma unroll
    for (int i = 0; i < 4; i++) { o[i][0] = (f32x4){0,0,0,0}; o[i][1] = (f32x4){0,0,0,0}; }
    #pragma unroll
    for (int ks = 0; ks < 2; ks++) {
        bf16x8 pa[4], vb[2];
        #pragma unroll
        for (int i = 0; i < 4; i++) {
            int row = i * 16 + c;
            int ch = (ks * 4 + g) ^ (row & 7);
            pa[i] = *(const bf16x8*)((char*)pl + row * 128 + ch * 16);
        }
        #pragma unroll
        for (int j = 0; j < 2; j++) {
            int d = j * 16 + c;
            vb[j] = *(const bf16x8*)(vt + d * 80 + ks * 32 + 8 * g);
        }
        #pragma unroll
        for (int i = 0; i < 4; i++)
            #pragma unroll
            for (int j = 0; j < 2; j++)
                o[i][j] = __builtin_amdgcn_mfma_f32_16x16x32_bf16(vb[j], pa[i], o[i][j], 0, 0, 0);
    }

    #pragma unroll
    for (int i = 0; i < 4; i++) {
        size_t row = (size_t)win * 64 + i * 16 + c;
        #pragma unroll
        for (int j = 0; j < 2; j++) {
            int col = head * 32 + j * 16 + 4 * g;
            uint2 pk = { pk2(o[i][j][0], o[i][j][1]), pk2(o[i][j][2], o[i][j][3]) };
            *(uint2*)(O + row * 256 + col) = pk;
        }
    }
}

// ------------------------------------------------------------ MLP mega ------
// out = x + fc2(gelu(fc1(LN(x)))), x bf16. 64 rows/block, 4 waves, 1024
// blocks, 64KB LDS -> 2 blocks/CU (R8 geometry: TLP won over halved weight
// traffic in R8/R9 A/B). Weight frags double-buffered in regs (wA/wB, ILP
// over ~200cyc L2 latency) + setprio(1) around MFMA clusters (T5: waves are
// phase-diverse between barriers). Direct f32 epilogue (no LDS bounce).
__global__ __launch_bounds__(256, 2) void mlp_mega(
    const u16* __restrict__ xb, const float* __restrict__ gw,
    const float* __restrict__ bw, const bf16x8* __restrict__ f1p,
    const bf16x8* __restrict__ f2p, const float* __restrict__ f1b,
    const float* __restrict__ f2b, float* __restrict__ out)
{
    __shared__ __align__(16) u16 Xl[64 * 256];   // 32 KB, swizzled
    __shared__ __align__(16) u16 Hl[64 * 256];   // 32 KB, swizzled
    const int t = threadIdx.x, lane = t & 63, w = t >> 6;
    const int g = lane >> 4, c = lane & 15;
    const int m0 = blockIdx.x * 64;

    // ---- LN inline: wave w handles rows w*16..+15 (bf16 in) ----
    {
        float4 gg = *(const float4*)(gw + lane * 4);
        float4 bb = *(const float4*)(bw + lane * 4);
        for (int it = 0; it < 16; it++) {
            int row = w * 16 + it;
            uint2 rv = *(const uint2*)(xb + (size_t)(m0 + row) * 256 + lane * 4);
            float v0 = bf2f((u16)rv.x), v1 = bf2f((u16)(rv.x >> 16));
            float v2 = bf2f((u16)rv.y), v3 = bf2f((u16)(rv.y >> 16));
            float s = v0 + v1 + v2 + v3;
            float q = v0 * v0 + v1 * v1 + v2 * v2 + v3 * v3;
            #pragma unroll
            for (int m = 1; m < 64; m <<= 1) {
                s += __shfl_xor(s, m, 64);
                q += __shfl_xor(q, m, 64);
            }
            float mean = s * (1.0f / 256.0f);
            float var  = q * (1.0f / 256.0f) - mean * mean;
            float rstd = rsqrtf(var + 1e-5f);
            float n0 = (v0 - mean) * rstd * gg.x + bb.x;
            float n1 = (v1 - mean) * rstd * gg.y + bb.y;
            float n2 = (v2 - mean) * rstd * gg.z + bb.z;
            float n3 = (v3 - mean) * rstd * gg.w + bb.w;
            uint2 pk = { pk2(n0, n1), pk2(n2, n3) };
            *(uint2*)((char*)Xl + row * 512 + (((lane >> 1) ^ (row & 7)) << 4)
                      + ((lane & 1) << 3)) = pk;
        }
    }
    __syncthreads();

    f32x4 acc2[4][4];
    #pragma unroll
    for (int i = 0; i < 4; i++)
        #pragma unroll
        for (int n = 0; n < 4; n++) acc2[i][n] = (f32x4){0, 0, 0, 0};

    #pragma unroll
    for (int hc = 0; hc < 4; hc++) {
        // ---- fc1: all 64 rows, wave's 64 cols of this 256-wide chunk ----
        f32x4 acc1[4][4];
        #pragma unroll
        for (int i = 0; i < 4; i++)
            #pragma unroll
            for (int n = 0; n < 4; n++) acc1[i][n] = (f32x4){0, 0, 0, 0};

        const bf16x8* f1base = f1p + (size_t)((hc * 16 + w * 4) * 8) * 64 + lane;
        bf16x8 wA[4], wB[4];
        #pragma unroll
        for (int n = 0; n < 4; n++) wA[n] = f1base[(n * 8 + 0) * 64];

#define FC1_STEP(WREG, ks_)                                                   \
        {                                                                     \
            bf16x8 af[4];                                                     \
            _Pragma("unroll")                                                 \
            for (int i = 0; i < 4; i++) {                                     \
                int row = i * 16 + c;                                         \
                af[i] = *(const bf16x8*)((char*)Xl + row * 512                \
                        + (((4 * (ks_) + g) ^ (row & 7)) << 4));              \
            }                                                                 \
            __builtin_amdgcn_s_setprio(1);                                    \
            _Pragma("unroll")                                                 \
            for (int i = 0; i < 4; i++)                                       \
                _Pragma("unroll")                                             \
                for (int n = 0; n < 4; n++)                                   \
                    acc1[i][n] = __builtin_amdgcn_mfma_f32_16x16x32_bf16(     \
                        WREG[n], af[i], acc1[i][n], 0, 0, 0);                 \
            __builtin_amdgcn_s_setprio(0);                                    \
        }

        #pragma unroll
        for (int ks = 0; ks < 8; ks += 2) {
            #pragma unroll
            for (int n = 0; n < 4; n++) wB[n] = f1base[(n * 8 + ks + 1) * 64];
            FC1_STEP(wA, ks)
            if (ks + 2 < 8) {
                #pragma unroll
                for (int n = 0; n < 4; n++) wA[n] = f1base[(n * 8 + ks + 2) * 64];
            }
            FC1_STEP(wB, ks + 1)
        }
#undef FC1_STEP

        // gelu + bias -> Hl (swizzled)
        #pragma unroll
        for (int i = 0; i < 4; i++) {
            int row = i * 16 + c;
            #pragma unroll
            for (int n = 0; n < 4; n++) {
                float4 b4 = *(const float4*)(f1b + hc * 256 + w * 64 + n * 16 + 4 * g);
                float h0 = gelu_t(acc1[i][n][0] + b4.x);
                float h1 = gelu_t(acc1[i][n][1] + b4.y);
                float h2 = gelu_t(acc1[i][n][2] + b4.z);
                float h3 = gelu_t(acc1[i][n][3] + b4.w);
                uint2 pk = { pk2(h0, h1), pk2(h2, h3) };
                int cq = 8 * w + 2 * n + (g >> 1);
                *(uint2*)((char*)Hl + row * 512 + (((cq ^ (row & 7)) << 4))
                          + ((g & 1) << 3)) = pk;
            }
        }
        __syncthreads();

        // ---- fc2: acc2 += h_chunk @ f2w_chunk ----
        const bf16x8* f2base = f2p + (size_t)((w * 4) * 32 + hc * 8) * 64 + lane;
        #pragma unroll
        for (int n = 0; n < 4; n++) wA[n] = f2base[(n * 32 + 0) * 64];

#define FC2_STEP(WREG, ks_)                                                   \
        {                                                                     \
            bf16x8 ah[4];                                                     \
            _Pragma("unroll")                                                 \
            for (int i = 0; i < 4; i++) {                                     \
                int row = i * 16 + c;                                         \
                ah[i] = *(const bf16x8*)((char*)Hl + row * 512                \
                        + (((4 * (ks_) + g) ^ (row & 7)) << 4));              \
            }                                                                 \
            __builtin_amdgcn_s_setprio(1);                                    \
            _Pragma("unroll")                                                 \
            for (int i = 0; i < 4; i++)                                       \
                _Pragma("unroll")                                             \
                for (int n = 0; n < 4; n++)                                   \
                    acc2[i][n] = __builtin_amdgcn_mfma_f32_16x16x32_bf16(     \
                        WREG[n], ah[i], acc2[i][n], 0, 0, 0);                 \
            __builtin_amdgcn_s_setprio(0);                                    \
        }

        #pragma unroll
        for (int ks = 0; ks < 8; ks += 2) {
            #pragma unroll
            for (int n = 0; n < 4; n++) wB[n] = f2base[(n * 32 + ks + 1) * 64];
            FC2_STEP(wA, ks)
            if (ks + 2 < 8) {
                #pragma unroll
                for (int n = 0; n < 4; n++) wA[n] = f2base[(n * 32 + ks + 2) * 64];
            }
            FC2_STEP(wB, ks + 1)
        }
#undef FC2_STEP
        __syncthreads();
    }

    // ---- direct epilogue: out = acc2 + f2b + x (bf16 resid), f32 stores ----
    #pragma unroll
    for (int i = 0; i < 4; i++) {
        int row = m0 + i * 16 + c;
        #pragma unroll
        for (int n = 0; n < 4; n++) {
            int col = w * 64 + n * 16 + 4 * g;
            float4 b4 = *(const float4*)(f2b + col);
            uint2 rr = *(const uint2*)(xb + (size_t)row * 256 + col);
            float4 ov = { acc2[i][n][0] + b4.x + bf2f((u16)rr.x),
                          acc2[i][n][1] + b4.y + bf2f((u16)(rr.x >> 16)),
                          acc2[i][n][2] + b4.z + bf2f((u16)rr.y),
                          acc2[i][n][3] + b4.w + bf2f((u16)(rr.y >> 16)) };
            *(float4*)(out + (size_t)row * 256 + col) = ov;
        }
    }
}

// -------------------------------------------------------------- launch ------
// Workspace (peak ~137 MB):
//   [0,       2.10M)  weights: qwt kvwt pwt f1p f2p biasF
//   [2.10M,  35.65M)  x1w -> attn (after Q gemm)
//   [35.65M, 69.21M)  x2w
//   [69.21M,136.31M)  Qb -> xbw bf16 (after attn)
//   [102.76M,169.87M) KVb
extern "C" void kernel_launch(void* const* d_in, const int* in_sizes, int n_in,
                              void* d_out, int out_size, void* d_ws, size_t ws_size,
                              hipStream_t stream)
{
    const float* x1  = (const float*)d_in[0];
    const float* x2  = (const float*)d_in[1];
    const float* n1g = (const float*)d_in[2];
    const float* n1b = (const float*)d_in[3];
    const float* q_w = (const float*)d_in[4];
    const float* q_b = (const float*)d_in[5];
    const float* kv_w= (const float*)d_in[6];
    const float* kv_b= (const float*)d_in[7];
    const float* p_w = (const float*)d_in[8];
    const float* p_b = (const float*)d_in[9];
    const float* rel = (const float*)d_in[10];
    const float* n3g = (const float*)d_in[11];
    const float* n3b = (const float*)d_in[12];
    const float* f1w = (const float*)d_in[13];
    const float* f1b = (const float*)d_in[14];
    const float* f2w = (const float*)d_in[15];
    const float* f2b = (const float*)d_in[16];

    char* ws = (char*)d_ws;
    u16*   qwt   = (u16*)(ws + 0);
    u16*   kvwt  = (u16*)(ws + 131072);
    u16*   pwt   = (u16*)(ws + 393216);
    u16*   f1p   = (u16*)(ws + 524288);
    u16*   f2p   = (u16*)(ws + 1048576);
    float* biasF = (float*)(ws + 1572864);

    u16*   x1w  = (u16*)(ws + 2097152);
    u16*   x2w  = (u16*)(ws + 35651584);
    u16*   Qb   = (u16*)(ws + 69206016);
    u16*   KVb  = (u16*)(ws + 102760448);
    u16*   attn = (u16*)(ws + 2097152);     // overlays x1w (dead after Q gemm)
    u16*   xbw  = (u16*)(ws + 69206016);    // bf16 x, overlays Qb (dead after attn)

    float* out = (float*)d_out;

    prep_k<<<3200, 256, 0, stream>>>(q_w, kv_w, p_w, f1w, f2w, rel,
                                     qwt, kvwt, pwt, f1p, f2p, biasF);
    ln_k<<<32768, 256, 0, stream>>>(x1, x2, n1g, n1b, x1w, x2w);
    gemm_k<256, 256, 0><<<dim3(512, 2), 256, 0, stream>>>(x1w, qwt, q_b, Qb, nullptr);
    gemm_k<512, 256, 0><<<dim3(512, 4), 256, 0, stream>>>(x2w, kvwt, kv_b, KVb, nullptr);
    attn_k<<<2048, 256, 0, stream>>>(Qb, KVb, biasF, attn);
    gemm_k<256, 256, 2><<<dim3(512, 2), 256, 0, stream>>>(attn, pwt, p_b, xbw, x1);
    mlp_mega<<<1024, 256, 0, stream>>>(xbw, n3g, n3b, (const bf16x8*)f1p,
                                       (const bf16x8*)f2p, f1b, f2b, out);
}

// Round 11
// 300.839 us; speedup vs baseline: 1.1069x; 1.0216x over previous
//
#include <hip/hip_runtime.h>

typedef __bf16 bf16x8 __attribute__((ext_vector_type(8)));
typedef float f32x4 __attribute__((ext_vector_type(4)));
using u16 = unsigned short;

#define SCALE 0.17677669529663689f  // 32^-0.5

// Direct HBM->LDS DMA, 16B per lane (dest linear: base + lane*16).
#define GLOAD16(lp, gp)                                                        \
    __builtin_amdgcn_global_load_lds(                                          \
        (const __attribute__((address_space(1))) void*)(gp),                   \
        (__attribute__((address_space(3))) void*)(lp), 16, 0, 0)

__device__ __forceinline__ u16 f2bf(float f) {
    union { float f; unsigned u; } x; x.f = f;
    unsigned r = x.u + 0x7fffu + ((x.u >> 16) & 1u);
    return (u16)(r >> 16);
}
__device__ __forceinline__ unsigned pk2(float a, float b) {
    return (unsigned)f2bf(a) | ((unsigned)f2bf(b) << 16);
}
__device__ __forceinline__ float bf2f(u16 h) {
    union { unsigned u; float f; } x; x.u = ((unsigned)h) << 16; return x.f;
}
// gelu = x * sigmoid(1.5957691*(x + 0.044715 x^3))  (tanh-form identity)
__device__ __forceinline__ float gelu_s(float x) {
    float u = 1.5957691216057308f * x * (1.f + 0.044715f * x * x);
    float e = __expf(-u);
    return x / (1.f + e);
}

// ---------------------------------------------------------------- prep ------
// qwt/kvwt/pwt: Wt[N][K] bf16 (for gemm_k). f1p/f2p: fragment-packed bf16
// (frag (ng,ks): lane l holds W[k=32ks+8(l>>4)+e][n=16ng+(l&15)]).
// biasF: rel-pos bias in swapped C-frag layout.
__global__ __launch_bounds__(256) void prep_k(
    const float* __restrict__ q_w, const float* __restrict__ kv_w,
    const float* __restrict__ p_w, const float* __restrict__ f1w,
    const float* __restrict__ f2w, const float* __restrict__ rel,
    u16* __restrict__ qwt, u16* __restrict__ kvwt, u16* __restrict__ pwt,
    u16* __restrict__ f1p, u16* __restrict__ f2p, float* __restrict__ biasF)
{
    int t = blockIdx.x * 256 + threadIdx.x;
    if (t < 65536) {                                   // q_w  256x256
        int k = t & 255, n = t >> 8;
        qwt[t] = f2bf(q_w[k * 256 + n]);
    } else if (t < 196608) {                           // kv_w 256x512
        int u = t - 65536; int k = u & 255, n = u >> 8;
        kvwt[u] = f2bf(kv_w[k * 512 + n]);
    } else if (t < 262144) {                           // proj_w 256x256
        int u = t - 196608; int k = u & 255, n = u >> 8;
        pwt[u] = f2bf(p_w[k * 256 + n]);
    } else if (t < 524288) {                           // f1p packed frags
        int u = t - 262144;
        int e = u & 7, l = (u >> 3) & 63, ks = (u >> 9) & 7, ng = u >> 12;
        int k = ks * 32 + (l >> 4) * 8 + e;
        int n = ng * 16 + (l & 15);
        f1p[u] = f2bf(f1w[k * 1024 + n]);
    } else if (t < 786432) {                           // f2p packed frags
        int u = t - 524288;
        int e = u & 7, l = (u >> 3) & 63, ks = (u >> 9) & 31, ng = u >> 14;
        int k = ks * 32 + (l >> 4) * 8 + e;
        int n = ng * 16 + (l & 15);
        f2p[u] = f2bf(f2w[k * 256 + n]);
    } else if (t < 819200) {                           // biasF 8*16*64*4
        int u = t - 786432;
        int r = u & 3, l = (u >> 2) & 63, fr = (u >> 8) & 15, h = u >> 12;
        int fi = fr >> 2, fj = fr & 3;
        int m = fi * 16 + (l & 15);
        int n = fj * 16 + 4 * (l >> 4) + r;
        int idx = ((m >> 3) - (n >> 3) + 7) * 15 + ((m & 7) - (n & 7) + 7);
        biasF[u] = rel[idx * 8 + h];
    }
}

// ----------------------------------------------------------- layernorm ------
// One wave per 256-elem row; two streams + window-partition permute.
__global__ __launch_bounds__(256) void ln_k(
    const float* __restrict__ xa, const float* __restrict__ xb,
    const float* __restrict__ gw, const float* __restrict__ bw,
    u16* __restrict__ oa, u16* __restrict__ ob)
{
    int lane = threadIdx.x & 63, wid = threadIdx.x >> 6;
    int r = blockIdx.x * 4 + wid;
    const float* src; u16* dst; int row;
    if (r < 65536) { src = xa; dst = oa; row = r; }
    else           { src = xb; dst = ob; row = r - 65536; }

    float4 v = *(const float4*)(src + (size_t)row * 256 + lane * 4);
    float s = v.x + v.y + v.z + v.w;
    float q = v.x * v.x + v.y * v.y + v.z * v.z + v.w * v.w;
    #pragma unroll
    for (int m = 1; m < 64; m <<= 1) {
        s += __shfl_xor(s, m, 64);
        q += __shfl_xor(q, m, 64);
    }
    float mean = s * (1.0f / 256.0f);
    float var  = q * (1.0f / 256.0f) - mean * mean;
    float rstd = rsqrtf(var + 1e-5f);
    float4 gg = *(const float4*)(gw + lane * 4);
    float4 bb = *(const float4*)(bw + lane * 4);

    int b_ = row >> 12, l = row & 4095;
    int hh = l >> 6, ww = l & 63;
    int wi = (hh >> 3) * 8 + (ww >> 3);
    int n  = (hh & 7) * 8 + (ww & 7);
    int orow = b_ * 4096 + wi * 64 + n;

    ushort4 o;
    o.x = f2bf((v.x - mean) * rstd * gg.x + bb.x);
    o.y = f2bf((v.y - mean) * rstd * gg.y + bb.y);
    o.z = f2bf((v.z - mean) * rstd * gg.z + bb.z);
    o.w = f2bf((v.w - mean) * rstd * gg.w + bb.w);
    *(ushort4*)(dst + (size_t)orow * 256 + lane * 4) = o;
}

// ---------------------------------------------------------------- GEMM ------
// 128x128 tile, BK=64, 2-phase dbuf global_load_lds, swapped mfma(B,A) ->
// wide stores. EPI: 0 bf16 out, 2 proj(+window-rev+resid) -> bf16.
template <int NCOLS, int KD, int EPI>
__global__ __launch_bounds__(256) void gemm_k(
    const u16* __restrict__ A, const u16* __restrict__ Bt,
    const float* __restrict__ bias, u16* __restrict__ obf,
    const float* __restrict__ res)
{
    __shared__ __align__(16) u16 As[2][128 * 64];
    __shared__ __align__(16) u16 Bs[2][128 * 64];
    const int t = threadIdx.x;
    const int lane = t & 63, w = t >> 6;
    const int wm = w >> 1, wn = w & 1;
    const int g = lane >> 4, c = lane & 15;
    const int bm = blockIdx.x * 128;
    const int bn = blockIdx.y * 128;
    const int r_in = lane >> 3;
    const int slot = lane & 7;
    const int gch  = slot ^ r_in;

    const u16* Ab = A  + (size_t)bm * KD + gch * 8;
    const u16* Bb = Bt + (size_t)bn * KD + gch * 8;

    f32x4 acc[4][4];
    #pragma unroll
    for (int i = 0; i < 4; i++)
        #pragma unroll
        for (int j = 0; j < 4; j++) acc[i][j] = (f32x4){0.f, 0.f, 0.f, 0.f};

#define STAGE(buf, k0)                                                        \
    {                                                                         \
        _Pragma("unroll")                                                     \
        for (int i_ = 0; i_ < 4; i_++) {                                      \
            const int rowbase = w * 32 + i_ * 8;                              \
            GLOAD16(&As[buf][rowbase * 64],                                   \
                    Ab + (size_t)(rowbase + r_in) * KD + (k0));               \
            GLOAD16(&Bs[buf][rowbase * 64],                                   \
                    Bb + (size_t)(rowbase + r_in) * KD + (k0));               \
        }                                                                     \
    }

#define COMPUTE(buf)                                                          \
    {                                                                         \
        _Pragma("unroll")                                                     \
        for (int kk = 0; kk < 2; kk++) {                                      \
            bf16x8 af[4], bfr[4];                                             \
            _Pragma("unroll")                                                 \
            for (int i_ = 0; i_ < 4; i_++) {                                  \
                int ra = wm * 64 + i_ * 16 + c;                               \
                af[i_]  = *(const bf16x8*)(&As[buf][ra * 64 + ((kk * 4 + g) ^ (ra & 7)) * 8]); \
                int rb = wn * 64 + i_ * 16 + c;                               \
                bfr[i_] = *(const bf16x8*)(&Bs[buf][rb * 64 + ((kk * 4 + g) ^ (rb & 7)) * 8]); \
            }                                                                 \
            _Pragma("unroll")                                                 \
            for (int i_ = 0; i_ < 4; i_++)                                    \
                _Pragma("unroll")                                             \
                for (int j_ = 0; j_ < 4; j_++)                                \
                    acc[i_][j_] = __builtin_amdgcn_mfma_f32_16x16x32_bf16(    \
                        bfr[j_], af[i_], acc[i_][j_], 0, 0, 0);               \
        }                                                                     \
    }

    STAGE(0, 0);
    __syncthreads();
    for (int k0 = 0; k0 < KD; k0 += 128) {
        STAGE(1, k0 + 64);
        COMPUTE(0);
        __syncthreads();
        if (k0 + 128 < KD) STAGE(0, k0 + 128);
        COMPUTE(1);
        if (k0 + 128 < KD) __syncthreads();
    }
#undef STAGE
#undef COMPUTE

    #pragma unroll
    for (int i = 0; i < 4; i++) {
        int row = bm + wm * 64 + i * 16 + c;
        #pragma unroll
        for (int j = 0; j < 4; j++) {
            int col = bn + wn * 64 + j * 16 + 4 * g;
            float4 b4 = *(const float4*)(bias + col);
            float v0 = acc[i][j][0] + b4.x;
            float v1 = acc[i][j][1] + b4.y;
            float v2 = acc[i][j][2] + b4.z;
            float v3 = acc[i][j][3] + b4.w;
            if constexpr (EPI == 0) {
                uint2 pk = { pk2(v0, v1), pk2(v2, v3) };
                *(uint2*)(obf + (size_t)row * NCOLS + col) = pk;
            } else {  // proj: window-reverse + residual(f32) -> bf16 x
                int b_ = row >> 12, wi = (row >> 6) & 63, n = row & 63;
                int hh = (wi >> 3) * 8 + (n >> 3);
                int ww = (wi & 7) * 8 + (n & 7);
                size_t nrow = (size_t)b_ * 4096 + hh * 64 + ww;
                float4 r4 = *(const float4*)(res + nrow * 256 + col);
                uint2 pk = { pk2(v0 + r4.x, v1 + r4.y), pk2(v2 + r4.z, v3 + r4.w) };
                *(uint2*)(obf + nrow * 256 + col) = pk;
            }
        }
    }
}

// ----------------------------------------------------------- attention ------
__global__ __launch_bounds__(256) void attn_k(
    const u16* __restrict__ Q, const u16* __restrict__ KV,
    const float* __restrict__ biasF, u16* __restrict__ O)
{
    __shared__ __align__(16) u16 Pl[4][64 * 64];
    __shared__ __align__(16) u16 Vt[4][32 * 80];
    const int t = threadIdx.x, lane = t & 63, w = t >> 6;
    const int g = lane >> 4, c = lane & 15;
    const int pair = blockIdx.x * 4 + w;
    const int win = pair >> 3, head = pair & 7;
    const size_t qbase  = (size_t)win * 64 * 256 + head * 32;
    const size_t kvbase = (size_t)win * 64 * 512 + head * 32;

    u16* vt = &Vt[w][0];
    {
        const u16* vp = KV + kvbase + 256 + (size_t)lane * 512;
        uint4 v0 = *(const uint4*)(vp);
        uint4 v1 = *(const uint4*)(vp + 8);
        uint4 v2 = *(const uint4*)(vp + 16);
        uint4 v3 = *(const uint4*)(vp + 24);
#define SCAT(vv, dbase)                                           \
        vt[(dbase + 0) * 80 + lane] = (u16)(vv.x);                \
        vt[(dbase + 1) * 80 + lane] = (u16)(vv.x >> 16);          \
        vt[(dbase + 2) * 80 + lane] = (u16)(vv.y);                \
        vt[(dbase + 3) * 80 + lane] = (u16)(vv.y >> 16);          \
        vt[(dbase + 4) * 80 + lane] = (u16)(vv.z);                \
        vt[(dbase + 5) * 80 + lane] = (u16)(vv.z >> 16);          \
        vt[(dbase + 6) * 80 + lane] = (u16)(vv.w);                \
        vt[(dbase + 7) * 80 + lane] = (u16)(vv.w >> 16);
        SCAT(v0, 0) SCAT(v1, 8) SCAT(v2, 16) SCAT(v3, 24)
#undef SCAT
    }

    bf16x8 qf[4], kf[4];
    #pragma unroll
    for (int i = 0; i < 4; i++) {
        qf[i] = *(const bf16x8*)(Q  + qbase  + (size_t)(i * 16 + c) * 256 + 8 * g);
        kf[i] = *(const bf16x8*)(KV + kvbase + (size_t)(i * 16 + c) * 512 + 8 * g);
    }
    f32x4 s[4][4];
    #pragma unroll
    for (int i = 0; i < 4; i++)
        #pragma unroll
        for (int j = 0; j < 4; j++) {
            s[i][j] = (f32x4){0.f, 0.f, 0.f, 0.f};
            s[i][j] = __builtin_amdgcn_mfma_f32_16x16x32_bf16(kf[j], qf[i], s[i][j], 0, 0, 0);
        }

    #pragma unroll
    for (int i = 0; i < 4; i++)
        #pragma unroll
        for (int j = 0; j < 4; j++) {
            f32x4 bf4 = *(const f32x4*)(biasF + ((size_t)(head * 16 + i * 4 + j) * 64 + lane) * 4);
            #pragma unroll
            for (int r = 0; r < 4; r++) s[i][j][r] = s[i][j][r] * SCALE + bf4[r];
        }

    #pragma unroll
    for (int i = 0; i < 4; i++) {
        float mx = -1e30f;
        #pragma unroll
        for (int j = 0; j < 4; j++)
            #pragma unroll
            for (int r = 0; r < 4; r++) mx = fmaxf(mx, s[i][j][r]);
        mx = fmaxf(mx, __shfl_xor(mx, 16, 64));
        mx = fmaxf(mx, __shfl_xor(mx, 32, 64));
        float sum = 0.f;
        #pragma unroll
        for (int j = 0; j < 4; j++)
            #pragma unroll
            for (int r = 0; r < 4; r++) {
                float e = __expf(s[i][j][r] - mx);
                s[i][j][r] = e; sum += e;
            }
        sum += __shfl_xor(sum, 16, 64);
        sum += __shfl_xor(sum, 32, 64);
        float inv = 1.f / sum;
        #pragma unroll
        for (int j = 0; j < 4; j++)
            #pragma unroll
            for (int r = 0; r < 4; r++) s[i][j][r] *= inv;
    }

    u16* pl = &Pl[w][0];
    #pragma unroll
    for (int i = 0; i < 4; i++) {
        int m = i * 16 + c;
        #pragma unroll
        for (int j = 0; j < 4; j++) {
            int kbyte = 32 * j + 8 * g;
            uint2 pk = { pk2(s[i][j][0], s[i][j][1]), pk2(s[i][j][2], s[i][j][3]) };
            *(uint2*)((char*)pl + m * 128 + (kbyte ^ ((m & 7) << 4))) = pk;
        }
    }

    f32x4 o[4][2];
    #pragma unroll
    for (int i = 0; i < 4; i++) { o[i][0] = (f32x4){0,0,0,0}; o[i][1] = (f32x4){0,0,0,0}; }
    #pragma unroll
    for (int ks = 0; ks < 2; ks++) {
        bf16x8 pa[4], vb[2];
        #pragma unroll
        for (int i = 0; i < 4; i++) {
            int row = i * 16 + c;
            int ch = (ks * 4 + g) ^ (row & 7);
            pa[i] = *(const bf16x8*)((char*)pl + row * 128 + ch * 16);
        }
        #pragma unroll
        for (int j = 0; j < 2; j++) {
            int d = j * 16 + c;
            vb[j] = *(const bf16x8*)(vt + d * 80 + ks * 32 + 8 * g);
        }
        #pragma unroll
        for (int i = 0; i < 4; i++)
            #pragma unroll
            for (int j = 0; j < 2; j++)
                o[i][j] = __builtin_amdgcn_mfma_f32_16x16x32_bf16(vb[j], pa[i], o[i][j], 0, 0, 0);
    }

    #pragma unroll
    for (int i = 0; i < 4; i++) {
        size_t row = (size_t)win * 64 + i * 16 + c;
        #pragma unroll
        for (int j = 0; j < 2; j++) {
            int col = head * 32 + j * 16 + 4 * g;
            uint2 pk = { pk2(o[i][j][0], o[i][j][1]), pk2(o[i][j][2], o[i][j][3]) };
            *(uint2*)(O + row * 256 + col) = pk;
        }
    }
}

// ------------------------------------------------------------ MLP mega ------
// out = x + fc2(gelu(fc1(LN(x)))), x bf16. 64 rows/block, 8 WAVES (512 thr),
// 1024 blocks, 64KB LDS -> 2 blocks/CU = 16 waves/CU = 4 waves/SIMD
// (launch_bounds(512,4) keeps VGPR<=128). Wave owns a 32-col slice of each
// hidden chunk and of the output -> half the per-wave VALU; 2x the TLP so
// VALU(LN/gelu) overlaps MFMA across waves. Direct f32 epilogue.
__global__ __launch_bounds__(512, 4) void mlp_mega(
    const u16* __restrict__ xb, const float* __restrict__ gw,
    const float* __restrict__ bw, const bf16x8* __restrict__ f1p,
    const bf16x8* __restrict__ f2p, const float* __restrict__ f1b,
    const float* __restrict__ f2b, float* __restrict__ out)
{
    __shared__ __align__(16) u16 Xl[64 * 256];   // 32 KB, swizzled
    __shared__ __align__(16) u16 Hl[64 * 256];   // 32 KB, swizzled
    const int t = threadIdx.x, lane = t & 63, w = t >> 6;   // w in 0..7
    const int g = lane >> 4, c = lane & 15;
    const int m0 = blockIdx.x * 64;

    // ---- LN inline: wave w handles rows w*8..+7 (bf16 in) ----
    {
        float4 gg = *(const float4*)(gw + lane * 4);
        float4 bb = *(const float4*)(bw + lane * 4);
        for (int it = 0; it < 8; it++) {
            int row = w * 8 + it;
            uint2 rv = *(const uint2*)(xb + (size_t)(m0 + row) * 256 + lane * 4);
            float v0 = bf2f((u16)rv.x), v1 = bf2f((u16)(rv.x >> 16));
            float v2 = bf2f((u16)rv.y), v3 = bf2f((u16)(rv.y >> 16));
            float s = v0 + v1 + v2 + v3;
            float q = v0 * v0 + v1 * v1 + v2 * v2 + v3 * v3;
            #pragma unroll
            for (int m = 1; m < 64; m <<= 1) {
                s += __shfl_xor(s, m, 64);
                q += __shfl_xor(q, m, 64);
            }
            float mean = s * (1.0f / 256.0f);
            float var  = q * (1.0f / 256.0f) - mean * mean;
            float rstd = rsqrtf(var + 1e-5f);
            float n0 = (v0 - mean) * rstd * gg.x + bb.x;
            float n1 = (v1 - mean) * rstd * gg.y + bb.y;
            float n2 = (v2 - mean) * rstd * gg.z + bb.z;
            float n3 = (v3 - mean) * rstd * gg.w + bb.w;
            uint2 pk = { pk2(n0, n1), pk2(n2, n3) };
            *(uint2*)((char*)Xl + row * 512 + (((lane >> 1) ^ (row & 7)) << 4)
                      + ((lane & 1) << 3)) = pk;
        }
    }
    __syncthreads();

    f32x4 acc2[4][2];
    #pragma unroll
    for (int i = 0; i < 4; i++) { acc2[i][0] = (f32x4){0,0,0,0}; acc2[i][1] = (f32x4){0,0,0,0}; }

    #pragma unroll
    for (int hc = 0; hc < 4; hc++) {
        // ---- fc1: all 64 rows, wave's 32 cols of this 256-wide chunk ----
        f32x4 acc1[4][2];
        #pragma unroll
        for (int i = 0; i < 4; i++) { acc1[i][0] = (f32x4){0,0,0,0}; acc1[i][1] = (f32x4){0,0,0,0}; }

        #pragma unroll
        for (int ks = 0; ks < 8; ks++) {
            bf16x8 wf[2], af[4];
            #pragma unroll
            for (int n = 0; n < 2; n++)
                wf[n] = f1p[(size_t)((hc * 16 + w * 2 + n) * 8 + ks) * 64 + lane];
            #pragma unroll
            for (int i = 0; i < 4; i++) {
                int row = i * 16 + c;
                af[i] = *(const bf16x8*)((char*)Xl + row * 512
                                         + (((4 * ks + g) ^ (row & 7)) << 4));
            }
            __builtin_amdgcn_s_setprio(1);
            #pragma unroll
            for (int i = 0; i < 4; i++)
                #pragma unroll
                for (int n = 0; n < 2; n++)
                    acc1[i][n] = __builtin_amdgcn_mfma_f32_16x16x32_bf16(
                        wf[n], af[i], acc1[i][n], 0, 0, 0);
            __builtin_amdgcn_s_setprio(0);
        }

        // gelu + bias -> Hl (swizzled)
        #pragma unroll
        for (int i = 0; i < 4; i++) {
            int row = i * 16 + c;
            #pragma unroll
            for (int n = 0; n < 2; n++) {
                float4 b4 = *(const float4*)(f1b + hc * 256 + w * 32 + n * 16 + 4 * g);
                float h0 = gelu_s(acc1[i][n][0] + b4.x);
                float h1 = gelu_s(acc1[i][n][1] + b4.y);
                float h2 = gelu_s(acc1[i][n][2] + b4.z);
                float h3 = gelu_s(acc1[i][n][3] + b4.w);
                uint2 pk = { pk2(h0, h1), pk2(h2, h3) };
                int cq = 4 * w + 2 * n + (g >> 1);
                *(uint2*)((char*)Hl + row * 512 + (((cq ^ (row & 7)) << 4))
                          + ((g & 1) << 3)) = pk;
            }
        }
        __syncthreads();

        // ---- fc2: acc2 += h_chunk @ f2w_chunk (wave's 32 out cols) ----
        #pragma unroll
        for (int ks = 0; ks < 8; ks++) {
            bf16x8 wf[2], ah[4];
            #pragma unroll
            for (int n = 0; n < 2; n++)
                wf[n] = f2p[(size_t)((w * 2 + n) * 32 + hc * 8 + ks) * 64 + lane];
            #pragma unroll
            for (int i = 0; i < 4; i++) {
                int row = i * 16 + c;
                ah[i] = *(const bf16x8*)((char*)Hl + row * 512
                                         + (((4 * ks + g) ^ (row & 7)) << 4));
            }
            __builtin_amdgcn_s_setprio(1);
            #pragma unroll
            for (int i = 0; i < 4; i++)
                #pragma unroll
                for (int n = 0; n < 2; n++)
                    acc2[i][n] = __builtin_amdgcn_mfma_f32_16x16x32_bf16(
                        wf[n], ah[i], acc2[i][n], 0, 0, 0);
            __builtin_amdgcn_s_setprio(0);
        }
        __syncthreads();
    }

    // ---- direct epilogue: out = acc2 + f2b + x (bf16 resid), f32 stores ----
    #pragma unroll
    for (int i = 0; i < 4; i++) {
        int row = m0 + i * 16 + c;
        #pragma unroll
        for (int n = 0; n < 2; n++) {
            int col = w * 32 + n * 16 + 4 * g;
            float4 b4 = *(const float4*)(f2b + col);
            uint2 rr = *(const uint2*)(xb + (size_t)row * 256 + col);
            float4 ov = { acc2[i][n][0] + b4.x + bf2f((u16)rr.x),
                          acc2[i][n][1] + b4.y + bf2f((u16)(rr.x >> 16)),
                          acc2[i][n][2] + b4.z + bf2f((u16)rr.y),
                          acc2[i][n][3] + b4.w + bf2f((u16)(rr.y >> 16)) };
            *(float4*)(out + (size_t)row * 256 + col) = ov;
        }
    }
}

// -------------------------------------------------------------- launch ------
// Workspace (peak ~137 MB):
//   [0,       2.10M)  weights: qwt kvwt pwt f1p f2p biasF
//   [2.10M,  35.65M)  x1w -> attn (after Q gemm)
//   [35.65M, 69.21M)  x2w
//   [69.21M,136.31M)  Qb -> xbw bf16 (after attn)
//   [102.76M,169.87M) KVb
extern "C" void kernel_launch(void* const* d_in, const int* in_sizes, int n_in,
                              void* d_out, int out_size, void* d_ws, size_t ws_size,
                              hipStream_t stream)
{
    const float* x1  = (const float*)d_in[0];
    const float* x2  = (const float*)d_in[1];
    const float* n1g = (const float*)d_in[2];
    const float* n1b = (const float*)d_in[3];
    const float* q_w = (const float*)d_in[4];
    const float* q_b = (const float*)d_in[5];
    const float* kv_w= (const float*)d_in[6];
    const float* kv_b= (const float*)d_in[7];
    const float* p_w = (const float*)d_in[8];
    const float* p_b = (const float*)d_in[9];
    const float* rel = (const float*)d_in[10];
    const float* n3g = (const float*)d_in[11];
    const float* n3b = (const float*)d_in[12];
    const float* f1w = (const float*)d_in[13];
    const float* f1b = (const float*)d_in[14];
    const float* f2w = (const float*)d_in[15];
    const float* f2b = (const float*)d_in[16];

    char* ws = (char*)d_ws;
    u16*   qwt   = (u16*)(ws + 0);
    u16*   kvwt  = (u16*)(ws + 131072);
    u16*   pwt   = (u16*)(ws + 393216);
    u16*   f1p   = (u16*)(ws + 524288);
    u16*   f2p   = (u16*)(ws + 1048576);
    float* biasF = (float*)(ws + 1572864);

    u16*   x1w  = (u16*)(ws + 2097152);
    u16*   x2w  = (u16*)(ws + 35651584);
    u16*   Qb   = (u16*)(ws + 69206016);
    u16*   KVb  = (u16*)(ws + 102760448);
    u16*   attn = (u16*)(ws + 2097152);     // overlays x1w (dead after Q gemm)
    u16*   xbw  = (u16*)(ws + 69206016);    // bf16 x, overlays Qb (dead after attn)

    float* out = (float*)d_out;

    prep_k<<<3200, 256, 0, stream>>>(q_w, kv_w, p_w, f1w, f2w, rel,
                                     qwt, kvwt, pwt, f1p, f2p, biasF);
    ln_k<<<32768, 256, 0, stream>>>(x1, x2, n1g, n1b, x1w, x2w);
    gemm_k<256, 256, 0><<<dim3(512, 2), 256, 0, stream>>>(x1w, qwt, q_b, Qb, nullptr);
    gemm_k<512, 256, 0><<<dim3(512, 4), 256, 0, stream>>>(x2w, kvwt, kv_b, KVb, nullptr);
    attn_k<<<2048, 256, 0, stream>>>(Qb, KVb, biasF, attn);
    gemm_k<256, 256, 2><<<dim3(512, 2), 256, 0, stream>>>(attn, pwt, p_b, xbw, x1);
    mlp_mega<<<1024, 512, 0, stream>>>(xbw, n3g, n3b, (const bf16x8*)f1p,
                                       (const bf16x8*)f2p, f1b, f2b, out);
}

// Round 12
// 298.944 us; speedup vs baseline: 1.1139x; 1.0063x over previous
//
#include <hip/hip_runtime.h>

typedef __bf16 bf16x8 __attribute__((ext_vector_type(8)));
typedef float f32x4 __attribute__((ext_vector_type(4)));
using u16 = unsigned short;

#define SCALE 0.17677669529663689f  // 32^-0.5

// Direct HBM->LDS DMA, 16B per lane (dest linear: base + lane*16).
#define GLOAD16(lp, gp)                                                        \
    __builtin_amdgcn_global_load_lds(                                          \
        (const __attribute__((address_space(1))) void*)(gp),                   \
        (__attribute__((address_space(3))) void*)(lp), 16, 0, 0)

__device__ __forceinline__ u16 f2bf(float f) {
    union { float f; unsigned u; } x; x.f = f;
    unsigned r = x.u + 0x7fffu + ((x.u >> 16) & 1u);
    return (u16)(r >> 16);
}
__device__ __forceinline__ unsigned pk2(float a, float b) {
    return (unsigned)f2bf(a) | ((unsigned)f2bf(b) << 16);
}
__device__ __forceinline__ float bf2f(u16 h) {
    union { unsigned u; float f; } x; x.u = ((unsigned)h) << 16; return x.f;
}
// gelu = x * sigmoid(1.5957691*(x + 0.044715 x^3))  (tanh-form identity)
__device__ __forceinline__ float gelu_s(float x) {
    float u = 1.5957691216057308f * x * (1.f + 0.044715f * x * x);
    float e = __expf(-u);
    return x / (1.f + e);
}

// ---------------------------------------------------------------- prep ------
// qwt/kvwt/pwt: Wt[N][K] bf16 (for gemm_k). f1p/f2p: fragment-packed bf16
// (frag (ng,ks): lane l holds W[k=32ks+8(l>>4)+e][n=16ng+(l&15)]).
// biasF: rel-pos bias in swapped C-frag layout.
__global__ __launch_bounds__(256) void prep_k(
    const float* __restrict__ q_w, const float* __restrict__ kv_w,
    const float* __restrict__ p_w, const float* __restrict__ f1w,
    const float* __restrict__ f2w, const float* __restrict__ rel,
    u16* __restrict__ qwt, u16* __restrict__ kvwt, u16* __restrict__ pwt,
    u16* __restrict__ f1p, u16* __restrict__ f2p, float* __restrict__ biasF)
{
    int t = blockIdx.x * 256 + threadIdx.x;
    if (t < 65536) {                                   // q_w  256x256
        int k = t & 255, n = t >> 8;
        qwt[t] = f2bf(q_w[k * 256 + n]);
    } else if (t < 196608) {                           // kv_w 256x512
        int u = t - 65536; int k = u & 255, n = u >> 8;
        kvwt[u] = f2bf(kv_w[k * 512 + n]);
    } else if (t < 262144) {                           // proj_w 256x256
        int u = t - 196608; int k = u & 255, n = u >> 8;
        pwt[u] = f2bf(p_w[k * 256 + n]);
    } else if (t < 524288) {                           // f1p packed frags
        int u = t - 262144;
        int e = u & 7, l = (u >> 3) & 63, ks = (u >> 9) & 7, ng = u >> 12;
        int k = ks * 32 + (l >> 4) * 8 + e;
        int n = ng * 16 + (l & 15);
        f1p[u] = f2bf(f1w[k * 1024 + n]);
    } else if (t < 786432) {                           // f2p packed frags
        int u = t - 524288;
        int e = u & 7, l = (u >> 3) & 63, ks = (u >> 9) & 31, ng = u >> 14;
        int k = ks * 32 + (l >> 4) * 8 + e;
        int n = ng * 16 + (l & 15);
        f2p[u] = f2bf(f2w[k * 256 + n]);
    } else if (t < 819200) {                           // biasF 8*16*64*4
        int u = t - 786432;
        int r = u & 3, l = (u >> 2) & 63, fr = (u >> 8) & 15, h = u >> 12;
        int fi = fr >> 2, fj = fr & 3;
        int m = fi * 16 + (l & 15);
        int n = fj * 16 + 4 * (l >> 4) + r;
        int idx = ((m >> 3) - (n >> 3) + 7) * 15 + ((m & 7) - (n & 7) + 7);
        biasF[u] = rel[idx * 8 + h];
    }
}

// ----------------------------------------------------------- layernorm ------
// One wave per 256-elem row; two streams + window-partition permute.
__global__ __launch_bounds__(256) void ln_k(
    const float* __restrict__ xa, const float* __restrict__ xb,
    const float* __restrict__ gw, const float* __restrict__ bw,
    u16* __restrict__ oa, u16* __restrict__ ob)
{
    int lane = threadIdx.x & 63, wid = threadIdx.x >> 6;
    int r = blockIdx.x * 4 + wid;
    const float* src; u16* dst; int row;
    if (r < 65536) { src = xa; dst = oa; row = r; }
    else           { src = xb; dst = ob; row = r - 65536; }

    float4 v = *(const float4*)(src + (size_t)row * 256 + lane * 4);
    float s = v.x + v.y + v.z + v.w;
    float q = v.x * v.x + v.y * v.y + v.z * v.z + v.w * v.w;
    #pragma unroll
    for (int m = 1; m < 64; m <<= 1) {
        s += __shfl_xor(s, m, 64);
        q += __shfl_xor(q, m, 64);
    }
    float mean = s * (1.0f / 256.0f);
    float var  = q * (1.0f / 256.0f) - mean * mean;
    float rstd = rsqrtf(var + 1e-5f);
    float4 gg = *(const float4*)(gw + lane * 4);
    float4 bb = *(const float4*)(bw + lane * 4);

    int b_ = row >> 12, l = row & 4095;
    int hh = l >> 6, ww = l & 63;
    int wi = (hh >> 3) * 8 + (ww >> 3);
    int n  = (hh & 7) * 8 + (ww & 7);
    int orow = b_ * 4096 + wi * 64 + n;

    ushort4 o;
    o.x = f2bf((v.x - mean) * rstd * gg.x + bb.x);
    o.y = f2bf((v.y - mean) * rstd * gg.y + bb.y);
    o.z = f2bf((v.z - mean) * rstd * gg.z + bb.z);
    o.w = f2bf((v.w - mean) * rstd * gg.w + bb.w);
    *(ushort4*)(dst + (size_t)orow * 256 + lane * 4) = o;
}

// ---------------------------------------------------------------- GEMM ------
// 128x128 tile, BK=64, 2-phase dbuf global_load_lds, swapped mfma(B,A) ->
// wide stores. EPI: 0 bf16 out, 2 proj(+window-rev+resid) -> bf16.
template <int NCOLS, int KD, int EPI>
__global__ __launch_bounds__(256) void gemm_k(
    const u16* __restrict__ A, const u16* __restrict__ Bt,
    const float* __restrict__ bias, u16* __restrict__ obf,
    const float* __restrict__ res)
{
    __shared__ __align__(16) u16 As[2][128 * 64];
    __shared__ __align__(16) u16 Bs[2][128 * 64];
    const int t = threadIdx.x;
    const int lane = t & 63, w = t >> 6;
    const int wm = w >> 1, wn = w & 1;
    const int g = lane >> 4, c = lane & 15;
    const int bm = blockIdx.x * 128;
    const int bn = blockIdx.y * 128;
    const int r_in = lane >> 3;
    const int slot = lane & 7;
    const int gch  = slot ^ r_in;

    const u16* Ab = A  + (size_t)bm * KD + gch * 8;
    const u16* Bb = Bt + (size_t)bn * KD + gch * 8;

    f32x4 acc[4][4];
    #pragma unroll
    for (int i = 0; i < 4; i++)
        #pragma unroll
        for (int j = 0; j < 4; j++) acc[i][j] = (f32x4){0.f, 0.f, 0.f, 0.f};

#define STAGE(buf, k0)                                                        \
    {                                                                         \
        _Pragma("unroll")                                                     \
        for (int i_ = 0; i_ < 4; i_++) {                                      \
            const int rowbase = w * 32 + i_ * 8;                              \
            GLOAD16(&As[buf][rowbase * 64],                                   \
                    Ab + (size_t)(rowbase + r_in) * KD + (k0));               \
            GLOAD16(&Bs[buf][rowbase * 64],                                   \
                    Bb + (size_t)(rowbase + r_in) * KD + (k0));               \
        }                                                                     \
    }

#define COMPUTE(buf)                                                          \
    {                                                                         \
        _Pragma("unroll")                                                     \
        for (int kk = 0; kk < 2; kk++) {                                      \
            bf16x8 af[4], bfr[4];                                             \
            _Pragma("unroll")                                                 \
            for (int i_ = 0; i_ < 4; i_++) {                                  \
                int ra = wm * 64 + i_ * 16 + c;                               \
                af[i_]  = *(const bf16x8*)(&As[buf][ra * 64 + ((kk * 4 + g) ^ (ra & 7)) * 8]); \
                int rb = wn * 64 + i_ * 16 + c;                               \
                bfr[i_] = *(const bf16x8*)(&Bs[buf][rb * 64 + ((kk * 4 + g) ^ (rb & 7)) * 8]); \
            }                                                                 \
            _Pragma("unroll")                                                 \
            for (int i_ = 0; i_ < 4; i_++)                                    \
                _Pragma("unroll")                                             \
                for (int j_ = 0; j_ < 4; j_++)                                \
                    acc[i_][j_] = __builtin_amdgcn_mfma_f32_16x16x32_bf16(    \
                        bfr[j_], af[i_], acc[i_][j_], 0, 0, 0);               \
        }                                                                     \
    }

    STAGE(0, 0);
    __syncthreads();
    for (int k0 = 0; k0 < KD; k0 += 128) {
        STAGE(1, k0 + 64);
        COMPUTE(0);
        __syncthreads();
        if (k0 + 128 < KD) STAGE(0, k0 + 128);
        COMPUTE(1);
        if (k0 + 128 < KD) __syncthreads();
    }
#undef STAGE
#undef COMPUTE

    #pragma unroll
    for (int i = 0; i < 4; i++) {
        int row = bm + wm * 64 + i * 16 + c;
        #pragma unroll
        for (int j = 0; j < 4; j++) {
            int col = bn + wn * 64 + j * 16 + 4 * g;
            float4 b4 = *(const float4*)(bias + col);
            float v0 = acc[i][j][0] + b4.x;
            float v1 = acc[i][j][1] + b4.y;
            float v2 = acc[i][j][2] + b4.z;
            float v3 = acc[i][j][3] + b4.w;
            if constexpr (EPI == 0) {
                uint2 pk = { pk2(v0, v1), pk2(v2, v3) };
                *(uint2*)(obf + (size_t)row * NCOLS + col) = pk;
            } else {  // proj: window-reverse + residual(f32) -> bf16 x
                int b_ = row >> 12, wi = (row >> 6) & 63, n = row & 63;
                int hh = (wi >> 3) * 8 + (n >> 3);
                int ww = (wi & 7) * 8 + (n & 7);
                size_t nrow = (size_t)b_ * 4096 + hh * 64 + ww;
                float4 r4 = *(const float4*)(res + nrow * 256 + col);
                uint2 pk = { pk2(v0 + r4.x, v1 + r4.y), pk2(v2 + r4.z, v3 + r4.w) };
                *(uint2*)(obf + nrow * 256 + col) = pk;
            }
        }
    }
}

// ----------------------------------------------------------- attention ------
__global__ __launch_bounds__(256) void attn_k(
    const u16* __restrict__ Q, const u16* __restrict__ KV,
    const float* __restrict__ biasF, u16* __restrict__ O)
{
    __shared__ __align__(16) u16 Pl[4][64 * 64];
    __shared__ __align__(16) u16 Vt[4][32 * 80];
    const int t = threadIdx.x, lane = t & 63, w = t >> 6;
    const int g = lane >> 4, c = lane & 15;
    const int pair = blockIdx.x * 4 + w;
    const int win = pair >> 3, head = pair & 7;
    const size_t qbase  = (size_t)win * 64 * 256 + head * 32;
    const size_t kvbase = (size_t)win * 64 * 512 + head * 32;

    u16* vt = &Vt[w][0];
    {
        const u16* vp = KV + kvbase + 256 + (size_t)lane * 512;
        uint4 v0 = *(const uint4*)(vp);
        uint4 v1 = *(const uint4*)(vp + 8);
        uint4 v2 = *(const uint4*)(vp + 16);
        uint4 v3 = *(const uint4*)(vp + 24);
#define SCAT(vv, dbase)                                           \
        vt[(dbase + 0) * 80 + lane] = (u16)(vv.x);                \
        vt[(dbase + 1) * 80 + lane] = (u16)(vv.x >> 16);          \
        vt[(dbase + 2) * 80 + lane] = (u16)(vv.y);                \
        vt[(dbase + 3) * 80 + lane] = (u16)(vv.y >> 16);          \
        vt[(dbase + 4) * 80 + lane] = (u16)(vv.z);                \
        vt[(dbase + 5) * 80 + lane] = (u16)(vv.z >> 16);          \
        vt[(dbase + 6) * 80 + lane] = (u16)(vv.w);                \
        vt[(dbase + 7) * 80 + lane] = (u16)(vv.w >> 16);
        SCAT(v0, 0) SCAT(v1, 8) SCAT(v2, 16) SCAT(v3, 24)
#undef SCAT
    }

    bf16x8 qf[4], kf[4];
    #pragma unroll
    for (int i = 0; i < 4; i++) {
        qf[i] = *(const bf16x8*)(Q  + qbase  + (size_t)(i * 16 + c) * 256 + 8 * g);
        kf[i] = *(const bf16x8*)(KV + kvbase + (size_t)(i * 16 + c) * 512 + 8 * g);
    }
    f32x4 s[4][4];
    #pragma unroll
    for (int i = 0; i < 4; i++)
        #pragma unroll
        for (int j = 0; j < 4; j++) {
            s[i][j] = (f32x4){0.f, 0.f, 0.f, 0.f};
            s[i][j] = __builtin_amdgcn_mfma_f32_16x16x32_bf16(kf[j], qf[i], s[i][j], 0, 0, 0);
        }

    #pragma unroll
    for (int i = 0; i < 4; i++)
        #pragma unroll
        for (int j = 0; j < 4; j++) {
            f32x4 bf4 = *(const f32x4*)(biasF + ((size_t)(head * 16 + i * 4 + j) * 64 + lane) * 4);
            #pragma unroll
            for (int r = 0; r < 4; r++) s[i][j][r] = s[i][j][r] * SCALE + bf4[r];
        }

    #pragma unroll
    for (int i = 0; i < 4; i++) {
        float mx = -1e30f;
        #pragma unroll
        for (int j = 0; j < 4; j++)
            #pragma unroll
            for (int r = 0; r < 4; r++) mx = fmaxf(mx, s[i][j][r]);
        mx = fmaxf(mx, __shfl_xor(mx, 16, 64));
        mx = fmaxf(mx, __shfl_xor(mx, 32, 64));
        float sum = 0.f;
        #pragma unroll
        for (int j = 0; j < 4; j++)
            #pragma unroll
            for (int r = 0; r < 4; r++) {
                float e = __expf(s[i][j][r] - mx);
                s[i][j][r] = e; sum += e;
            }
        sum += __shfl_xor(sum, 16, 64);
        sum += __shfl_xor(sum, 32, 64);
        float inv = 1.f / sum;
        #pragma unroll
        for (int j = 0; j < 4; j++)
            #pragma unroll
            for (int r = 0; r < 4; r++) s[i][j][r] *= inv;
    }

    u16* pl = &Pl[w][0];
    #pragma unroll
    for (int i = 0; i < 4; i++) {
        int m = i * 16 + c;
        #pragma unroll
        for (int j = 0; j < 4; j++) {
            int kbyte = 32 * j + 8 * g;
            uint2 pk = { pk2(s[i][j][0], s[i][j][1]), pk2(s[i][j][2], s[i][j][3]) };
            *(uint2*)((char*)pl + m * 128 + (kbyte ^ ((m & 7) << 4))) = pk;
        }
    }

    f32x4 o[4][2];
    #pragma unroll
    for (int i = 0; i < 4; i++) { o[i][0] = (f32x4){0,0,0,0}; o[i][1] = (f32x4){0,0,0,0}; }
    #pragma unroll
    for (int ks = 0; ks < 2; ks++) {
        bf16x8 pa[4], vb[2];
        #pragma unroll
        for (int i = 0; i < 4; i++) {
            int row = i * 16 + c;
            int ch = (ks * 4 + g) ^ (row & 7);
            pa[i] = *(const bf16x8*)((char*)pl + row * 128 + ch * 16);
        }
        #pragma unroll
        for (int j = 0; j < 2; j++) {
            int d = j * 16 + c;
            vb[j] = *(const bf16x8*)(vt + d * 80 + ks * 32 + 8 * g);
        }
        #pragma unroll
        for (int i = 0; i < 4; i++)
            #pragma unroll
            for (int j = 0; j < 2; j++)
                o[i][j] = __builtin_amdgcn_mfma_f32_16x16x32_bf16(vb[j], pa[i], o[i][j], 0, 0, 0);
    }

    #pragma unroll
    for (int i = 0; i < 4; i++) {
        size_t row = (size_t)win * 64 + i * 16 + c;
        #pragma unroll
        for (int j = 0; j < 2; j++) {
            int col = head * 32 + j * 16 + 4 * g;
            uint2 pk = { pk2(o[i][j][0], o[i][j][1]), pk2(o[i][j][2], o[i][j][3]) };
            *(uint2*)(O + row * 256 + col) = pk;
        }
    }
}

// ------------------------------------------------------------ MLP mega ------
// out = x + fc2(gelu(fc1(LN(x)))), x bf16. 64 rows/block, 8 waves (512 thr),
// 1024 blocks, 64KB LDS -> 2 blocks/CU = 4 waves/SIMD. Wave owns a 32-col
// slice. R10+R11 combo: TLP (8 waves) AND ILP (explicit wA/wB weight-frag
// double-buffer keeps the next L2 load in flight under each MFMA cluster;
// 16 extra VGPR, fits the 128 cap of (512,4)). setprio around MFMA.
__global__ __launch_bounds__(512, 4) void mlp_mega(
    const u16* __restrict__ xb, const float* __restrict__ gw,
    const float* __restrict__ bw, const bf16x8* __restrict__ f1p,
    const bf16x8* __restrict__ f2p, const float* __restrict__ f1b,
    const float* __restrict__ f2b, float* __restrict__ out)
{
    __shared__ __align__(16) u16 Xl[64 * 256];   // 32 KB, swizzled
    __shared__ __align__(16) u16 Hl[64 * 256];   // 32 KB, swizzled
    const int t = threadIdx.x, lane = t & 63, w = t >> 6;   // w in 0..7
    const int g = lane >> 4, c = lane & 15;
    const int m0 = blockIdx.x * 64;

    // ---- LN inline: wave w handles rows w*8..+7 (bf16 in) ----
    {
        float4 gg = *(const float4*)(gw + lane * 4);
        float4 bb = *(const float4*)(bw + lane * 4);
        for (int it = 0; it < 8; it++) {
            int row = w * 8 + it;
            uint2 rv = *(const uint2*)(xb + (size_t)(m0 + row) * 256 + lane * 4);
            float v0 = bf2f((u16)rv.x), v1 = bf2f((u16)(rv.x >> 16));
            float v2 = bf2f((u16)rv.y), v3 = bf2f((u16)(rv.y >> 16));
            float s = v0 + v1 + v2 + v3;
            float q = v0 * v0 + v1 * v1 + v2 * v2 + v3 * v3;
            #pragma unroll
            for (int m = 1; m < 64; m <<= 1) {
                s += __shfl_xor(s, m, 64);
                q += __shfl_xor(q, m, 64);
            }
            float mean = s * (1.0f / 256.0f);
            float var  = q * (1.0f / 256.0f) - mean * mean;
            float rstd = rsqrtf(var + 1e-5f);
            float n0 = (v0 - mean) * rstd * gg.x + bb.x;
            float n1 = (v1 - mean) * rstd * gg.y + bb.y;
            float n2 = (v2 - mean) * rstd * gg.z + bb.z;
            float n3 = (v3 - mean) * rstd * gg.w + bb.w;
            uint2 pk = { pk2(n0, n1), pk2(n2, n3) };
            *(uint2*)((char*)Xl + row * 512 + (((lane >> 1) ^ (row & 7)) << 4)
                      + ((lane & 1) << 3)) = pk;
        }
    }
    __syncthreads();

    f32x4 acc2[4][2];
    #pragma unroll
    for (int i = 0; i < 4; i++) { acc2[i][0] = (f32x4){0,0,0,0}; acc2[i][1] = (f32x4){0,0,0,0}; }

    #pragma unroll
    for (int hc = 0; hc < 4; hc++) {
        // ---- fc1: all 64 rows, wave's 32 cols of this 256-wide chunk ----
        f32x4 acc1[4][2];
        #pragma unroll
        for (int i = 0; i < 4; i++) { acc1[i][0] = (f32x4){0,0,0,0}; acc1[i][1] = (f32x4){0,0,0,0}; }

        const bf16x8* f1base = f1p + (size_t)((hc * 16 + w * 2) * 8) * 64 + lane;
        bf16x8 wA[2], wB[2];
        #pragma unroll
        for (int n = 0; n < 2; n++) wA[n] = f1base[(n * 8 + 0) * 64];

#define FC1_STEP(WREG, ks_)                                                   \
        {                                                                     \
            bf16x8 af[4];                                                     \
            _Pragma("unroll")                                                 \
            for (int i = 0; i < 4; i++) {                                     \
                int row = i * 16 + c;                                         \
                af[i] = *(const bf16x8*)((char*)Xl + row * 512                \
                        + (((4 * (ks_) + g) ^ (row & 7)) << 4));              \
            }                                                                 \
            __builtin_amdgcn_s_setprio(1);                                    \
            _Pragma("unroll")                                                 \
            for (int i = 0; i < 4; i++)                                       \
                _Pragma("unroll")                                             \
                for (int n = 0; n < 2; n++)                                   \
                    acc1[i][n] = __builtin_amdgcn_mfma_f32_16x16x32_bf16(     \
                        WREG[n], af[i], acc1[i][n], 0, 0, 0);                 \
            __builtin_amdgcn_s_setprio(0);                                    \
        }

        #pragma unroll
        for (int ks = 0; ks < 8; ks += 2) {
            #pragma unroll
            for (int n = 0; n < 2; n++) wB[n] = f1base[(n * 8 + ks + 1) * 64];
            FC1_STEP(wA, ks)
            if (ks + 2 < 8) {
                #pragma unroll
                for (int n = 0; n < 2; n++) wA[n] = f1base[(n * 8 + ks + 2) * 64];
            }
            FC1_STEP(wB, ks + 1)
        }
#undef FC1_STEP

        // gelu + bias -> Hl (swizzled)
        #pragma unroll
        for (int i = 0; i < 4; i++) {
            int row = i * 16 + c;
            #pragma unroll
            for (int n = 0; n < 2; n++) {
                float4 b4 = *(const float4*)(f1b + hc * 256 + w * 32 + n * 16 + 4 * g);
                float h0 = gelu_s(acc1[i][n][0] + b4.x);
                float h1 = gelu_s(acc1[i][n][1] + b4.y);
                float h2 = gelu_s(acc1[i][n][2] + b4.z);
                float h3 = gelu_s(acc1[i][n][3] + b4.w);
                uint2 pk = { pk2(h0, h1), pk2(h2, h3) };
                int cq = 4 * w + 2 * n + (g >> 1);
                *(uint2*)((char*)Hl + row * 512 + (((cq ^ (row & 7)) << 4))
                          + ((g & 1) << 3)) = pk;
            }
        }
        __syncthreads();

        // ---- fc2: acc2 += h_chunk @ f2w_chunk (wave's 32 out cols) ----
        const bf16x8* f2base = f2p + (size_t)((w * 2) * 32 + hc * 8) * 64 + lane;
        #pragma unroll
        for (int n = 0; n < 2; n++) wA[n] = f2base[(n * 32 + 0) * 64];

#define FC2_STEP(WREG, ks_)                                                   \
        {                                                                     \
            bf16x8 ah[4];                                                     \
            _Pragma("unroll")                                                 \
            for (int i = 0; i < 4; i++) {                                     \
                int row = i * 16 + c;                                         \
                ah[i] = *(const bf16x8*)((char*)Hl + row * 512                \
                        + (((4 * (ks_) + g) ^ (row & 7)) << 4));              \
            }                                                                 \
            __builtin_amdgcn_s_setprio(1);                                    \
            _Pragma("unroll")                                                 \
            for (int i = 0; i < 4; i++)                                       \
                _Pragma("unroll")                                             \
                for (int n = 0; n < 2; n++)                                   \
                    acc2[i][n] = __builtin_amdgcn_mfma_f32_16x16x32_bf16(     \
                        WREG[n], ah[i], acc2[i][n], 0, 0, 0);                 \
            __builtin_amdgcn_s_setprio(0);                                    \
        }

        #pragma unroll
        for (int ks = 0; ks < 8; ks += 2) {
            #pragma unroll
            for (int n = 0; n < 2; n++) wB[n] = f2base[(n * 32 + ks + 1) * 64];
            FC2_STEP(wA, ks)
            if (ks + 2 < 8) {
                #pragma unroll
                for (int n = 0; n < 2; n++) wA[n] = f2base[(n * 32 + ks + 2) * 64];
            }
            FC2_STEP(wB, ks + 1)
        }
#undef FC2_STEP
        __syncthreads();
    }

    // ---- direct epilogue: out = acc2 + f2b + x (bf16 resid), f32 stores ----
    #pragma unroll
    for (int i = 0; i < 4; i++) {
        int row = m0 + i * 16 + c;
        #pragma unroll
        for (int n = 0; n < 2; n++) {
            int col = w * 32 + n * 16 + 4 * g;
            float4 b4 = *(const float4*)(f2b + col);
            uint2 rr = *(const uint2*)(xb + (size_t)row * 256 + col);
            float4 ov = { acc2[i][n][0] + b4.x + bf2f((u16)rr.x),
                          acc2[i][n][1] + b4.y + bf2f((u16)(rr.x >> 16)),
                          acc2[i][n][2] + b4.z + bf2f((u16)rr.y),
                          acc2[i][n][3] + b4.w + bf2f((u16)(rr.y >> 16)) };
            *(float4*)(out + (size_t)row * 256 + col) = ov;
        }
    }
}

// -------------------------------------------------------------- launch ------
// Workspace (peak ~137 MB):
//   [0,       2.10M)  weights: qwt kvwt pwt f1p f2p biasF
//   [2.10M,  35.65M)  x1w -> attn (after Q gemm)
//   [35.65M, 69.21M)  x2w
//   [69.21M,136.31M)  Qb -> xbw bf16 (after attn)
//   [102.76M,169.87M) KVb
extern "C" void kernel_launch(void* const* d_in, const int* in_sizes, int n_in,
                              void* d_out, int out_size, void* d_ws, size_t ws_size,
                              hipStream_t stream)
{
    const float* x1  = (const float*)d_in[0];
    const float* x2  = (const float*)d_in[1];
    const float* n1g = (const float*)d_in[2];
    const float* n1b = (const float*)d_in[3];
    const float* q_w = (const float*)d_in[4];
    const float* q_b = (const float*)d_in[5];
    const float* kv_w= (const float*)d_in[6];
    const float* kv_b= (const float*)d_in[7];
    const float* p_w = (const float*)d_in[8];
    const float* p_b = (const float*)d_in[9];
    const float* rel = (const float*)d_in[10];
    const float* n3g = (const float*)d_in[11];
    const float* n3b = (const float*)d_in[12];
    const float* f1w = (const float*)d_in[13];
    const float* f1b = (const float*)d_in[14];
    const float* f2w = (const float*)d_in[15];
    const float* f2b = (const float*)d_in[16];

    char* ws = (char*)d_ws;
    u16*   qwt   = (u16*)(ws + 0);
    u16*   kvwt  = (u16*)(ws + 131072);
    u16*   pwt   = (u16*)(ws + 393216);
    u16*   f1p   = (u16*)(ws + 524288);
    u16*   f2p   = (u16*)(ws + 1048576);
    float* biasF = (float*)(ws + 1572864);

    u16*   x1w  = (u16*)(ws + 2097152);
    u16*   x2w  = (u16*)(ws + 35651584);
    u16*   Qb   = (u16*)(ws + 69206016);
    u16*   KVb  = (u16*)(ws + 102760448);
    u16*   attn = (u16*)(ws + 2097152);     // overlays x1w (dead after Q gemm)
    u16*   xbw  = (u16*)(ws + 69206016);    // bf16 x, overlays Qb (dead after attn)

    float* out = (float*)d_out;

    prep_k<<<3200, 256, 0, stream>>>(q_w, kv_w, p_w, f1w, f2w, rel,
                                     qwt, kvwt, pwt, f1p, f2p, biasF);
    ln_k<<<32768, 256, 0, stream>>>(x1, x2, n1g, n1b, x1w, x2w);
    gemm_k<256, 256, 0><<<dim3(512, 2), 256, 0, stream>>>(x1w, qwt, q_b, Qb, nullptr);
    gemm_k<512, 256, 0><<<dim3(512, 4), 256, 0, stream>>>(x2w, kvwt, kv_b, KVb, nullptr);
    attn_k<<<2048, 256, 0, stream>>>(Qb, KVb, biasF, attn);
    gemm_k<256, 256, 2><<<dim3(512, 2), 256, 0, stream>>>(attn, pwt, p_b, xbw, x1);
    mlp_mega<<<1024, 512, 0, stream>>>(xbw, n3g, n3b, (const bf16x8*)f1p,
                                       (const bf16x8*)f2p, f1b, f2b, out);
}

// Round 13
// 290.736 us; speedup vs baseline: 1.1453x; 1.0282x over previous
//
#include <hip/hip_runtime.h>

typedef __bf16 bf16x8 __attribute__((ext_vector_type(8)));
typedef float f32x4 __attribute__((ext_vector_type(4)));
using u16 = unsigned short;

#define SCALE 0.17677669529663689f  // 32^-0.5

// Direct HBM->LDS DMA, 16B per lane (dest linear: base + lane*16).
#define GLOAD16(lp, gp)                                                        \
    __builtin_amdgcn_global_load_lds(                                          \
        (const __attribute__((address_space(1))) void*)(gp),                   \
        (__attribute__((address_space(3))) void*)(lp), 16, 0, 0)

__device__ __forceinline__ u16 f2bf(float f) {
    union { float f; unsigned u; } x; x.f = f;
    unsigned r = x.u + 0x7fffu + ((x.u >> 16) & 1u);
    return (u16)(r >> 16);
}
__device__ __forceinline__ unsigned pk2(float a, float b) {
    return (unsigned)f2bf(a) | ((unsigned)f2bf(b) << 16);
}
__device__ __forceinline__ float bf2f(u16 h) {
    union { unsigned u; float f; } x; x.u = ((unsigned)h) << 16; return x.f;
}
// gelu = x * sigmoid(1.5957691*(x + 0.044715 x^3))  (tanh-form identity)
__device__ __forceinline__ float gelu_s(float x) {
    float u = 1.5957691216057308f * x * (1.f + 0.044715f * x * x);
    float e = __expf(-u);
    return x / (1.f + e);
}

// ---------------------------------------------------------------- prep ------
// qwt/kvwt/pwt: Wt[N][K] bf16 (for gemm_k). f1p/f2p: fragment-packed bf16
// (frag (ng,ks): lane l holds W[k=32ks+8(l>>4)+e][n=16ng+(l&15)]).
// biasF: rel-pos bias in swapped C-frag layout.
__global__ __launch_bounds__(256) void prep_k(
    const float* __restrict__ q_w, const float* __restrict__ kv_w,
    const float* __restrict__ p_w, const float* __restrict__ f1w,
    const float* __restrict__ f2w, const float* __restrict__ rel,
    u16* __restrict__ qwt, u16* __restrict__ kvwt, u16* __restrict__ pwt,
    u16* __restrict__ f1p, u16* __restrict__ f2p, float* __restrict__ biasF)
{
    int t = blockIdx.x * 256 + threadIdx.x;
    if (t < 65536) {                                   // q_w  256x256
        int k = t & 255, n = t >> 8;
        qwt[t] = f2bf(q_w[k * 256 + n]);
    } else if (t < 196608) {                           // kv_w 256x512
        int u = t - 65536; int k = u & 255, n = u >> 8;
        kvwt[u] = f2bf(kv_w[k * 512 + n]);
    } else if (t < 262144) {                           // proj_w 256x256
        int u = t - 196608; int k = u & 255, n = u >> 8;
        pwt[u] = f2bf(p_w[k * 256 + n]);
    } else if (t < 524288) {                           // f1p packed frags
        int u = t - 262144;
        int e = u & 7, l = (u >> 3) & 63, ks = (u >> 9) & 7, ng = u >> 12;
        int k = ks * 32 + (l >> 4) * 8 + e;
        int n = ng * 16 + (l & 15);
        f1p[u] = f2bf(f1w[k * 1024 + n]);
    } else if (t < 786432) {                           // f2p packed frags
        int u = t - 524288;
        int e = u & 7, l = (u >> 3) & 63, ks = (u >> 9) & 31, ng = u >> 14;
        int k = ks * 32 + (l >> 4) * 8 + e;
        int n = ng * 16 + (l & 15);
        f2p[u] = f2bf(f2w[k * 256 + n]);
    } else if (t < 819200) {                           // biasF 8*16*64*4
        int u = t - 786432;
        int r = u & 3, l = (u >> 2) & 63, fr = (u >> 8) & 15, h = u >> 12;
        int fi = fr >> 2, fj = fr & 3;
        int m = fi * 16 + (l & 15);
        int n = fj * 16 + 4 * (l >> 4) + r;
        int idx = ((m >> 3) - (n >> 3) + 7) * 15 + ((m & 7) - (n & 7) + 7);
        biasF[u] = rel[idx * 8 + h];
    }
}

// ----------------------------------------------------------- layernorm ------
// One wave per 256-elem row; two streams + window-partition permute.
__global__ __launch_bounds__(256) void ln_k(
    const float* __restrict__ xa, const float* __restrict__ xb,
    const float* __restrict__ gw, const float* __restrict__ bw,
    u16* __restrict__ oa, u16* __restrict__ ob)
{
    int lane = threadIdx.x & 63, wid = threadIdx.x >> 6;
    int r = blockIdx.x * 4 + wid;
    const float* src; u16* dst; int row;
    if (r < 65536) { src = xa; dst = oa; row = r; }
    else           { src = xb; dst = ob; row = r - 65536; }

    float4 v = *(const float4*)(src + (size_t)row * 256 + lane * 4);
    float s = v.x + v.y + v.z + v.w;
    float q = v.x * v.x + v.y * v.y + v.z * v.z + v.w * v.w;
    #pragma unroll
    for (int m = 1; m < 64; m <<= 1) {
        s += __shfl_xor(s, m, 64);
        q += __shfl_xor(q, m, 64);
    }
    float mean = s * (1.0f / 256.0f);
    float var  = q * (1.0f / 256.0f) - mean * mean;
    float rstd = rsqrtf(var + 1e-5f);
    float4 gg = *(const float4*)(gw + lane * 4);
    float4 bb = *(const float4*)(bw + lane * 4);

    int b_ = row >> 12, l = row & 4095;
    int hh = l >> 6, ww = l & 63;
    int wi = (hh >> 3) * 8 + (ww >> 3);
    int n  = (hh & 7) * 8 + (ww & 7);
    int orow = b_ * 4096 + wi * 64 + n;

    ushort4 o;
    o.x = f2bf((v.x - mean) * rstd * gg.x + bb.x);
    o.y = f2bf((v.y - mean) * rstd * gg.y + bb.y);
    o.z = f2bf((v.z - mean) * rstd * gg.z + bb.z);
    o.w = f2bf((v.w - mean) * rstd * gg.w + bb.w);
    *(ushort4*)(dst + (size_t)orow * 256 + lane * 4) = o;
}

// ---------------------------------------------------------------- GEMM ------
// 128x128 tile, BK=64, 2-phase dbuf global_load_lds, swapped mfma(B,A) ->
// wide stores. EPI: 0 bf16 out, 2 proj(+window-rev+resid) -> bf16.
template <int NCOLS, int KD, int EPI>
__global__ __launch_bounds__(256) void gemm_k(
    const u16* __restrict__ A, const u16* __restrict__ Bt,
    const float* __restrict__ bias, u16* __restrict__ obf,
    const float* __restrict__ res)
{
    __shared__ __align__(16) u16 As[2][128 * 64];
    __shared__ __align__(16) u16 Bs[2][128 * 64];
    const int t = threadIdx.x;
    const int lane = t & 63, w = t >> 6;
    const int wm = w >> 1, wn = w & 1;
    const int g = lane >> 4, c = lane & 15;
    const int bm = blockIdx.x * 128;
    const int bn = blockIdx.y * 128;
    const int r_in = lane >> 3;
    const int slot = lane & 7;
    const int gch  = slot ^ r_in;

    const u16* Ab = A  + (size_t)bm * KD + gch * 8;
    const u16* Bb = Bt + (size_t)bn * KD + gch * 8;

    f32x4 acc[4][4];
    #pragma unroll
    for (int i = 0; i < 4; i++)
        #pragma unroll
        for (int j = 0; j < 4; j++) acc[i][j] = (f32x4){0.f, 0.f, 0.f, 0.f};

#define STAGE(buf, k0)                                                        \
    {                                                                         \
        _Pragma("unroll")                                                     \
        for (int i_ = 0; i_ < 4; i_++) {                                      \
            const int rowbase = w * 32 + i_ * 8;                              \
            GLOAD16(&As[buf][rowbase * 64],                                   \
                    Ab + (size_t)(rowbase + r_in) * KD + (k0));               \
            GLOAD16(&Bs[buf][rowbase * 64],                                   \
                    Bb + (size_t)(rowbase + r_in) * KD + (k0));               \
        }                                                                     \
    }

#define COMPUTE(buf)                                                          \
    {                                                                         \
        _Pragma("unroll")                                                     \
        for (int kk = 0; kk < 2; kk++) {                                      \
            bf16x8 af[4], bfr[4];                                             \
            _Pragma("unroll")                                                 \
            for (int i_ = 0; i_ < 4; i_++) {                                  \
                int ra = wm * 64 + i_ * 16 + c;                               \
                af[i_]  = *(const bf16x8*)(&As[buf][ra * 64 + ((kk * 4 + g) ^ (ra & 7)) * 8]); \
                int rb = wn * 64 + i_ * 16 + c;                               \
                bfr[i_] = *(const bf16x8*)(&Bs[buf][rb * 64 + ((kk * 4 + g) ^ (rb & 7)) * 8]); \
            }                                                                 \
            _Pragma("unroll")                                                 \
            for (int i_ = 0; i_ < 4; i_++)                                    \
                _Pragma("unroll")                                             \
                for (int j_ = 0; j_ < 4; j_++)                                \
                    acc[i_][j_] = __builtin_amdgcn_mfma_f32_16x16x32_bf16(    \
                        bfr[j_], af[i_], acc[i_][j_], 0, 0, 0);               \
        }                                                                     \
    }

    STAGE(0, 0);
    __syncthreads();
    for (int k0 = 0; k0 < KD; k0 += 128) {
        STAGE(1, k0 + 64);
        COMPUTE(0);
        __syncthreads();
        if (k0 + 128 < KD) STAGE(0, k0 + 128);
        COMPUTE(1);
        if (k0 + 128 < KD) __syncthreads();
    }
#undef STAGE
#undef COMPUTE

    #pragma unroll
    for (int i = 0; i < 4; i++) {
        int row = bm + wm * 64 + i * 16 + c;
        #pragma unroll
        for (int j = 0; j < 4; j++) {
            int col = bn + wn * 64 + j * 16 + 4 * g;
            float4 b4 = *(const float4*)(bias + col);
            float v0 = acc[i][j][0] + b4.x;
            float v1 = acc[i][j][1] + b4.y;
            float v2 = acc[i][j][2] + b4.z;
            float v3 = acc[i][j][3] + b4.w;
            if constexpr (EPI == 0) {
                uint2 pk = { pk2(v0, v1), pk2(v2, v3) };
                *(uint2*)(obf + (size_t)row * NCOLS + col) = pk;
            } else {  // proj: window-reverse + residual(f32) -> bf16 x
                int b_ = row >> 12, wi = (row >> 6) & 63, n = row & 63;
                int hh = (wi >> 3) * 8 + (n >> 3);
                int ww = (wi & 7) * 8 + (n & 7);
                size_t nrow = (size_t)b_ * 4096 + hh * 64 + ww;
                float4 r4 = *(const float4*)(res + nrow * 256 + col);
                uint2 pk = { pk2(v0 + r4.x, v1 + r4.y), pk2(v2 + r4.z, v3 + r4.w) };
                *(uint2*)(obf + nrow * 256 + col) = pk;
            }
        }
    }
}

// ----------------------------------------------------------- attention ------
__global__ __launch_bounds__(256) void attn_k(
    const u16* __restrict__ Q, const u16* __restrict__ KV,
    const float* __restrict__ biasF, u16* __restrict__ O)
{
    __shared__ __align__(16) u16 Pl[4][64 * 64];
    __shared__ __align__(16) u16 Vt[4][32 * 80];
    const int t = threadIdx.x, lane = t & 63, w = t >> 6;
    const int g = lane >> 4, c = lane & 15;
    const int pair = blockIdx.x * 4 + w;
    const int win = pair >> 3, head = pair & 7;
    const size_t qbase  = (size_t)win * 64 * 256 + head * 32;
    const size_t kvbase = (size_t)win * 64 * 512 + head * 32;

    u16* vt = &Vt[w][0];
    {
        const u16* vp = KV + kvbase + 256 + (size_t)lane * 512;
        uint4 v0 = *(const uint4*)(vp);
        uint4 v1 = *(const uint4*)(vp + 8);
        uint4 v2 = *(const uint4*)(vp + 16);
        uint4 v3 = *(const uint4*)(vp + 24);
#define SCAT(vv, dbase)                                           \
        vt[(dbase + 0) * 80 + lane] = (u16)(vv.x);                \
        vt[(dbase + 1) * 80 + lane] = (u16)(vv.x >> 16);          \
        vt[(dbase + 2) * 80 + lane] = (u16)(vv.y);                \
        vt[(dbase + 3) * 80 + lane] = (u16)(vv.y >> 16);          \
        vt[(dbase + 4) * 80 + lane] = (u16)(vv.z);                \
        vt[(dbase + 5) * 80 + lane] = (u16)(vv.z >> 16);          \
        vt[(dbase + 6) * 80 + lane] = (u16)(vv.w);                \
        vt[(dbase + 7) * 80 + lane] = (u16)(vv.w >> 16);
        SCAT(v0, 0) SCAT(v1, 8) SCAT(v2, 16) SCAT(v3, 24)
#undef SCAT
    }

    bf16x8 qf[4], kf[4];
    #pragma unroll
    for (int i = 0; i < 4; i++) {
        qf[i] = *(const bf16x8*)(Q  + qbase  + (size_t)(i * 16 + c) * 256 + 8 * g);
        kf[i] = *(const bf16x8*)(KV + kvbase + (size_t)(i * 16 + c) * 512 + 8 * g);
    }
    f32x4 s[4][4];
    #pragma unroll
    for (int i = 0; i < 4; i++)
        #pragma unroll
        for (int j = 0; j < 4; j++) {
            s[i][j] = (f32x4){0.f, 0.f, 0.f, 0.f};
            s[i][j] = __builtin_amdgcn_mfma_f32_16x16x32_bf16(kf[j], qf[i], s[i][j], 0, 0, 0);
        }

    #pragma unroll
    for (int i = 0; i < 4; i++)
        #pragma unroll
        for (int j = 0; j < 4; j++) {
            f32x4 bf4 = *(const f32x4*)(biasF + ((size_t)(head * 16 + i * 4 + j) * 64 + lane) * 4);
            #pragma unroll
            for (int r = 0; r < 4; r++) s[i][j][r] = s[i][j][r] * SCALE + bf4[r];
        }

    #pragma unroll
    for (int i = 0; i < 4; i++) {
        float mx = -1e30f;
        #pragma unroll
        for (int j = 0; j < 4; j++)
            #pragma unroll
            for (int r = 0; r < 4; r++) mx = fmaxf(mx, s[i][j][r]);
        mx = fmaxf(mx, __shfl_xor(mx, 16, 64));
        mx = fmaxf(mx, __shfl_xor(mx, 32, 64));
        float sum = 0.f;
        #pragma unroll
        for (int j = 0; j < 4; j++)
            #pragma unroll
            for (int r = 0; r < 4; r++) {
                float e = __expf(s[i][j][r] - mx);
                s[i][j][r] = e; sum += e;
            }
        sum += __shfl_xor(sum, 16, 64);
        sum += __shfl_xor(sum, 32, 64);
        float inv = 1.f / sum;
        #pragma unroll
        for (int j = 0; j < 4; j++)
            #pragma unroll
            for (int r = 0; r < 4; r++) s[i][j][r] *= inv;
    }

    u16* pl = &Pl[w][0];
    #pragma unroll
    for (int i = 0; i < 4; i++) {
        int m = i * 16 + c;
        #pragma unroll
        for (int j = 0; j < 4; j++) {
            int kbyte = 32 * j + 8 * g;
            uint2 pk = { pk2(s[i][j][0], s[i][j][1]), pk2(s[i][j][2], s[i][j][3]) };
            *(uint2*)((char*)pl + m * 128 + (kbyte ^ ((m & 7) << 4))) = pk;
        }
    }

    f32x4 o[4][2];
    #pragma unroll
    for (int i = 0; i < 4; i++) { o[i][0] = (f32x4){0,0,0,0}; o[i][1] = (f32x4){0,0,0,0}; }
    #pragma unroll
    for (int ks = 0; ks < 2; ks++) {
        bf16x8 pa[4], vb[2];
        #pragma unroll
        for (int i = 0; i < 4; i++) {
            int row = i * 16 + c;
            int ch = (ks * 4 + g) ^ (row & 7);
            pa[i] = *(const bf16x8*)((char*)pl + row * 128 + ch * 16);
        }
        #pragma unroll
        for (int j = 0; j < 2; j++) {
            int d = j * 16 + c;
            vb[j] = *(const bf16x8*)(vt + d * 80 + ks * 32 + 8 * g);
        }
        #pragma unroll
        for (int i = 0; i < 4; i++)
            #pragma unroll
            for (int j = 0; j < 2; j++)
                o[i][j] = __builtin_amdgcn_mfma_f32_16x16x32_bf16(vb[j], pa[i], o[i][j], 0, 0, 0);
    }

    #pragma unroll
    for (int i = 0; i < 4; i++) {
        size_t row = (size_t)win * 64 + i * 16 + c;
        #pragma unroll
        for (int j = 0; j < 2; j++) {
            int col = head * 32 + j * 16 + 4 * g;
            uint2 pk = { pk2(o[i][j][0], o[i][j][1]), pk2(o[i][j][2], o[i][j][3]) };
            *(uint2*)(O + row * 256 + col) = pk;
        }
    }
}

// ------------------------------------------------------------ MLP mega ------
// out = x + fc2(gelu(fc1(LN(x)))), x bf16. 64 rows/block, 8 waves (512 thr),
// 1024 blocks, 2 blocks/CU. PADDED-LINEAR LDS (row stride 528B = 132 words;
// 132%32=4): b128 reads land uniform 8/bank (optimal), 8B writes uniform
// 4/bank (optimal) -- zero conflicts AND zero per-access XOR VALU; all ds
// offsets are base + compile-time immediates. Wave owns a 32-col slice;
// wA/wB weight dbuf + setprio retained.
#define XROW 528   // bytes per LDS row (264 u16)
__global__ __launch_bounds__(512, 4) void mlp_mega(
    const u16* __restrict__ xb, const float* __restrict__ gw,
    const float* __restrict__ bw, const bf16x8* __restrict__ f1p,
    const bf16x8* __restrict__ f2p, const float* __restrict__ f1b,
    const float* __restrict__ f2b, float* __restrict__ out)
{
    __shared__ __align__(16) u16 Xl[64 * 264];   // 33 KB, padded-linear
    __shared__ __align__(16) u16 Hl[64 * 264];   // 33 KB, padded-linear
    const int t = threadIdx.x, lane = t & 63, w = t >> 6;   // w in 0..7
    const int g = lane >> 4, c = lane & 15;
    const int m0 = blockIdx.x * 64;

    // ---- LN inline: wave w handles rows w*8..+7 (bf16 in) ----
    {
        float4 gg = *(const float4*)(gw + lane * 4);
        float4 bb = *(const float4*)(bw + lane * 4);
        for (int it = 0; it < 8; it++) {
            int row = w * 8 + it;
            uint2 rv = *(const uint2*)(xb + (size_t)(m0 + row) * 256 + lane * 4);
            float v0 = bf2f((u16)rv.x), v1 = bf2f((u16)(rv.x >> 16));
            float v2 = bf2f((u16)rv.y), v3 = bf2f((u16)(rv.y >> 16));
            float s = v0 + v1 + v2 + v3;
            float q = v0 * v0 + v1 * v1 + v2 * v2 + v3 * v3;
            #pragma unroll
            for (int m = 1; m < 64; m <<= 1) {
                s += __shfl_xor(s, m, 64);
                q += __shfl_xor(q, m, 64);
            }
            float mean = s * (1.0f / 256.0f);
            float var  = q * (1.0f / 256.0f) - mean * mean;
            float rstd = rsqrtf(var + 1e-5f);
            float n0 = (v0 - mean) * rstd * gg.x + bb.x;
            float n1 = (v1 - mean) * rstd * gg.y + bb.y;
            float n2 = (v2 - mean) * rstd * gg.z + bb.z;
            float n3 = (v3 - mean) * rstd * gg.w + bb.w;
            uint2 pk = { pk2(n0, n1), pk2(n2, n3) };
            *(uint2*)((char*)Xl + row * XROW + lane * 8) = pk;   // linear cols
        }
    }
    __syncthreads();

    f32x4 acc2[4][2];
    #pragma unroll
    for (int i = 0; i < 4; i++) { acc2[i][0] = (f32x4){0,0,0,0}; acc2[i][1] = (f32x4){0,0,0,0}; }

    #pragma unroll
    for (int hc = 0; hc < 4; hc++) {
        // ---- fc1: all 64 rows, wave's 32 cols of this 256-wide chunk ----
        f32x4 acc1[4][2];
        #pragma unroll
        for (int i = 0; i < 4; i++) { acc1[i][0] = (f32x4){0,0,0,0}; acc1[i][1] = (f32x4){0,0,0,0}; }

        const bf16x8* f1base = f1p + (size_t)((hc * 16 + w * 2) * 8) * 64 + lane;
        bf16x8 wA[2], wB[2];
        #pragma unroll
        for (int n = 0; n < 2; n++) wA[n] = f1base[(n * 8 + 0) * 64];

#define FC1_STEP(WREG, ks_)                                                   \
        {                                                                     \
            bf16x8 af[4];                                                     \
            _Pragma("unroll")                                                 \
            for (int i = 0; i < 4; i++)                                       \
                af[i] = *(const bf16x8*)((char*)Xl + (i * 16 + c) * XROW      \
                                         + g * 16 + (ks_) * 64);             \
            __builtin_amdgcn_s_setprio(1);                                    \
            _Pragma("unroll")                                                 \
            for (int i = 0; i < 4; i++)                                       \
                _Pragma("unroll")                                             \
                for (int n = 0; n < 2; n++)                                   \
                    acc1[i][n] = __builtin_amdgcn_mfma_f32_16x16x32_bf16(     \
                        WREG[n], af[i], acc1[i][n], 0, 0, 0);                 \
            __builtin_amdgcn_s_setprio(0);                                    \
        }

        #pragma unroll
        for (int ks = 0; ks < 8; ks += 2) {
            #pragma unroll
            for (int n = 0; n < 2; n++) wB[n] = f1base[(n * 8 + ks + 1) * 64];
            FC1_STEP(wA, ks)
            if (ks + 2 < 8) {
                #pragma unroll
                for (int n = 0; n < 2; n++) wA[n] = f1base[(n * 8 + ks + 2) * 64];
            }
            FC1_STEP(wB, ks + 1)
        }
#undef FC1_STEP

        // gelu + bias -> Hl (linear cols, base + immediate offsets)
        #pragma unroll
        for (int i = 0; i < 4; i++) {
            int row = i * 16 + c;
            #pragma unroll
            for (int n = 0; n < 2; n++) {
                float4 b4 = *(const float4*)(f1b + hc * 256 + w * 32 + n * 16 + 4 * g);
                float h0 = gelu_s(acc1[i][n][0] + b4.x);
                float h1 = gelu_s(acc1[i][n][1] + b4.y);
                float h2 = gelu_s(acc1[i][n][2] + b4.z);
                float h3 = gelu_s(acc1[i][n][3] + b4.w);
                uint2 pk = { pk2(h0, h1), pk2(h2, h3) };
                *(uint2*)((char*)Hl + row * XROW + w * 64 + n * 32 + g * 8) = pk;
            }
        }
        __syncthreads();

        // ---- fc2: acc2 += h_chunk @ f2w_chunk (wave's 32 out cols) ----
        const bf16x8* f2base = f2p + (size_t)((w * 2) * 32 + hc * 8) * 64 + lane;
        #pragma unroll
        for (int n = 0; n < 2; n++) wA[n] = f2base[(n * 32 + 0) * 64];

#define FC2_STEP(WREG, ks_)                                                   \
        {                                                                     \
            bf16x8 ah[4];                                                     \
            _Pragma("unroll")                                                 \
            for (int i = 0; i < 4; i++)                                       \
                ah[i] = *(const bf16x8*)((char*)Hl + (i * 16 + c) * XROW      \
                                         + g * 16 + (ks_) * 64);             \
            __builtin_amdgcn_s_setprio(1);                                    \
            _Pragma("unroll")                                                 \
            for (int i = 0; i < 4; i++)                                       \
                _Pragma("unroll")                                             \
                for (int n = 0; n < 2; n++)                                   \
                    acc2[i][n] = __builtin_amdgcn_mfma_f32_16x16x32_bf16(     \
                        WREG[n], ah[i], acc2[i][n], 0, 0, 0);                 \
            __builtin_amdgcn_s_setprio(0);                                    \
        }

        #pragma unroll
        for (int ks = 0; ks < 8; ks += 2) {
            #pragma unroll
            for (int n = 0; n < 2; n++) wB[n] = f2base[(n * 32 + ks + 1) * 64];
            FC2_STEP(wA, ks)
            if (ks + 2 < 8) {
                #pragma unroll
                for (int n = 0; n < 2; n++) wA[n] = f2base[(n * 32 + ks + 2) * 64];
            }
            FC2_STEP(wB, ks + 1)
        }
#undef FC2_STEP
        __syncthreads();
    }

    // ---- direct epilogue: out = acc2 + f2b + x (bf16 resid), f32 stores ----
    #pragma unroll
    for (int i = 0; i < 4; i++) {
        int row = m0 + i * 16 + c;
        #pragma unroll
        for (int n = 0; n < 2; n++) {
            int col = w * 32 + n * 16 + 4 * g;
            float4 b4 = *(const float4*)(f2b + col);
            uint2 rr = *(const uint2*)(xb + (size_t)row * 256 + col);
            float4 ov = { acc2[i][n][0] + b4.x + bf2f((u16)rr.x),
                          acc2[i][n][1] + b4.y + bf2f((u16)(rr.x >> 16)),
                          acc2[i][n][2] + b4.z + bf2f((u16)rr.y),
                          acc2[i][n][3] + b4.w + bf2f((u16)(rr.y >> 16)) };
            *(float4*)(out + (size_t)row * 256 + col) = ov;
        }
    }
}
#undef XROW

// -------------------------------------------------------------- launch ------
// Workspace (peak ~137 MB):
//   [0,       2.10M)  weights: qwt kvwt pwt f1p f2p biasF
//   [2.10M,  35.65M)  x1w -> attn (after Q gemm)
//   [35.65M, 69.21M)  x2w
//   [69.21M,136.31M)  Qb -> xbw bf16 (after attn)
//   [102.76M,169.87M) KVb
extern "C" void kernel_launch(void* const* d_in, const int* in_sizes, int n_in,
                              void* d_out, int out_size, void* d_ws, size_t ws_size,
                              hipStream_t stream)
{
    const float* x1  = (const float*)d_in[0];
    const float* x2  = (const float*)d_in[1];
    const float* n1g = (const float*)d_in[2];
    const float* n1b = (const float*)d_in[3];
    const float* q_w = (const float*)d_in[4];
    const float* q_b = (const float*)d_in[5];
    const float* kv_w= (const float*)d_in[6];
    const float* kv_b= (const float*)d_in[7];
    const float* p_w = (const float*)d_in[8];
    const float* p_b = (const float*)d_in[9];
    const float* rel = (const float*)d_in[10];
    const float* n3g = (const float*)d_in[11];
    const float* n3b = (const float*)d_in[12];
    const float* f1w = (const float*)d_in[13];
    const float* f1b = (const float*)d_in[14];
    const float* f2w = (const float*)d_in[15];
    const float* f2b = (const float*)d_in[16];

    char* ws = (char*)d_ws;
    u16*   qwt   = (u16*)(ws + 0);
    u16*   kvwt  = (u16*)(ws + 131072);
    u16*   pwt   = (u16*)(ws + 393216);
    u16*   f1p   = (u16*)(ws + 524288);
    u16*   f2p   = (u16*)(ws + 1048576);
    float* biasF = (float*)(ws + 1572864);

    u16*   x1w  = (u16*)(ws + 2097152);
    u16*   x2w  = (u16*)(ws + 35651584);
    u16*   Qb   = (u16*)(ws + 69206016);
    u16*   KVb  = (u16*)(ws + 102760448);
    u16*   attn = (u16*)(ws + 2097152);     // overlays x1w (dead after Q gemm)
    u16*   xbw  = (u16*)(ws + 69206016);    // bf16 x, overlays Qb (dead after attn)

    float* out = (float*)d_out;

    prep_k<<<3200, 256, 0, stream>>>(q_w, kv_w, p_w, f1w, f2w, rel,
                                     qwt, kvwt, pwt, f1p, f2p, biasF);
    ln_k<<<32768, 256, 0, stream>>>(x1, x2, n1g, n1b, x1w, x2w);
    gemm_k<256, 256, 0><<<dim3(512, 2), 256, 0, stream>>>(x1w, qwt, q_b, Qb, nullptr);
    gemm_k<512, 256, 0><<<dim3(512, 4), 256, 0, stream>>>(x2w, kvwt, kv_b, KVb, nullptr);
    attn_k<<<2048, 256, 0, stream>>>(Qb, KVb, biasF, attn);
    gemm_k<256, 256, 2><<<dim3(512, 2), 256, 0, stream>>>(attn, pwt, p_b, xbw, x1);
    mlp_mega<<<1024, 512, 0, stream>>>(xbw, n3g, n3b, (const bf16x8*)f1p,
                                       (const bf16x8*)f2p, f1b, f2b, out);
}

// Round 14
// 248.695 us; speedup vs baseline: 1.3389x; 1.1690x over previous
//
#include <hip/hip_runtime.h>

typedef __bf16 bf16x8 __attribute__((ext_vector_type(8)));
typedef float f32x4 __attribute__((ext_vector_type(4)));
using u16 = unsigned short;

#define SCALE 0.17677669529663689f  // 32^-0.5
#define XROW 528                    // padded LDS row stride (264 u16)

__device__ __forceinline__ u16 f2bf(float f) {
    union { float f; unsigned u; } x; x.f = f;
    unsigned r = x.u + 0x7fffu + ((x.u >> 16) & 1u);
    return (u16)(r >> 16);
}
__device__ __forceinline__ unsigned pk2(float a, float b) {
    return (unsigned)f2bf(a) | ((unsigned)f2bf(b) << 16);
}
__device__ __forceinline__ float bf2f(u16 h) {
    union { unsigned u; float f; } x; x.u = ((unsigned)h) << 16; return x.f;
}
// gelu = x * sigmoid(1.5957691*(x + 0.044715 x^3))
__device__ __forceinline__ float gelu_s(float x) {
    float u = 1.5957691216057308f * x * (1.f + 0.044715f * x * x);
    float e = __expf(-u);
    return x / (1.f + e);
}

// ---------------------------------------------------------------- prep ------
// ALL weights in fragment-packed layout (frag (ng,ks): lane l holds
// W[k=32ks+8(l>>4)+e][n=16ng+(l&15)]). biasF: rel-pos bias, swapped C-frag.
__global__ __launch_bounds__(256) void prep_k(
    const float* __restrict__ q_w, const float* __restrict__ kv_w,
    const float* __restrict__ p_w, const float* __restrict__ f1w,
    const float* __restrict__ f2w, const float* __restrict__ rel,
    u16* __restrict__ qp, u16* __restrict__ kvp, u16* __restrict__ pp,
    u16* __restrict__ f1p, u16* __restrict__ f2p, float* __restrict__ biasF)
{
    int t = blockIdx.x * 256 + threadIdx.x;
    if (t < 65536) {                                   // qp: 256x256, ks 0..7
        int u = t;
        int e = u & 7, l = (u >> 3) & 63, ks = (u >> 9) & 7, ng = u >> 12;
        int k = ks * 32 + (l >> 4) * 8 + e;
        int n = ng * 16 + (l & 15);
        qp[u] = f2bf(q_w[k * 256 + n]);
    } else if (t < 196608) {                           // kvp: 256x512
        int u = t - 65536;
        int e = u & 7, l = (u >> 3) & 63, ks = (u >> 9) & 7, ng = u >> 12;
        int k = ks * 32 + (l >> 4) * 8 + e;
        int n = ng * 16 + (l & 15);
        kvp[u] = f2bf(kv_w[k * 512 + n]);
    } else if (t < 262144) {                           // pp: 256x256
        int u = t - 196608;
        int e = u & 7, l = (u >> 3) & 63, ks = (u >> 9) & 7, ng = u >> 12;
        int k = ks * 32 + (l >> 4) * 8 + e;
        int n = ng * 16 + (l & 15);
        pp[u] = f2bf(p_w[k * 256 + n]);
    } else if (t < 524288) {                           // f1p: 256x1024
        int u = t - 262144;
        int e = u & 7, l = (u >> 3) & 63, ks = (u >> 9) & 7, ng = u >> 12;
        int k = ks * 32 + (l >> 4) * 8 + e;
        int n = ng * 16 + (l & 15);
        f1p[u] = f2bf(f1w[k * 1024 + n]);
    } else if (t < 786432) {                           // f2p: 1024x256
        int u = t - 524288;
        int e = u & 7, l = (u >> 3) & 63, ks = (u >> 9) & 31, ng = u >> 14;
        int k = ks * 32 + (l >> 4) * 8 + e;
        int n = ng * 16 + (l & 15);
        f2p[u] = f2bf(f2w[k * 256 + n]);
    } else if (t < 819200) {                           // biasF 8*16*64*4
        int u = t - 786432;
        int r = u & 3, l = (u >> 2) & 63, fr = (u >> 8) & 15, h = u >> 12;
        int fi = fr >> 2, fj = fr & 3;
        int m = fi * 16 + (l & 15);
        int n = fj * 16 + 4 * (l >> 4) + r;
        int idx = ((m >> 3) - (n >> 3) + 7) * 15 + ((m & 7) - (n & 7) + 7);
        biasF[u] = rel[idx * 8 + h];
    }
}

// ------------------------------------------------------------ QKV mega ------
// Block = 1 window (64 tokens), 8 waves. LN1(x1)->Xl[0], LN1(x2)->Xl[1]
// (window-partition row gather), then Q = Xl0 @ q_w (wave: 32 cols) and
// KV = Xl1 @ kv_w (wave: 64 cols) from packed fragments. Wide C-layout out.
__global__ __launch_bounds__(512, 4) void qkv_mega(
    const float* __restrict__ x1, const float* __restrict__ x2,
    const float* __restrict__ gw, const float* __restrict__ bw,
    const bf16x8* __restrict__ qp, const bf16x8* __restrict__ kvp,
    const float* __restrict__ q_b, const float* __restrict__ kv_b,
    u16* __restrict__ Qb, u16* __restrict__ KVb)
{
    __shared__ __align__(16) u16 Xl[2][64 * 264];   // 66 KB
    const int t = threadIdx.x, lane = t & 63, w = t >> 6;
    const int g = lane >> 4, c = lane & 15;
    const int win = blockIdx.x;
    const int b_ = win >> 6, wh = (win >> 3) & 7, ww = win & 7;

    // ---- LN: 16 rows/wave over 128 rows (2 streams x 64 tokens) ----
    {
        float4 gg = *(const float4*)(gw + lane * 4);
        float4 bb = *(const float4*)(bw + lane * 4);
        for (int it = 0; it < 16; it++) {
            int idx = w * 16 + it;
            int st = idx >> 6, n = idx & 63;
            const float* src = st ? x2 : x1;
            size_t srow = (size_t)b_ * 4096 + (wh * 8 + (n >> 3)) * 64 + ww * 8 + (n & 7);
            float4 v = *(const float4*)(src + srow * 256 + lane * 4);
            float s = v.x + v.y + v.z + v.w;
            float q = v.x * v.x + v.y * v.y + v.z * v.z + v.w * v.w;
            #pragma unroll
            for (int m = 1; m < 64; m <<= 1) {
                s += __shfl_xor(s, m, 64);
                q += __shfl_xor(q, m, 64);
            }
            float mean = s * (1.0f / 256.0f);
            float var  = q * (1.0f / 256.0f) - mean * mean;
            float rstd = rsqrtf(var + 1e-5f);
            float n0 = (v.x - mean) * rstd * gg.x + bb.x;
            float n1 = (v.y - mean) * rstd * gg.y + bb.y;
            float n2 = (v.z - mean) * rstd * gg.z + bb.z;
            float n3 = (v.w - mean) * rstd * gg.w + bb.w;
            uint2 pk = { pk2(n0, n1), pk2(n2, n3) };
            *(uint2*)((char*)&Xl[st][0] + n * XROW + lane * 8) = pk;
        }
    }
    __syncthreads();

    // ---- Q: wave w -> cols w*32..+32 (2 n-frags), K=256 ----
    {
        f32x4 aq[4][2];
        #pragma unroll
        for (int i = 0; i < 4; i++) { aq[i][0] = (f32x4){0,0,0,0}; aq[i][1] = (f32x4){0,0,0,0}; }
        #pragma unroll
        for (int ks = 0; ks < 8; ks++) {
            bf16x8 wf[2], af[4];
            #pragma unroll
            for (int n = 0; n < 2; n++)
                wf[n] = qp[(size_t)((w * 2 + n) * 8 + ks) * 64 + lane];
            #pragma unroll
            for (int i = 0; i < 4; i++)
                af[i] = *(const bf16x8*)((char*)&Xl[0][0] + (i * 16 + c) * XROW
                                         + g * 16 + ks * 64);
            __builtin_amdgcn_s_setprio(1);
            #pragma unroll
            for (int i = 0; i < 4; i++)
                #pragma unroll
                for (int n = 0; n < 2; n++)
                    aq[i][n] = __builtin_amdgcn_mfma_f32_16x16x32_bf16(
                        wf[n], af[i], aq[i][n], 0, 0, 0);
            __builtin_amdgcn_s_setprio(0);
        }
        #pragma unroll
        for (int i = 0; i < 4; i++) {
            size_t row = (size_t)win * 64 + i * 16 + c;
            #pragma unroll
            for (int n = 0; n < 2; n++) {
                int col = w * 32 + n * 16 + 4 * g;
                float4 b4 = *(const float4*)(q_b + col);
                uint2 pk = { pk2(aq[i][n][0] + b4.x, aq[i][n][1] + b4.y),
                             pk2(aq[i][n][2] + b4.z, aq[i][n][3] + b4.w) };
                *(uint2*)(Qb + row * 256 + col) = pk;
            }
        }
    }

    // ---- KV: wave w -> cols w*64..+64 of 512 (4 n-frags), K=256 ----
    {
        f32x4 akv[4][4];
        #pragma unroll
        for (int i = 0; i < 4; i++)
            #pragma unroll
            for (int n = 0; n < 4; n++) akv[i][n] = (f32x4){0,0,0,0};
        #pragma unroll
        for (int ks = 0; ks < 8; ks++) {
            bf16x8 wf[4], af[4];
            #pragma unroll
            for (int n = 0; n < 4; n++)
                wf[n] = kvp[(size_t)((w * 4 + n) * 8 + ks) * 64 + lane];
            #pragma unroll
            for (int i = 0; i < 4; i++)
                af[i] = *(const bf16x8*)((char*)&Xl[1][0] + (i * 16 + c) * XROW
                                         + g * 16 + ks * 64);
            __builtin_amdgcn_s_setprio(1);
            #pragma unroll
            for (int i = 0; i < 4; i++)
                #pragma unroll
                for (int n = 0; n < 4; n++)
                    akv[i][n] = __builtin_amdgcn_mfma_f32_16x16x32_bf16(
                        wf[n], af[i], akv[i][n], 0, 0, 0);
            __builtin_amdgcn_s_setprio(0);
        }
        #pragma unroll
        for (int i = 0; i < 4; i++) {
            size_t row = (size_t)win * 64 + i * 16 + c;
            #pragma unroll
            for (int n = 0; n < 4; n++) {
                int col = w * 64 + n * 16 + 4 * g;
                float4 b4 = *(const float4*)(kv_b + col);
                uint2 pk = { pk2(akv[i][n][0] + b4.x, akv[i][n][1] + b4.y),
                             pk2(akv[i][n][2] + b4.z, akv[i][n][3] + b4.w) };
                *(uint2*)(KVb + row * 512 + col) = pk;
            }
        }
    }
}

// ------------------------------------------------------ attn+proj mega ------
// Block = 1 window, wave = head. attn core (Vt SCAT, QK^T, frag bias,
// softmax) as verified; P repacked to A-frags IN REGISTERS via shfl;
// O -> Olds; proj (K=256 from Olds, packed frags) + window-reverse +
// f32 residual -> bf16 x.
__global__ __launch_bounds__(512, 4) void attnproj_mega(
    const u16* __restrict__ Q, const u16* __restrict__ KV,
    const float* __restrict__ biasF, const bf16x8* __restrict__ pp,
    const float* __restrict__ p_b, const float* __restrict__ x1,
    u16* __restrict__ xbw)
{
    __shared__ __align__(16) u16 Vt[8][32 * 80];   // 40 KB
    __shared__ __align__(16) u16 Olds[64 * 264];   // 33 KB
    const int t = threadIdx.x, lane = t & 63, w = t >> 6;   // w = head
    const int g = lane >> 4, c = lane & 15;
    const int win = blockIdx.x;
    const int b_ = win >> 6, wh = (win >> 3) & 7, ww = win & 7;
    const size_t qbase  = (size_t)win * 64 * 256 + w * 32;
    const size_t kvbase = (size_t)win * 64 * 512 + w * 32;

    // stage V^T into LDS: Vt[d][n]
    u16* vt = &Vt[w][0];
    {
        const u16* vp = KV + kvbase + 256 + (size_t)lane * 512;
        uint4 v0 = *(const uint4*)(vp);
        uint4 v1 = *(const uint4*)(vp + 8);
        uint4 v2 = *(const uint4*)(vp + 16);
        uint4 v3 = *(const uint4*)(vp + 24);
#define SCAT(vv, dbase)                                           \
        vt[(dbase + 0) * 80 + lane] = (u16)(vv.x);                \
        vt[(dbase + 1) * 80 + lane] = (u16)(vv.x >> 16);          \
        vt[(dbase + 2) * 80 + lane] = (u16)(vv.y);                \
        vt[(dbase + 3) * 80 + lane] = (u16)(vv.y >> 16);          \
        vt[(dbase + 4) * 80 + lane] = (u16)(vv.z);                \
        vt[(dbase + 5) * 80 + lane] = (u16)(vv.z >> 16);          \
        vt[(dbase + 6) * 80 + lane] = (u16)(vv.w);                \
        vt[(dbase + 7) * 80 + lane] = (u16)(vv.w >> 16);
        SCAT(v0, 0) SCAT(v1, 8) SCAT(v2, 16) SCAT(v3, 24)
#undef SCAT
    }

    // QK^T (head dim 32 = one MFMA K-step); swapped mfma(K, Q)
    f32x4 s[4][4];
    {
        bf16x8 qf[4], kf[4];
        #pragma unroll
        for (int i = 0; i < 4; i++) {
            qf[i] = *(const bf16x8*)(Q  + qbase  + (size_t)(i * 16 + c) * 256 + 8 * g);
            kf[i] = *(const bf16x8*)(KV + kvbase + (size_t)(i * 16 + c) * 512 + 8 * g);
        }
        #pragma unroll
        for (int i = 0; i < 4; i++)
            #pragma unroll
            for (int j = 0; j < 4; j++) {
                s[i][j] = (f32x4){0.f, 0.f, 0.f, 0.f};
                s[i][j] = __builtin_amdgcn_mfma_f32_16x16x32_bf16(kf[j], qf[i], s[i][j], 0, 0, 0);
            }
    }

    // scale + rel-pos bias (frag layout, head = w)
    #pragma unroll
    for (int i = 0; i < 4; i++)
        #pragma unroll
        for (int j = 0; j < 4; j++) {
            f32x4 bf4 = *(const f32x4*)(biasF + ((size_t)(w * 16 + i * 4 + j) * 64 + lane) * 4);
            #pragma unroll
            for (int r = 0; r < 4; r++) s[i][j][r] = s[i][j][r] * SCALE + bf4[r];
        }

    // softmax over keys (row m = i*16+c; 16 in-lane + lanes +-16/32)
    #pragma unroll
    for (int i = 0; i < 4; i++) {
        float mx = -1e30f;
        #pragma unroll
        for (int j = 0; j < 4; j++)
            #pragma unroll
            for (int r = 0; r < 4; r++) mx = fmaxf(mx, s[i][j][r]);
        mx = fmaxf(mx, __shfl_xor(mx, 16, 64));
        mx = fmaxf(mx, __shfl_xor(mx, 32, 64));
        float sum = 0.f;
        #pragma unroll
        for (int j = 0; j < 4; j++)
            #pragma unroll
            for (int r = 0; r < 4; r++) {
                float e = __expf(s[i][j][r] - mx);
                s[i][j][r] = e; sum += e;
            }
        sum += __shfl_xor(sum, 16, 64);
        sum += __shfl_xor(sum, 32, 64);
        float inv = 1.f / sum;
        #pragma unroll
        for (int j = 0; j < 4; j++)
            #pragma unroll
            for (int r = 0; r < 4; r++) s[i][j][r] *= inv;
    }

    // pack P to bf16 word pairs: pw0[i][j] = keys(4j..),regs0-1; pw1 = regs2-3
    unsigned pw0[4][4], pw1[4][4];
    #pragma unroll
    for (int i = 0; i < 4; i++)
        #pragma unroll
        for (int j = 0; j < 4; j++) {
            pw0[i][j] = pk2(s[i][j][0], s[i][j][1]);
            pw1[i][j] = pk2(s[i][j][2], s[i][j][3]);
        }

    // O = P V (2 MFMA K-steps); pa built in-register via shfl:
    // target lane (c,g), keys 32ks+8g+e: srcA = c+16*((2g)&3) (e0..3),
    // srcB = srcA+16 (e4..7); reg set j0 = 2ks + (g>>1).
    f32x4 o[4][2];
    #pragma unroll
    for (int i = 0; i < 4; i++) { o[i][0] = (f32x4){0,0,0,0}; o[i][1] = (f32x4){0,0,0,0}; }
    const int srcA = c + 16 * ((2 * g) & 3);
    const int srcB = srcA + 16;
    const bool hi = (g >= 2);
    #pragma unroll
    for (int ks = 0; ks < 2; ks++) {
        bf16x8 pa[4], vb[2];
        #pragma unroll
        for (int i = 0; i < 4; i++) {
            unsigned a0 = __shfl(pw0[i][2 * ks], srcA), b0 = __shfl(pw0[i][2 * ks + 1], srcA);
            unsigned a1 = __shfl(pw1[i][2 * ks], srcA), b1 = __shfl(pw1[i][2 * ks + 1], srcA);
            unsigned a2 = __shfl(pw0[i][2 * ks], srcB), b2 = __shfl(pw0[i][2 * ks + 1], srcB);
            unsigned a3 = __shfl(pw1[i][2 * ks], srcB), b3 = __shfl(pw1[i][2 * ks + 1], srcB);
            union { uint4 u; bf16x8 v; } cv;
            cv.u.x = hi ? b0 : a0;
            cv.u.y = hi ? b1 : a1;
            cv.u.z = hi ? b2 : a2;
            cv.u.w = hi ? b3 : a3;
            pa[i] = cv.v;
        }
        #pragma unroll
        for (int j = 0; j < 2; j++) {
            int d = j * 16 + c;
            vb[j] = *(const bf16x8*)(vt + d * 80 + ks * 32 + 8 * g);
        }
        #pragma unroll
        for (int i = 0; i < 4; i++)
            #pragma unroll
            for (int j = 0; j < 2; j++)
                o[i][j] = __builtin_amdgcn_mfma_f32_16x16x32_bf16(vb[j], pa[i], o[i][j], 0, 0, 0);
    }

    // O -> Olds (bf16, padded-linear; head w owns cols w*32..+32)
    #pragma unroll
    for (int i = 0; i < 4; i++) {
        int row = i * 16 + c;
        #pragma unroll
        for (int j = 0; j < 2; j++) {
            uint2 pk = { pk2(o[i][j][0], o[i][j][1]), pk2(o[i][j][2], o[i][j][3]) };
            *(uint2*)((char*)Olds + row * XROW + w * 64 + j * 32 + g * 8) = pk;
        }
    }
    __syncthreads();

    // proj: wave w -> out cols w*32..+32, K=256 from Olds
    f32x4 ap[4][2];
    #pragma unroll
    for (int i = 0; i < 4; i++) { ap[i][0] = (f32x4){0,0,0,0}; ap[i][1] = (f32x4){0,0,0,0}; }
    #pragma unroll
    for (int ks = 0; ks < 8; ks++) {
        bf16x8 wf[2], ah[4];
        #pragma unroll
        for (int n = 0; n < 2; n++)
            wf[n] = pp[(size_t)((w * 2 + n) * 8 + ks) * 64 + lane];
        #pragma unroll
        for (int i = 0; i < 4; i++)
            ah[i] = *(const bf16x8*)((char*)Olds + (i * 16 + c) * XROW
                                     + g * 16 + ks * 64);
        __builtin_amdgcn_s_setprio(1);
        #pragma unroll
        for (int i = 0; i < 4; i++)
            #pragma unroll
            for (int n = 0; n < 2; n++)
                ap[i][n] = __builtin_amdgcn_mfma_f32_16x16x32_bf16(
                    wf[n], ah[i], ap[i][n], 0, 0, 0);
        __builtin_amdgcn_s_setprio(0);
    }

    // epilogue: window-reverse + f32 residual -> bf16 x
    #pragma unroll
    for (int i = 0; i < 4; i++) {
        int n = i * 16 + c;
        size_t nrow = (size_t)b_ * 4096 + (wh * 8 + (n >> 3)) * 64 + ww * 8 + (n & 7);
        #pragma unroll
        for (int j = 0; j < 2; j++) {
            int col = w * 32 + j * 16 + 4 * g;
            float4 b4 = *(const float4*)(p_b + col);
            float4 r4 = *(const float4*)(x1 + nrow * 256 + col);
            uint2 pk = { pk2(ap[i][j][0] + b4.x + r4.x, ap[i][j][1] + b4.y + r4.y),
                         pk2(ap[i][j][2] + b4.z + r4.z, ap[i][j][3] + b4.w + r4.w) };
            *(uint2*)(xbw + nrow * 256 + col) = pk;
        }
    }
}

// ------------------------------------------------------------ MLP mega ------
// (R13 verified) out = x + fc2(gelu(fc1(LN(x)))), x bf16. 64 rows/block,
// 8 waves, padded-linear LDS, wA/wB weight dbuf + setprio.
__global__ __launch_bounds__(512, 4) void mlp_mega(
    const u16* __restrict__ xb, const float* __restrict__ gw,
    const float* __restrict__ bw, const bf16x8* __restrict__ f1p,
    const bf16x8* __restrict__ f2p, const float* __restrict__ f1b,
    const float* __restrict__ f2b, float* __restrict__ out)
{
    __shared__ __align__(16) u16 Xl[64 * 264];
    __shared__ __align__(16) u16 Hl[64 * 264];
    const int t = threadIdx.x, lane = t & 63, w = t >> 6;
    const int g = lane >> 4, c = lane & 15;
    const int m0 = blockIdx.x * 64;

    {
        float4 gg = *(const float4*)(gw + lane * 4);
        float4 bb = *(const float4*)(bw + lane * 4);
        for (int it = 0; it < 8; it++) {
            int row = w * 8 + it;
            uint2 rv = *(const uint2*)(xb + (size_t)(m0 + row) * 256 + lane * 4);
            float v0 = bf2f((u16)rv.x), v1 = bf2f((u16)(rv.x >> 16));
            float v2 = bf2f((u16)rv.y), v3 = bf2f((u16)(rv.y >> 16));
            float s = v0 + v1 + v2 + v3;
            float q = v0 * v0 + v1 * v1 + v2 * v2 + v3 * v3;
            #pragma unroll
            for (int m = 1; m < 64; m <<= 1) {
                s += __shfl_xor(s, m, 64);
                q += __shfl_xor(q, m, 64);
            }
            float mean = s * (1.0f / 256.0f);
            float var  = q * (1.0f / 256.0f) - mean * mean;
            float rstd = rsqrtf(var + 1e-5f);
            float n0 = (v0 - mean) * rstd * gg.x + bb.x;
            float n1 = (v1 - mean) * rstd * gg.y + bb.y;
            float n2 = (v2 - mean) * rstd * gg.z + bb.z;
            float n3 = (v3 - mean) * rstd * gg.w + bb.w;
            uint2 pk = { pk2(n0, n1), pk2(n2, n3) };
            *(uint2*)((char*)Xl + row * XROW + lane * 8) = pk;
        }
    }
    __syncthreads();

    f32x4 acc2[4][2];
    #pragma unroll
    for (int i = 0; i < 4; i++) { acc2[i][0] = (f32x4){0,0,0,0}; acc2[i][1] = (f32x4){0,0,0,0}; }

    #pragma unroll
    for (int hc = 0; hc < 4; hc++) {
        f32x4 acc1[4][2];
        #pragma unroll
        for (int i = 0; i < 4; i++) { acc1[i][0] = (f32x4){0,0,0,0}; acc1[i][1] = (f32x4){0,0,0,0}; }

        const bf16x8* f1base = f1p + (size_t)((hc * 16 + w * 2) * 8) * 64 + lane;
        bf16x8 wA[2], wB[2];
        #pragma unroll
        for (int n = 0; n < 2; n++) wA[n] = f1base[(n * 8 + 0) * 64];

#define FC1_STEP(WREG, ks_)                                                   \
        {                                                                     \
            bf16x8 af[4];                                                     \
            _Pragma("unroll")                                                 \
            for (int i = 0; i < 4; i++)                                       \
                af[i] = *(const bf16x8*)((char*)Xl + (i * 16 + c) * XROW      \
                                         + g * 16 + (ks_) * 64);             \
            __builtin_amdgcn_s_setprio(1);                                    \
            _Pragma("unroll")                                                 \
            for (int i = 0; i < 4; i++)                                       \
                _Pragma("unroll")                                             \
                for (int n = 0; n < 2; n++)                                   \
                    acc1[i][n] = __builtin_amdgcn_mfma_f32_16x16x32_bf16(     \
                        WREG[n], af[i], acc1[i][n], 0, 0, 0);                 \
            __builtin_amdgcn_s_setprio(0);                                    \
        }

        #pragma unroll
        for (int ks = 0; ks < 8; ks += 2) {
            #pragma unroll
            for (int n = 0; n < 2; n++) wB[n] = f1base[(n * 8 + ks + 1) * 64];
            FC1_STEP(wA, ks)
            if (ks + 2 < 8) {
                #pragma unroll
                for (int n = 0; n < 2; n++) wA[n] = f1base[(n * 8 + ks + 2) * 64];
            }
            FC1_STEP(wB, ks + 1)
        }
#undef FC1_STEP

        #pragma unroll
        for (int i = 0; i < 4; i++) {
            int row = i * 16 + c;
            #pragma unroll
            for (int n = 0; n < 2; n++) {
                float4 b4 = *(const float4*)(f1b + hc * 256 + w * 32 + n * 16 + 4 * g);
                float h0 = gelu_s(acc1[i][n][0] + b4.x);
                float h1 = gelu_s(acc1[i][n][1] + b4.y);
                float h2 = gelu_s(acc1[i][n][2] + b4.z);
                float h3 = gelu_s(acc1[i][n][3] + b4.w);
                uint2 pk = { pk2(h0, h1), pk2(h2, h3) };
                *(uint2*)((char*)Hl + row * XROW + w * 64 + n * 32 + g * 8) = pk;
            }
        }
        __syncthreads();

        const bf16x8* f2base = f2p + (size_t)((w * 2) * 32 + hc * 8) * 64 + lane;
        #pragma unroll
        for (int n = 0; n < 2; n++) wA[n] = f2base[(n * 32 + 0) * 64];

#define FC2_STEP(WREG, ks_)                                                   \
        {                                                                     \
            bf16x8 ah[4];                                                     \
            _Pragma("unroll")                                                 \
            for (int i = 0; i < 4; i++)                                       \
                ah[i] = *(const bf16x8*)((char*)Hl + (i * 16 + c) * XROW      \
                                         + g * 16 + (ks_) * 64);             \
            __builtin_amdgcn_s_setprio(1);                                    \
            _Pragma("unroll")                                                 \
            for (int i = 0; i < 4; i++)                                       \
                _Pragma("unroll")                                             \
                for (int n = 0; n < 2; n++)                                   \
                    acc2[i][n] = __builtin_amdgcn_mfma_f32_16x16x32_bf16(     \
                        WREG[n], ah[i], acc2[i][n], 0, 0, 0);                 \
            __builtin_amdgcn_s_setprio(0);                                    \
        }

        #pragma unroll
        for (int ks = 0; ks < 8; ks += 2) {
            #pragma unroll
            for (int n = 0; n < 2; n++) wB[n] = f2base[(n * 32 + ks + 1) * 64];
            FC2_STEP(wA, ks)
            if (ks + 2 < 8) {
                #pragma unroll
                for (int n = 0; n < 2; n++) wA[n] = f2base[(n * 32 + ks + 2) * 64];
            }
            FC2_STEP(wB, ks + 1)
        }
#undef FC2_STEP
        __syncthreads();
    }

    #pragma unroll
    for (int i = 0; i < 4; i++) {
        int row = m0 + i * 16 + c;
        #pragma unroll
        for (int n = 0; n < 2; n++) {
            int col = w * 32 + n * 16 + 4 * g;
            float4 b4 = *(const float4*)(f2b + col);
            uint2 rr = *(const uint2*)(xb + (size_t)row * 256 + col);
            float4 ov = { acc2[i][n][0] + b4.x + bf2f((u16)rr.x),
                          acc2[i][n][1] + b4.y + bf2f((u16)(rr.x >> 16)),
                          acc2[i][n][2] + b4.z + bf2f((u16)rr.y),
                          acc2[i][n][3] + b4.w + bf2f((u16)(rr.y >> 16)) };
            *(float4*)(out + (size_t)row * 256 + col) = ov;
        }
    }
}

// -------------------------------------------------------------- launch ------
// Workspace (peak ~136 MB):
//   [0,       2.10M)  weights: qp kvp pp f1p f2p biasF
//   [2.10M,  35.65M)  xbw (bf16 x, attnproj out -> mlp in)
//   [35.65M, 69.21M)  Qb
//   [69.21M, 136.31M) KVb
extern "C" void kernel_launch(void* const* d_in, const int* in_sizes, int n_in,
                              void* d_out, int out_size, void* d_ws, size_t ws_size,
                              hipStream_t stream)
{
    const float* x1  = (const float*)d_in[0];
    const float* x2  = (const float*)d_in[1];
    const float* n1g = (const float*)d_in[2];
    const float* n1b = (const float*)d_in[3];
    const float* q_w = (const float*)d_in[4];
    const float* q_b = (const float*)d_in[5];
    const float* kv_w= (const float*)d_in[6];
    const float* kv_b= (const float*)d_in[7];
    const float* p_w = (const float*)d_in[8];
    const float* p_b = (const float*)d_in[9];
    const float* rel = (const float*)d_in[10];
    const float* n3g = (const float*)d_in[11];
    const float* n3b = (const float*)d_in[12];
    const float* f1w = (const float*)d_in[13];
    const float* f1b = (const float*)d_in[14];
    const float* f2w = (const float*)d_in[15];
    const float* f2b = (const float*)d_in[16];

    char* ws = (char*)d_ws;
    u16*   qp    = (u16*)(ws + 0);
    u16*   kvp   = (u16*)(ws + 131072);
    u16*   pp    = (u16*)(ws + 393216);
    u16*   f1p   = (u16*)(ws + 524288);
    u16*   f2p   = (u16*)(ws + 1048576);
    float* biasF = (float*)(ws + 1572864);

    u16*   xbw  = (u16*)(ws + 2097152);
    u16*   Qb   = (u16*)(ws + 35651584);
    u16*   KVb  = (u16*)(ws + 69206016);

    float* out = (float*)d_out;

    prep_k<<<3200, 256, 0, stream>>>(q_w, kv_w, p_w, f1w, f2w, rel,
                                     qp, kvp, pp, f1p, f2p, biasF);
    qkv_mega<<<1024, 512, 0, stream>>>(x1, x2, n1g, n1b, (const bf16x8*)qp,
                                       (const bf16x8*)kvp, q_b, kv_b, Qb, KVb);
    attnproj_mega<<<1024, 512, 0, stream>>>(Qb, KVb, biasF, (const bf16x8*)pp,
                                            p_b, x1, xbw);
    mlp_mega<<<1024, 512, 0, stream>>>(xbw, n3g, n3b, (const bf16x8*)f1p,
                                       (const bf16x8*)f2p, f1b, f2b, out);
}

// Round 15
// 241.585 us; speedup vs baseline: 1.3783x; 1.0294x over previous
//
#include <hip/hip_runtime.h>

typedef __bf16 bf16x8 __attribute__((ext_vector_type(8)));
typedef float f32x4 __attribute__((ext_vector_type(4)));
using u16 = unsigned short;

#define SCALE 0.17677669529663689f  // 32^-0.5
#define XROW 528                    // padded LDS row stride (264 u16)

__device__ __forceinline__ u16 f2bf(float f) {
    union { float f; unsigned u; } x; x.f = f;
    unsigned r = x.u + 0x7fffu + ((x.u >> 16) & 1u);
    return (u16)(r >> 16);
}
__device__ __forceinline__ unsigned pk2(float a, float b) {
    return (unsigned)f2bf(a) | ((unsigned)f2bf(b) << 16);
}
__device__ __forceinline__ float bf2f(u16 h) {
    union { unsigned u; float f; } x; x.u = ((unsigned)h) << 16; return x.f;
}
// gelu = x * sigmoid(1.5957691*(x + 0.044715 x^3))
__device__ __forceinline__ float gelu_s(float x) {
    float u = 1.5957691216057308f * x * (1.f + 0.044715f * x * x);
    float e = __expf(-u);
    return x / (1.f + e);
}

// ---------------------------------------------------------------- prep ------
// ALL weights fragment-packed (frag (ng,ks): lane l holds
// W[k=32ks+8(l>>4)+e][n=16ng+(l&15)]). biasF: rel-pos bias, swapped C-frag.
__global__ __launch_bounds__(256) void prep_k(
    const float* __restrict__ q_w, const float* __restrict__ kv_w,
    const float* __restrict__ p_w, const float* __restrict__ f1w,
    const float* __restrict__ f2w, const float* __restrict__ rel,
    u16* __restrict__ qp, u16* __restrict__ kvp, u16* __restrict__ pp,
    u16* __restrict__ f1p, u16* __restrict__ f2p, float* __restrict__ biasF)
{
    int t = blockIdx.x * 256 + threadIdx.x;
    if (t < 65536) {                                   // qp: 256x256
        int u = t;
        int e = u & 7, l = (u >> 3) & 63, ks = (u >> 9) & 7, ng = u >> 12;
        int k = ks * 32 + (l >> 4) * 8 + e;
        int n = ng * 16 + (l & 15);
        qp[u] = f2bf(q_w[k * 256 + n]);
    } else if (t < 196608) {                           // kvp: 256x512
        int u = t - 65536;
        int e = u & 7, l = (u >> 3) & 63, ks = (u >> 9) & 7, ng = u >> 12;
        int k = ks * 32 + (l >> 4) * 8 + e;
        int n = ng * 16 + (l & 15);
        kvp[u] = f2bf(kv_w[k * 512 + n]);
    } else if (t < 262144) {                           // pp: 256x256
        int u = t - 196608;
        int e = u & 7, l = (u >> 3) & 63, ks = (u >> 9) & 7, ng = u >> 12;
        int k = ks * 32 + (l >> 4) * 8 + e;
        int n = ng * 16 + (l & 15);
        pp[u] = f2bf(p_w[k * 256 + n]);
    } else if (t < 524288) {                           // f1p: 256x1024
        int u = t - 262144;
        int e = u & 7, l = (u >> 3) & 63, ks = (u >> 9) & 7, ng = u >> 12;
        int k = ks * 32 + (l >> 4) * 8 + e;
        int n = ng * 16 + (l & 15);
        f1p[u] = f2bf(f1w[k * 1024 + n]);
    } else if (t < 786432) {                           // f2p: 1024x256
        int u = t - 524288;
        int e = u & 7, l = (u >> 3) & 63, ks = (u >> 9) & 31, ng = u >> 14;
        int k = ks * 32 + (l >> 4) * 8 + e;
        int n = ng * 16 + (l & 15);
        f2p[u] = f2bf(f2w[k * 256 + n]);
    } else if (t < 819200) {                           // biasF 8*16*64*4
        int u = t - 786432;
        int r = u & 3, l = (u >> 2) & 63, fr = (u >> 8) & 15, h = u >> 12;
        int fi = fr >> 2, fj = fr & 3;
        int m = fi * 16 + (l & 15);
        int n = fj * 16 + 4 * (l >> 4) + r;
        int idx = ((m >> 3) - (n >> 3) + 7) * 15 + ((m & 7) - (n & 7) + 7);
        biasF[u] = rel[idx * 8 + h];
    }
}

// ------------------------------------------------------------ attn mega ------
// Block = 1 window, wave = head. LN1(x1,x2)->Xl; wave computes OWN head's
// Q/K/V (K=256, packed frags, C-layout); Q,K repacked C-layout->row-frag
// in-register (same shfl algebra as the verified P-repack); V scattered to
// Vt LDS. Then QK^T + bias + softmax + P-repack + PV + O->Olds + proj +
// window-reverse + f32 residual -> bf16 x. LDS phases aliased (73 KB).
__global__ __launch_bounds__(512, 3) void attn_mega(
    const float* __restrict__ x1, const float* __restrict__ x2,
    const float* __restrict__ gw, const float* __restrict__ bw,
    const bf16x8* __restrict__ qp, const bf16x8* __restrict__ kvp,
    const float* __restrict__ q_b, const float* __restrict__ kv_b,
    const float* __restrict__ biasF, const bf16x8* __restrict__ pp,
    const float* __restrict__ p_b, u16* __restrict__ xbw)
{
    __shared__ __align__(16) char SMEM[74752];
    u16* Xl0  = (u16*)SMEM;            // 33792 B   (phase 1-2)
    u16* Xl1  = (u16*)(SMEM + 33792);  // 33792 B   (phase 1-2)
    u16* VtA  = (u16*)SMEM;            // 40960 B   (phase 3; after bar2)
    u16* Olds = (u16*)(SMEM + 40960);  // 33792 B   (phase 3; after bar2)
    const int t = threadIdx.x, lane = t & 63, w = t >> 6;   // w = head
    const int g = lane >> 4, c = lane & 15;
    const int win = blockIdx.x;
    const int b_ = win >> 6, wh = (win >> 3) & 7, ww = win & 7;

    // ---- phase 1: LN of both streams (16 rows/wave over 128) ----
    {
        float4 gg = *(const float4*)(gw + lane * 4);
        float4 bb = *(const float4*)(bw + lane * 4);
        for (int it = 0; it < 16; it++) {
            int idx = w * 16 + it;
            int st = idx >> 6, n = idx & 63;
            const float* src = st ? x2 : x1;
            size_t srow = (size_t)b_ * 4096 + (wh * 8 + (n >> 3)) * 64 + ww * 8 + (n & 7);
            float4 v = *(const float4*)(src + srow * 256 + lane * 4);
            float s = v.x + v.y + v.z + v.w;
            float q = v.x * v.x + v.y * v.y + v.z * v.z + v.w * v.w;
            #pragma unroll
            for (int m = 1; m < 64; m <<= 1) {
                s += __shfl_xor(s, m, 64);
                q += __shfl_xor(q, m, 64);
            }
            float mean = s * (1.0f / 256.0f);
            float var  = q * (1.0f / 256.0f) - mean * mean;
            float rstd = rsqrtf(var + 1e-5f);
            float n0 = (v.x - mean) * rstd * gg.x + bb.x;
            float n1 = (v.y - mean) * rstd * gg.y + bb.y;
            float n2 = (v.z - mean) * rstd * gg.z + bb.z;
            float n3 = (v.w - mean) * rstd * gg.w + bb.w;
            uint2 pk = { pk2(n0, n1), pk2(n2, n3) };
            u16* dst = st ? Xl1 : Xl0;
            *(uint2*)((char*)dst + n * XROW + lane * 8) = pk;
        }
    }
    __syncthreads();   // bar1: Xl ready

    // ---- phase 2: own-head Q/K/V GEMMs (K=256) ----
    // C-layout->row-frag repack (verified P-repack algebra family):
    // target lane (c,g) elem e = dim 8g+e; src lane c+16*((2g)&3) (+16 e>=4),
    // reg r=e&3 (regs 0,1 -> w0, regs 2,3 -> w1), n-select g>=2.
    const int srcA = c + 16 * ((2 * g) & 3);
    const int srcB = srcA + 16;
    const bool nhi = (g >= 2);

#define GEMM256(acc, WPTR, NGBASE, XSRC)                                      \
    { _Pragma("unroll")                                                       \
      for (int i = 0; i < 4; i++) { acc[i][0] = (f32x4){0,0,0,0};             \
                                    acc[i][1] = (f32x4){0,0,0,0}; }           \
      _Pragma("unroll")                                                       \
      for (int ks = 0; ks < 8; ks++) {                                        \
          bf16x8 wf[2], af[4];                                                \
          _Pragma("unroll")                                                   \
          for (int n = 0; n < 2; n++)                                         \
              wf[n] = WPTR[(size_t)(((NGBASE) + n) * 8 + ks) * 64 + lane];    \
          _Pragma("unroll")                                                   \
          for (int i = 0; i < 4; i++)                                         \
              af[i] = *(const bf16x8*)((char*)XSRC + (i * 16 + c) * XROW      \
                                       + g * 16 + ks * 64);                   \
          __builtin_amdgcn_s_setprio(1);                                      \
          _Pragma("unroll")                                                   \
          for (int i = 0; i < 4; i++)                                         \
              _Pragma("unroll")                                               \
              for (int n = 0; n < 2; n++)                                     \
                  acc[i][n] = __builtin_amdgcn_mfma_f32_16x16x32_bf16(        \
                      wf[n], af[i], acc[i][n], 0, 0, 0);                      \
          __builtin_amdgcn_s_setprio(0);                                      \
      } }

#define ADDBIAS(acc, BPTR, CBASE)                                             \
    { _Pragma("unroll")                                                       \
      for (int i = 0; i < 4; i++)                                             \
          _Pragma("unroll")                                                   \
          for (int n = 0; n < 2; n++) {                                       \
              float4 b4 = *(const float4*)((BPTR) + (CBASE) + n * 16 + 4 * g);\
              acc[i][n][0] += b4.x; acc[i][n][1] += b4.y;                     \
              acc[i][n][2] += b4.z; acc[i][n][3] += b4.w;                     \
          } }

#define REPACK(acc, frag)                                                     \
    { unsigned w0_[4][2], w1_[4][2];                                          \
      _Pragma("unroll")                                                       \
      for (int i = 0; i < 4; i++)                                             \
          _Pragma("unroll")                                                   \
          for (int n = 0; n < 2; n++) {                                       \
              w0_[i][n] = pk2(acc[i][n][0], acc[i][n][1]);                    \
              w1_[i][n] = pk2(acc[i][n][2], acc[i][n][3]);                    \
          }                                                                   \
      _Pragma("unroll")                                                       \
      for (int i = 0; i < 4; i++) {                                           \
          unsigned x0a = __shfl(w0_[i][0], srcA), x0b = __shfl(w0_[i][1], srcA);\
          unsigned y0a = __shfl(w1_[i][0], srcA), y0b = __shfl(w1_[i][1], srcA);\
          unsigned x1a = __shfl(w0_[i][0], srcB), x1b = __shfl(w0_[i][1], srcB);\
          unsigned y1a = __shfl(w1_[i][0], srcB), y1b = __shfl(w1_[i][1], srcB);\
          union { uint4 u; bf16x8 v; } cv;                                    \
          cv.u.x = nhi ? x0b : x0a;                                           \
          cv.u.y = nhi ? y0b : y0a;                                           \
          cv.u.z = nhi ? x1b : x1a;                                           \
          cv.u.w = nhi ? y1b : y1a;                                           \
          frag[i] = cv.v;                                                     \
      } }

    bf16x8 qf[4], kf[4];
    f32x4 av[4][2];
    {
        f32x4 acc[4][2];
        GEMM256(acc, kvp, 2 * w, Xl1)            // K = head w's kv cols w*32..
        ADDBIAS(acc, kv_b, w * 32)
        REPACK(acc, kf)
        GEMM256(acc, qp, 2 * w, Xl0)             // Q
        ADDBIAS(acc, q_b, w * 32)
        REPACK(acc, qf)
        GEMM256(av, kvp, 16 + 2 * w, Xl1)        // V = kv cols 256 + w*32..
        ADDBIAS(av, kv_b, 256 + w * 32)
    }
    __syncthreads();   // bar2: all Xl reads done -> safe to write VtA/Olds

    // V scatter: Vt[d][key], padded 80 (same layout as verified SCAT)
    u16* vt = VtA + w * 32 * 80;
    #pragma unroll
    for (int i = 0; i < 4; i++)
        #pragma unroll
        for (int n = 0; n < 2; n++)
            #pragma unroll
            for (int r = 0; r < 4; r++)
                vt[(n * 16 + 4 * g + r) * 80 + i * 16 + c] = f2bf(av[i][n][r]);

    // QK^T (head dim 32 = 1 MFMA K-step); swapped mfma(K, Q)
    f32x4 s[4][4];
    #pragma unroll
    for (int i = 0; i < 4; i++)
        #pragma unroll
        for (int j = 0; j < 4; j++) {
            s[i][j] = (f32x4){0.f, 0.f, 0.f, 0.f};
            s[i][j] = __builtin_amdgcn_mfma_f32_16x16x32_bf16(kf[j], qf[i], s[i][j], 0, 0, 0);
        }

    // scale + rel-pos bias (frag layout, head = w)
    #pragma unroll
    for (int i = 0; i < 4; i++)
        #pragma unroll
        for (int j = 0; j < 4; j++) {
            f32x4 bf4 = *(const f32x4*)(biasF + ((size_t)(w * 16 + i * 4 + j) * 64 + lane) * 4);
            #pragma unroll
            for (int r = 0; r < 4; r++) s[i][j][r] = s[i][j][r] * SCALE + bf4[r];
        }

    // softmax over keys
    #pragma unroll
    for (int i = 0; i < 4; i++) {
        float mx = -1e30f;
        #pragma unroll
        for (int j = 0; j < 4; j++)
            #pragma unroll
            for (int r = 0; r < 4; r++) mx = fmaxf(mx, s[i][j][r]);
        mx = fmaxf(mx, __shfl_xor(mx, 16, 64));
        mx = fmaxf(mx, __shfl_xor(mx, 32, 64));
        float sum = 0.f;
        #pragma unroll
        for (int j = 0; j < 4; j++)
            #pragma unroll
            for (int r = 0; r < 4; r++) {
                float e = __expf(s[i][j][r] - mx);
                s[i][j][r] = e; sum += e;
            }
        sum += __shfl_xor(sum, 16, 64);
        sum += __shfl_xor(sum, 32, 64);
        float inv = 1.f / sum;
        #pragma unroll
        for (int j = 0; j < 4; j++)
            #pragma unroll
            for (int r = 0; r < 4; r++) s[i][j][r] *= inv;
    }

    // P repack (verified): keys 32ks+8g+e from reg pair 2ks(+1), lanes srcA/B
    unsigned pw0[4][4], pw1[4][4];
    #pragma unroll
    for (int i = 0; i < 4; i++)
        #pragma unroll
        for (int j = 0; j < 4; j++) {
            pw0[i][j] = pk2(s[i][j][0], s[i][j][1]);
            pw1[i][j] = pk2(s[i][j][2], s[i][j][3]);
        }
    f32x4 o[4][2];
    #pragma unroll
    for (int i = 0; i < 4; i++) { o[i][0] = (f32x4){0,0,0,0}; o[i][1] = (f32x4){0,0,0,0}; }
    #pragma unroll
    for (int ks = 0; ks < 2; ks++) {
        bf16x8 pa[4], vb[2];
        #pragma unroll
        for (int i = 0; i < 4; i++) {
            unsigned a0 = __shfl(pw0[i][2 * ks], srcA), b0 = __shfl(pw0[i][2 * ks + 1], srcA);
            unsigned a1 = __shfl(pw1[i][2 * ks], srcA), b1 = __shfl(pw1[i][2 * ks + 1], srcA);
            unsigned a2 = __shfl(pw0[i][2 * ks], srcB), b2 = __shfl(pw0[i][2 * ks + 1], srcB);
            unsigned a3 = __shfl(pw1[i][2 * ks], srcB), b3 = __shfl(pw1[i][2 * ks + 1], srcB);
            union { uint4 u; bf16x8 v; } cv;
            cv.u.x = nhi ? b0 : a0;
            cv.u.y = nhi ? b1 : a1;
            cv.u.z = nhi ? b2 : a2;
            cv.u.w = nhi ? b3 : a3;
            pa[i] = cv.v;
        }
        #pragma unroll
        for (int j = 0; j < 2; j++) {
            int d = j * 16 + c;
            vb[j] = *(const bf16x8*)(vt + d * 80 + ks * 32 + 8 * g);
        }
        #pragma unroll
        for (int i = 0; i < 4; i++)
            #pragma unroll
            for (int j = 0; j < 2; j++)
                o[i][j] = __builtin_amdgcn_mfma_f32_16x16x32_bf16(vb[j], pa[i], o[i][j], 0, 0, 0);
    }

    // O -> Olds (bf16, padded-linear; head w cols w*32..+32)
    #pragma unroll
    for (int i = 0; i < 4; i++) {
        int row = i * 16 + c;
        #pragma unroll
        for (int j = 0; j < 2; j++) {
            uint2 pk = { pk2(o[i][j][0], o[i][j][1]), pk2(o[i][j][2], o[i][j][3]) };
            *(uint2*)((char*)Olds + row * XROW + w * 64 + j * 32 + g * 8) = pk;
        }
    }
    __syncthreads();   // bar3: all heads' O in Olds

    // proj: wave w -> out cols w*32..+32, K=256 from Olds
    f32x4 ap[4][2];
    #pragma unroll
    for (int i = 0; i < 4; i++) { ap[i][0] = (f32x4){0,0,0,0}; ap[i][1] = (f32x4){0,0,0,0}; }
    #pragma unroll
    for (int ks = 0; ks < 8; ks++) {
        bf16x8 wf[2], ah[4];
        #pragma unroll
        for (int n = 0; n < 2; n++)
            wf[n] = pp[(size_t)((w * 2 + n) * 8 + ks) * 64 + lane];
        #pragma unroll
        for (int i = 0; i < 4; i++)
            ah[i] = *(const bf16x8*)((char*)Olds + (i * 16 + c) * XROW
                                     + g * 16 + ks * 64);
        __builtin_amdgcn_s_setprio(1);
        #pragma unroll
        for (int i = 0; i < 4; i++)
            #pragma unroll
            for (int n = 0; n < 2; n++)
                ap[i][n] = __builtin_amdgcn_mfma_f32_16x16x32_bf16(
                    wf[n], ah[i], ap[i][n], 0, 0, 0);
        __builtin_amdgcn_s_setprio(0);
    }

    // epilogue: window-reverse + f32 residual -> bf16 x
    #pragma unroll
    for (int i = 0; i < 4; i++) {
        int n = i * 16 + c;
        size_t nrow = (size_t)b_ * 4096 + (wh * 8 + (n >> 3)) * 64 + ww * 8 + (n & 7);
        #pragma unroll
        for (int j = 0; j < 2; j++) {
            int col = w * 32 + j * 16 + 4 * g;
            float4 b4 = *(const float4*)(p_b + col);
            float4 r4 = *(const float4*)(x1 + nrow * 256 + col);
            uint2 pk = { pk2(ap[i][j][0] + b4.x + r4.x, ap[i][j][1] + b4.y + r4.y),
                         pk2(ap[i][j][2] + b4.z + r4.z, ap[i][j][3] + b4.w + r4.w) };
            *(uint2*)(xbw + nrow * 256 + col) = pk;
        }
    }
#undef GEMM256
#undef ADDBIAS
#undef REPACK
}

// ------------------------------------------------------------ MLP mega ------
// (R13 verified) out = x + fc2(gelu(fc1(LN(x)))), x bf16. 64 rows/block,
// 8 waves, padded-linear LDS, wA/wB weight dbuf + setprio.
__global__ __launch_bounds__(512, 4) void mlp_mega(
    const u16* __restrict__ xb, const float* __restrict__ gw,
    const float* __restrict__ bw, const bf16x8* __restrict__ f1p,
    const bf16x8* __restrict__ f2p, const float* __restrict__ f1b,
    const float* __restrict__ f2b, float* __restrict__ out)
{
    __shared__ __align__(16) u16 Xl[64 * 264];
    __shared__ __align__(16) u16 Hl[64 * 264];
    const int t = threadIdx.x, lane = t & 63, w = t >> 6;
    const int g = lane >> 4, c = lane & 15;
    const int m0 = blockIdx.x * 64;

    {
        float4 gg = *(const float4*)(gw + lane * 4);
        float4 bb = *(const float4*)(bw + lane * 4);
        for (int it = 0; it < 8; it++) {
            int row = w * 8 + it;
            uint2 rv = *(const uint2*)(xb + (size_t)(m0 + row) * 256 + lane * 4);
            float v0 = bf2f((u16)rv.x), v1 = bf2f((u16)(rv.x >> 16));
            float v2 = bf2f((u16)rv.y), v3 = bf2f((u16)(rv.y >> 16));
            float s = v0 + v1 + v2 + v3;
            float q = v0 * v0 + v1 * v1 + v2 * v2 + v3 * v3;
            #pragma unroll
            for (int m = 1; m < 64; m <<= 1) {
                s += __shfl_xor(s, m, 64);
                q += __shfl_xor(q, m, 64);
            }
            float mean = s * (1.0f / 256.0f);
            float var  = q * (1.0f / 256.0f) - mean * mean;
            float rstd = rsqrtf(var + 1e-5f);
            float n0 = (v0 - mean) * rstd * gg.x + bb.x;
            float n1 = (v1 - mean) * rstd * gg.y + bb.y;
            float n2 = (v2 - mean) * rstd * gg.z + bb.z;
            float n3 = (v3 - mean) * rstd * gg.w + bb.w;
            uint2 pk = { pk2(n0, n1), pk2(n2, n3) };
            *(uint2*)((char*)Xl + row * XROW + lane * 8) = pk;
        }
    }
    __syncthreads();

    f32x4 acc2[4][2];
    #pragma unroll
    for (int i = 0; i < 4; i++) { acc2[i][0] = (f32x4){0,0,0,0}; acc2[i][1] = (f32x4){0,0,0,0}; }

    #pragma unroll
    for (int hc = 0; hc < 4; hc++) {
        f32x4 acc1[4][2];
        #pragma unroll
        for (int i = 0; i < 4; i++) { acc1[i][0] = (f32x4){0,0,0,0}; acc1[i][1] = (f32x4){0,0,0,0}; }

        const bf16x8* f1base = f1p + (size_t)((hc * 16 + w * 2) * 8) * 64 + lane;
        bf16x8 wA[2], wB[2];
        #pragma unroll
        for (int n = 0; n < 2; n++) wA[n] = f1base[(n * 8 + 0) * 64];

#define FC1_STEP(WREG, ks_)                                                   \
        {                                                                     \
            bf16x8 af[4];                                                     \
            _Pragma("unroll")                                                 \
            for (int i = 0; i < 4; i++)                                       \
                af[i] = *(const bf16x8*)((char*)Xl + (i * 16 + c) * XROW      \
                                         + g * 16 + (ks_) * 64);             \
            __builtin_amdgcn_s_setprio(1);                                    \
            _Pragma("unroll")                                                 \
            for (int i = 0; i < 4; i++)                                       \
                _Pragma("unroll")                                             \
                for (int n = 0; n < 2; n++)                                   \
                    acc1[i][n] = __builtin_amdgcn_mfma_f32_16x16x32_bf16(     \
                        WREG[n], af[i], acc1[i][n], 0, 0, 0);                 \
            __builtin_amdgcn_s_setprio(0);                                    \
        }

        #pragma unroll
        for (int ks = 0; ks < 8; ks += 2) {
            #pragma unroll
            for (int n = 0; n < 2; n++) wB[n] = f1base[(n * 8 + ks + 1) * 64];
            FC1_STEP(wA, ks)
            if (ks + 2 < 8) {
                #pragma unroll
                for (int n = 0; n < 2; n++) wA[n] = f1base[(n * 8 + ks + 2) * 64];
            }
            FC1_STEP(wB, ks + 1)
        }
#undef FC1_STEP

        #pragma unroll
        for (int i = 0; i < 4; i++) {
            int row = i * 16 + c;
            #pragma unroll
            for (int n = 0; n < 2; n++) {
                float4 b4 = *(const float4*)(f1b + hc * 256 + w * 32 + n * 16 + 4 * g);
                float h0 = gelu_s(acc1[i][n][0] + b4.x);
                float h1 = gelu_s(acc1[i][n][1] + b4.y);
                float h2 = gelu_s(acc1[i][n][2] + b4.z);
                float h3 = gelu_s(acc1[i][n][3] + b4.w);
                uint2 pk = { pk2(h0, h1), pk2(h2, h3) };
                *(uint2*)((char*)Hl + row * XROW + w * 64 + n * 32 + g * 8) = pk;
            }
        }
        __syncthreads();

        const bf16x8* f2base = f2p + (size_t)((w * 2) * 32 + hc * 8) * 64 + lane;
        #pragma unroll
        for (int n = 0; n < 2; n++) wA[n] = f2base[(n * 32 + 0) * 64];

#define FC2_STEP(WREG, ks_)                                                   \
        {                                                                     \
            bf16x8 ah[4];                                                     \
            _Pragma("unroll")                                                 \
            for (int i = 0; i < 4; i++)                                       \
                ah[i] = *(const bf16x8*)((char*)Hl + (i * 16 + c) * XROW      \
                                         + g * 16 + (ks_) * 64);             \
            __builtin_amdgcn_s_setprio(1);                                    \
            _Pragma("unroll")                                                 \
            for (int i = 0; i < 4; i++)                                       \
                _Pragma("unroll")                                             \
                for (int n = 0; n < 2; n++)                                   \
                    acc2[i][n] = __builtin_amdgcn_mfma_f32_16x16x32_bf16(     \
                        WREG[n], ah[i], acc2[i][n], 0, 0, 0);                 \
            __builtin_amdgcn_s_setprio(0);                                    \
        }

        #pragma unroll
        for (int ks = 0; ks < 8; ks += 2) {
            #pragma unroll
            for (int n = 0; n < 2; n++) wB[n] = f2base[(n * 32 + ks + 1) * 64];
            FC2_STEP(wA, ks)
            if (ks + 2 < 8) {
                #pragma unroll
                for (int n = 0; n < 2; n++) wA[n] = f2base[(n * 32 + ks + 2) * 64];
            }
            FC2_STEP(wB, ks + 1)
        }
#undef FC2_STEP
        __syncthreads();
    }

    #pragma unroll
    for (int i = 0; i < 4; i++) {
        int row = m0 + i * 16 + c;
        #pragma unroll
        for (int n = 0; n < 2; n++) {
            int col = w * 32 + n * 16 + 4 * g;
            float4 b4 = *(const float4*)(f2b + col);
            uint2 rr = *(const uint2*)(xb + (size_t)row * 256 + col);
            float4 ov = { acc2[i][n][0] + b4.x + bf2f((u16)rr.x),
                          acc2[i][n][1] + b4.y + bf2f((u16)(rr.x >> 16)),
                          acc2[i][n][2] + b4.z + bf2f((u16)rr.y),
                          acc2[i][n][3] + b4.w + bf2f((u16)(rr.y >> 16)) };
            *(float4*)(out + (size_t)row * 256 + col) = ov;
        }
    }
}

// -------------------------------------------------------------- launch ------
// Workspace (peak ~36 MB):
//   [0,       2.10M)  weights: qp kvp pp f1p f2p biasF
//   [2.10M,  35.65M)  xbw (bf16 x, attn_mega out -> mlp in)
extern "C" void kernel_launch(void* const* d_in, const int* in_sizes, int n_in,
                              void* d_out, int out_size, void* d_ws, size_t ws_size,
                              hipStream_t stream)
{
    const float* x1  = (const float*)d_in[0];
    const float* x2  = (const float*)d_in[1];
    const float* n1g = (const float*)d_in[2];
    const float* n1b = (const float*)d_in[3];
    const float* q_w = (const float*)d_in[4];
    const float* q_b = (const float*)d_in[5];
    const float* kv_w= (const float*)d_in[6];
    const float* kv_b= (const float*)d_in[7];
    const float* p_w = (const float*)d_in[8];
    const float* p_b = (const float*)d_in[9];
    const float* rel = (const float*)d_in[10];
    const float* n3g = (const float*)d_in[11];
    const float* n3b = (const float*)d_in[12];
    const float* f1w = (const float*)d_in[13];
    const float* f1b = (const float*)d_in[14];
    const float* f2w = (const float*)d_in[15];
    const float* f2b = (const float*)d_in[16];

    char* ws = (char*)d_ws;
    u16*   qp    = (u16*)(ws + 0);
    u16*   kvp   = (u16*)(ws + 131072);
    u16*   pp    = (u16*)(ws + 393216);
    u16*   f1p   = (u16*)(ws + 524288);
    u16*   f2p   = (u16*)(ws + 1048576);
    float* biasF = (float*)(ws + 1572864);
    u16*   xbw   = (u16*)(ws + 2097152);

    float* out = (float*)d_out;

    prep_k<<<3200, 256, 0, stream>>>(q_w, kv_w, p_w, f1w, f2w, rel,
                                     qp, kvp, pp, f1p, f2p, biasF);
    attn_mega<<<1024, 512, 0, stream>>>(x1, x2, n1g, n1b, (const bf16x8*)qp,
                                        (const bf16x8*)kvp, q_b, kv_b, biasF,
                                        (const bf16x8*)pp, p_b, xbw);
    mlp_mega<<<1024, 512, 0, stream>>>(xbw, n3g, n3b, (const bf16x8*)f1p,
                                       (const bf16x8*)f2p, f1b, f2b, out);
}

// Round 17
// 222.651 us; speedup vs baseline: 1.4956x; 1.0850x over previous
//
#include <hip/hip_runtime.h>

typedef __bf16 bf16x8 __attribute__((ext_vector_type(8)));
typedef float f32x4 __attribute__((ext_vector_type(4)));
using u16 = unsigned short;

#define SCALE 0.17677669529663689f  // 32^-0.5
#define XROW 528                    // padded LDS row stride (264 u16)

// Native bf16 casts (RTNE) -> compiler fuses pairs into v_cvt_pk_bf16_f32.
__device__ __forceinline__ u16 f2bf(float f) {
    union { __bf16 h; u16 u; } x; x.h = (__bf16)f; return x.u;
}
__device__ __forceinline__ unsigned pk2(float a, float b) {
    union { struct { __bf16 lo, hi; } s; unsigned u; } x;
    x.s.lo = (__bf16)a; x.s.hi = (__bf16)b; return x.u;
}
__device__ __forceinline__ float bf2f(u16 h) {
    union { unsigned u; float f; } x; x.u = ((unsigned)h) << 16; return x.f;
}
// gelu = x * sigmoid(1.5957691*(x+0.044715x^3)); exp folded to native exp2
__device__ __forceinline__ float gelu_s(float x) {
    float u = 2.3022150048054216f * x * (1.f + 0.044715f * x * x); // *log2(e)
    float e = exp2f(-u);
    return x / (1.f + e);
}

// ---------------------------------------------------------------- prep ------
// ALL weights fragment-packed (frag (ng,ks): lane l holds
// W[k=32ks+8(l>>4)+e][n=16ng+(l&15)]). biasF: rel-pos bias, swapped C-frag.
__global__ __launch_bounds__(256) void prep_k(
    const float* __restrict__ q_w, const float* __restrict__ kv_w,
    const float* __restrict__ p_w, const float* __restrict__ f1w,
    const float* __restrict__ f2w, const float* __restrict__ rel,
    u16* __restrict__ qp, u16* __restrict__ kvp, u16* __restrict__ pp,
    u16* __restrict__ f1p, u16* __restrict__ f2p, float* __restrict__ biasF)
{
    int t = blockIdx.x * 256 + threadIdx.x;
    if (t < 65536) {                                   // qp: 256x256
        int u = t;
        int e = u & 7, l = (u >> 3) & 63, ks = (u >> 9) & 7, ng = u >> 12;
        int k = ks * 32 + (l >> 4) * 8 + e;
        int n = ng * 16 + (l & 15);
        qp[u] = f2bf(q_w[k * 256 + n]);
    } else if (t < 196608) {                           // kvp: 256x512
        int u = t - 65536;
        int e = u & 7, l = (u >> 3) & 63, ks = (u >> 9) & 7, ng = u >> 12;
        int k = ks * 32 + (l >> 4) * 8 + e;
        int n = ng * 16 + (l & 15);
        kvp[u] = f2bf(kv_w[k * 512 + n]);
    } else if (t < 262144) {                           // pp: 256x256
        int u = t - 196608;
        int e = u & 7, l = (u >> 3) & 63, ks = (u >> 9) & 7, ng = u >> 12;
        int k = ks * 32 + (l >> 4) * 8 + e;
        int n = ng * 16 + (l & 15);
        pp[u] = f2bf(p_w[k * 256 + n]);
    } else if (t < 524288) {                           // f1p: 256x1024
        int u = t - 262144;
        int e = u & 7, l = (u >> 3) & 63, ks = (u >> 9) & 7, ng = u >> 12;
        int k = ks * 32 + (l >> 4) * 8 + e;
        int n = ng * 16 + (l & 15);
        f1p[u] = f2bf(f1w[k * 1024 + n]);
    } else if (t < 786432) {                           // f2p: 1024x256
        int u = t - 524288;
        int e = u & 7, l = (u >> 3) & 63, ks = (u >> 9) & 31, ng = u >> 14;
        int k = ks * 32 + (l >> 4) * 8 + e;
        int n = ng * 16 + (l & 15);
        f2p[u] = f2bf(f2w[k * 256 + n]);
    } else if (t < 819200) {                           // biasF 8*16*64*4
        int u = t - 786432;
        int r = u & 3, l = (u >> 2) & 63, fr = (u >> 8) & 15, h = u >> 12;
        int fi = fr >> 2, fj = fr & 3;
        int m = fi * 16 + (l & 15);
        int n = fj * 16 + 4 * (l >> 4) + r;
        int idx = ((m >> 3) - (n >> 3) + 7) * 15 + ((m & 7) - (n & 7) + 7);
        biasF[u] = rel[idx * 8 + h];
    }
}

// Fast LN of one 256-col row per 16-lane group: lane owns 16 contiguous
// cols; 4-level shfl_xor reduce; emits 16 bf16 (2x uint4). NOTE: internal
// temporaries renamed o0_/o1_ (R16 bug: they shadowed the caller's o0/o1).
#define LN_ROW16(SRCP, GG, BB, OUT0, OUT1)                                    \
    {                                                                         \
        float4 v0 = *(const float4*)(SRCP);                                   \
        float4 v1 = *(const float4*)(SRCP + 4);                               \
        float4 v2 = *(const float4*)(SRCP + 8);                               \
        float4 v3 = *(const float4*)(SRCP + 12);                              \
        float s = (v0.x + v0.y + v0.z + v0.w) + (v1.x + v1.y + v1.z + v1.w)   \
                + (v2.x + v2.y + v2.z + v2.w) + (v3.x + v3.y + v3.z + v3.w);  \
        float q = v0.x*v0.x + v0.y*v0.y + v0.z*v0.z + v0.w*v0.w               \
                + v1.x*v1.x + v1.y*v1.y + v1.z*v1.z + v1.w*v1.w               \
                + v2.x*v2.x + v2.y*v2.y + v2.z*v2.z + v2.w*v2.w               \
                + v3.x*v3.x + v3.y*v3.y + v3.z*v3.z + v3.w*v3.w;              \
        _Pragma("unroll")                                                     \
        for (int m_ = 1; m_ <= 8; m_ <<= 1) {                                 \
            s += __shfl_xor(s, m_, 64);                                       \
            q += __shfl_xor(q, m_, 64);                                       \
        }                                                                     \
        float mean = s * (1.0f / 256.0f);                                     \
        float rstd = rsqrtf(q * (1.0f / 256.0f) - mean * mean + 1e-5f);       \
        uint4 o0_, o1_;                                                       \
        o0_.x = pk2((v0.x-mean)*rstd*GG[0].x+BB[0].x, (v0.y-mean)*rstd*GG[0].y+BB[0].y); \
        o0_.y = pk2((v0.z-mean)*rstd*GG[0].z+BB[0].z, (v0.w-mean)*rstd*GG[0].w+BB[0].w); \
        o0_.z = pk2((v1.x-mean)*rstd*GG[1].x+BB[1].x, (v1.y-mean)*rstd*GG[1].y+BB[1].y); \
        o0_.w = pk2((v1.z-mean)*rstd*GG[1].z+BB[1].z, (v1.w-mean)*rstd*GG[1].w+BB[1].w); \
        o1_.x = pk2((v2.x-mean)*rstd*GG[2].x+BB[2].x, (v2.y-mean)*rstd*GG[2].y+BB[2].y); \
        o1_.y = pk2((v2.z-mean)*rstd*GG[2].z+BB[2].z, (v2.w-mean)*rstd*GG[2].w+BB[2].w); \
        o1_.z = pk2((v3.x-mean)*rstd*GG[3].x+BB[3].x, (v3.y-mean)*rstd*GG[3].y+BB[3].y); \
        o1_.w = pk2((v3.z-mean)*rstd*GG[3].z+BB[3].z, (v3.w-mean)*rstd*GG[3].w+BB[3].w); \
        OUT0 = o0_; OUT1 = o1_;                                               \
    }

// ------------------------------------------------------------ attn mega ------
// Block = 1 window, wave = head. LN1(x1,x2)->Xl; own-head Q/K/V GEMMs
// (K=256, packed frags); Q,K repacked C-layout->row-frag via shfl; V->Vt
// LDS; QK^T + bias + softmax + P-repack + PV + O->Olds + proj + window-
// reverse + f32 residual -> bf16 x. LDS phases aliased (73 KB).
__global__ __launch_bounds__(512, 3) void attn_mega(
    const float* __restrict__ x1, const float* __restrict__ x2,
    const float* __restrict__ gw, const float* __restrict__ bw,
    const bf16x8* __restrict__ qp, const bf16x8* __restrict__ kvp,
    const float* __restrict__ q_b, const float* __restrict__ kv_b,
    const float* __restrict__ biasF, const bf16x8* __restrict__ pp,
    const float* __restrict__ p_b, u16* __restrict__ xbw)
{
    __shared__ __align__(16) char SMEM[74752];
    u16* Xl0  = (u16*)SMEM;            // 33792 B   (phase 1-2)
    u16* Xl1  = (u16*)(SMEM + 33792);  // 33792 B   (phase 1-2)
    u16* VtA  = (u16*)SMEM;            // 40960 B   (phase 3; after bar2)
    u16* Olds = (u16*)(SMEM + 40960);  // 33792 B   (phase 3; after bar2)
    const int t = threadIdx.x, lane = t & 63, w = t >> 6;   // w = head
    const int g = lane >> 4, c = lane & 15;
    const int win = blockIdx.x;
    const int b_ = win >> 6, wh = (win >> 3) & 7, ww = win & 7;

    // ---- phase 1: LN of both streams; 4 rows/iter (16-lane groups) ----
    {
        const int ln_sub = lane >> 4, ln_c = lane & 15;
        float4 GG[4], BB[4];
        #pragma unroll
        for (int j = 0; j < 4; j++) {
            GG[j] = *(const float4*)(gw + ln_c * 16 + j * 4);
            BB[j] = *(const float4*)(bw + ln_c * 16 + j * 4);
        }
        #pragma unroll
        for (int it = 0; it < 4; it++) {
            int idx = w * 16 + it * 4 + ln_sub;    // 0..127
            int st = idx >> 6, n = idx & 63;
            const float* src = st ? x2 : x1;
            size_t srow = (size_t)b_ * 4096 + (wh * 8 + (n >> 3)) * 64 + ww * 8 + (n & 7);
            const float* p = src + srow * 256 + ln_c * 16;
            uint4 o0, o1;
            LN_ROW16(p, GG, BB, o0, o1)
            u16* dst = st ? Xl1 : Xl0;
            char* base = (char*)dst + n * XROW + ln_c * 32;
            *(uint4*)(base) = o0;
            *(uint4*)(base + 16) = o1;
        }
    }
    __syncthreads();   // bar1: Xl ready

    // ---- phase 2: own-head Q/K/V GEMMs (K=256) ----
    const int srcA = c + 16 * ((2 * g) & 3);
    const int srcB = srcA + 16;
    const bool nhi = (g >= 2);

#define GEMM256(acc, WPTR, NGBASE, XSRC)                                      \
    { _Pragma("unroll")                                                       \
      for (int i = 0; i < 4; i++) { acc[i][0] = (f32x4){0,0,0,0};             \
                                    acc[i][1] = (f32x4){0,0,0,0}; }           \
      _Pragma("unroll")                                                       \
      for (int ks = 0; ks < 8; ks++) {                                        \
          bf16x8 wf[2], af[4];                                                \
          _Pragma("unroll")                                                   \
          for (int n = 0; n < 2; n++)                                         \
              wf[n] = WPTR[(size_t)(((NGBASE) + n) * 8 + ks) * 64 + lane];    \
          _Pragma("unroll")                                                   \
          for (int i = 0; i < 4; i++)                                         \
              af[i] = *(const bf16x8*)((char*)XSRC + (i * 16 + c) * XROW      \
                                       + g * 16 + ks * 64);                   \
          __builtin_amdgcn_s_setprio(1);                                      \
          _Pragma("unroll")                                                   \
          for (int i = 0; i < 4; i++)                                         \
              _Pragma("unroll")                                               \
              for (int n = 0; n < 2; n++)                                     \
                  acc[i][n] = __builtin_amdgcn_mfma_f32_16x16x32_bf16(        \
                      wf[n], af[i], acc[i][n], 0, 0, 0);                      \
          __builtin_amdgcn_s_setprio(0);                                      \
      } }

#define ADDBIAS(acc, BPTR, CBASE)                                             \
    { _Pragma("unroll")                                                       \
      for (int i = 0; i < 4; i++)                                             \
          _Pragma("unroll")                                                   \
          for (int n = 0; n < 2; n++) {                                       \
              float4 b4 = *(const float4*)((BPTR) + (CBASE) + n * 16 + 4 * g);\
              acc[i][n][0] += b4.x; acc[i][n][1] += b4.y;                     \
              acc[i][n][2] += b4.z; acc[i][n][3] += b4.w;                     \
          } }

#define REPACK(acc, frag)                                                     \
    { unsigned w0_[4][2], w1_[4][2];                                          \
      _Pragma("unroll")                                                       \
      for (int i = 0; i < 4; i++)                                             \
          _Pragma("unroll")                                                   \
          for (int n = 0; n < 2; n++) {                                       \
              w0_[i][n] = pk2(acc[i][n][0], acc[i][n][1]);                    \
              w1_[i][n] = pk2(acc[i][n][2], acc[i][n][3]);                    \
          }                                                                   \
      _Pragma("unroll")                                                       \
      for (int i = 0; i < 4; i++) {                                           \
          unsigned x0a = __shfl(w0_[i][0], srcA), x0b = __shfl(w0_[i][1], srcA);\
          unsigned y0a = __shfl(w1_[i][0], srcA), y0b = __shfl(w1_[i][1], srcA);\
          unsigned x1a = __shfl(w0_[i][0], srcB), x1b = __shfl(w0_[i][1], srcB);\
          unsigned y1a = __shfl(w1_[i][0], srcB), y1b = __shfl(w1_[i][1], srcB);\
          union { uint4 u; bf16x8 v; } cv;                                    \
          cv.u.x = nhi ? x0b : x0a;                                           \
          cv.u.y = nhi ? y0b : y0a;                                           \
          cv.u.z = nhi ? x1b : x1a;                                           \
          cv.u.w = nhi ? y1b : y1a;                                           \
          frag[i] = cv.v;                                                     \
      } }

    bf16x8 qf[4], kf[4];
    f32x4 av[4][2];
    {
        f32x4 acc[4][2];
        GEMM256(acc, kvp, 2 * w, Xl1)            // K
        ADDBIAS(acc, kv_b, w * 32)
        REPACK(acc, kf)
        GEMM256(acc, qp, 2 * w, Xl0)             // Q
        ADDBIAS(acc, q_b, w * 32)
        REPACK(acc, qf)
        GEMM256(av, kvp, 16 + 2 * w, Xl1)        // V
        ADDBIAS(av, kv_b, 256 + w * 32)
    }
    __syncthreads();   // bar2: Xl reads done -> safe to write VtA/Olds

    // V scatter: Vt[d][key], padded 80
    u16* vt = VtA + w * 32 * 80;
    #pragma unroll
    for (int i = 0; i < 4; i++)
        #pragma unroll
        for (int n = 0; n < 2; n++)
            #pragma unroll
            for (int r = 0; r < 4; r++)
                vt[(n * 16 + 4 * g + r) * 80 + i * 16 + c] = f2bf(av[i][n][r]);

    // QK^T; swapped mfma(K, Q)
    f32x4 s[4][4];
    #pragma unroll
    for (int i = 0; i < 4; i++)
        #pragma unroll
        for (int j = 0; j < 4; j++) {
            s[i][j] = (f32x4){0.f, 0.f, 0.f, 0.f};
            s[i][j] = __builtin_amdgcn_mfma_f32_16x16x32_bf16(kf[j], qf[i], s[i][j], 0, 0, 0);
        }

    // scale + rel-pos bias
    #pragma unroll
    for (int i = 0; i < 4; i++)
        #pragma unroll
        for (int j = 0; j < 4; j++) {
            f32x4 bf4 = *(const f32x4*)(biasF + ((size_t)(w * 16 + i * 4 + j) * 64 + lane) * 4);
            #pragma unroll
            for (int r = 0; r < 4; r++) s[i][j][r] = s[i][j][r] * SCALE + bf4[r];
        }

    // softmax over keys
    #pragma unroll
    for (int i = 0; i < 4; i++) {
        float mx = -1e30f;
        #pragma unroll
        for (int j = 0; j < 4; j++)
            #pragma unroll
            for (int r = 0; r < 4; r++) mx = fmaxf(mx, s[i][j][r]);
        mx = fmaxf(mx, __shfl_xor(mx, 16, 64));
        mx = fmaxf(mx, __shfl_xor(mx, 32, 64));
        float sum = 0.f;
        #pragma unroll
        for (int j = 0; j < 4; j++)
            #pragma unroll
            for (int r = 0; r < 4; r++) {
                float e = __expf(s[i][j][r] - mx);
                s[i][j][r] = e; sum += e;
            }
        sum += __shfl_xor(sum, 16, 64);
        sum += __shfl_xor(sum, 32, 64);
        float inv = 1.f / sum;
        #pragma unroll
        for (int j = 0; j < 4; j++)
            #pragma unroll
            for (int r = 0; r < 4; r++) s[i][j][r] *= inv;
    }

    // P repack + PV
    unsigned pw0[4][4], pw1[4][4];
    #pragma unroll
    for (int i = 0; i < 4; i++)
        #pragma unroll
        for (int j = 0; j < 4; j++) {
            pw0[i][j] = pk2(s[i][j][0], s[i][j][1]);
            pw1[i][j] = pk2(s[i][j][2], s[i][j][3]);
        }
    f32x4 o[4][2];
    #pragma unroll
    for (int i = 0; i < 4; i++) { o[i][0] = (f32x4){0,0,0,0}; o[i][1] = (f32x4){0,0,0,0}; }
    #pragma unroll
    for (int ks = 0; ks < 2; ks++) {
        bf16x8 pa[4], vb[2];
        #pragma unroll
        for (int i = 0; i < 4; i++) {
            unsigned a0 = __shfl(pw0[i][2 * ks], srcA), b0 = __shfl(pw0[i][2 * ks + 1], srcA);
            unsigned a1 = __shfl(pw1[i][2 * ks], srcA), b1 = __shfl(pw1[i][2 * ks + 1], srcA);
            unsigned a2 = __shfl(pw0[i][2 * ks], srcB), b2 = __shfl(pw0[i][2 * ks + 1], srcB);
            unsigned a3 = __shfl(pw1[i][2 * ks], srcB), b3 = __shfl(pw1[i][2 * ks + 1], srcB);
            union { uint4 u; bf16x8 v; } cv;
            cv.u.x = nhi ? b0 : a0;
            cv.u.y = nhi ? b1 : a1;
            cv.u.z = nhi ? b2 : a2;
            cv.u.w = nhi ? b3 : a3;
            pa[i] = cv.v;
        }
        #pragma unroll
        for (int j = 0; j < 2; j++) {
            int d = j * 16 + c;
            vb[j] = *(const bf16x8*)(vt + d * 80 + ks * 32 + 8 * g);
        }
        #pragma unroll
        for (int i = 0; i < 4; i++)
            #pragma unroll
            for (int j = 0; j < 2; j++)
                o[i][j] = __builtin_amdgcn_mfma_f32_16x16x32_bf16(vb[j], pa[i], o[i][j], 0, 0, 0);
    }

    // O -> Olds
    #pragma unroll
    for (int i = 0; i < 4; i++) {
        int row = i * 16 + c;
        #pragma unroll
        for (int j = 0; j < 2; j++) {
            uint2 pk = { pk2(o[i][j][0], o[i][j][1]), pk2(o[i][j][2], o[i][j][3]) };
            *(uint2*)((char*)Olds + row * XROW + w * 64 + j * 32 + g * 8) = pk;
        }
    }
    __syncthreads();   // bar3

    // proj: wave w -> out cols w*32..+32, K=256 from Olds
    f32x4 ap[4][2];
    #pragma unroll
    for (int i = 0; i < 4; i++) { ap[i][0] = (f32x4){0,0,0,0}; ap[i][1] = (f32x4){0,0,0,0}; }
    #pragma unroll
    for (int ks = 0; ks < 8; ks++) {
        bf16x8 wf[2], ah[4];
        #pragma unroll
        for (int n = 0; n < 2; n++)
            wf[n] = pp[(size_t)((w * 2 + n) * 8 + ks) * 64 + lane];
        #pragma unroll
        for (int i = 0; i < 4; i++)
            ah[i] = *(const bf16x8*)((char*)Olds + (i * 16 + c) * XROW
                                     + g * 16 + ks * 64);
        __builtin_amdgcn_s_setprio(1);
        #pragma unroll
        for (int i = 0; i < 4; i++)
            #pragma unroll
            for (int n = 0; n < 2; n++)
                ap[i][n] = __builtin_amdgcn_mfma_f32_16x16x32_bf16(
                    wf[n], ah[i], ap[i][n], 0, 0, 0);
        __builtin_amdgcn_s_setprio(0);
    }

    // epilogue: window-reverse + f32 residual -> bf16 x
    #pragma unroll
    for (int i = 0; i < 4; i++) {
        int n = i * 16 + c;
        size_t nrow = (size_t)b_ * 4096 + (wh * 8 + (n >> 3)) * 64 + ww * 8 + (n & 7);
        #pragma unroll
        for (int j = 0; j < 2; j++) {
            int col = w * 32 + j * 16 + 4 * g;
            float4 b4 = *(const float4*)(p_b + col);
            float4 r4 = *(const float4*)(x1 + nrow * 256 + col);
            uint2 pk = { pk2(ap[i][j][0] + b4.x + r4.x, ap[i][j][1] + b4.y + r4.y),
                         pk2(ap[i][j][2] + b4.z + r4.z, ap[i][j][3] + b4.w + r4.w) };
            *(uint2*)(xbw + nrow * 256 + col) = pk;
        }
    }
#undef GEMM256
#undef ADDBIAS
#undef REPACK
}

// ------------------------------------------------------------ MLP mega ------
// out = x + fc2(gelu(fc1(LN(x)))), x bf16. 64 rows/block, 8 waves, padded-
// linear LDS, wA/wB weight dbuf + setprio. LN via 16-lane groups (bf16 in).
__global__ __launch_bounds__(512, 4) void mlp_mega(
    const u16* __restrict__ xb, const float* __restrict__ gw,
    const float* __restrict__ bw, const bf16x8* __restrict__ f1p,
    const bf16x8* __restrict__ f2p, const float* __restrict__ f1b,
    const float* __restrict__ f2b, float* __restrict__ out)
{
    __shared__ __align__(16) u16 Xl[64 * 264];
    __shared__ __align__(16) u16 Hl[64 * 264];
    const int t = threadIdx.x, lane = t & 63, w = t >> 6;
    const int g = lane >> 4, c = lane & 15;
    const int m0 = blockIdx.x * 64;

    // ---- LN: 4 rows/iter via 16-lane groups; bf16 input ----
    {
        const int ln_sub = lane >> 4, ln_c = lane & 15;
        float4 GG[4], BB[4];
        #pragma unroll
        for (int j = 0; j < 4; j++) {
            GG[j] = *(const float4*)(gw + ln_c * 16 + j * 4);
            BB[j] = *(const float4*)(bw + ln_c * 16 + j * 4);
        }
        #pragma unroll
        for (int it = 0; it < 2; it++) {
            int row = w * 8 + it * 4 + ln_sub;
            const u16* p = xb + (size_t)(m0 + row) * 256 + ln_c * 16;
            uint4 rv = *(const uint4*)(p);
            uint4 rw = *(const uint4*)(p + 8);
            float v[16];
            v[0] = bf2f((u16)rv.x);  v[1] = bf2f((u16)(rv.x >> 16));
            v[2] = bf2f((u16)rv.y);  v[3] = bf2f((u16)(rv.y >> 16));
            v[4] = bf2f((u16)rv.z);  v[5] = bf2f((u16)(rv.z >> 16));
            v[6] = bf2f((u16)rv.w);  v[7] = bf2f((u16)(rv.w >> 16));
            v[8] = bf2f((u16)rw.x);  v[9] = bf2f((u16)(rw.x >> 16));
            v[10] = bf2f((u16)rw.y); v[11] = bf2f((u16)(rw.y >> 16));
            v[12] = bf2f((u16)rw.z); v[13] = bf2f((u16)(rw.z >> 16));
            v[14] = bf2f((u16)rw.w); v[15] = bf2f((u16)(rw.w >> 16));
            float s = 0.f, q = 0.f;
            #pragma unroll
            for (int e = 0; e < 16; e++) { s += v[e]; q += v[e] * v[e]; }
            #pragma unroll
            for (int m_ = 1; m_ <= 8; m_ <<= 1) {
                s += __shfl_xor(s, m_, 64);
                q += __shfl_xor(q, m_, 64);
            }
            float mean = s * (1.0f / 256.0f);
            float rstd = rsqrtf(q * (1.0f / 256.0f) - mean * mean + 1e-5f);
            uint4 o0, o1;
            const float* G = (const float*)GG;
            const float* B = (const float*)BB;
            o0.x = pk2((v[0]-mean)*rstd*G[0]+B[0],  (v[1]-mean)*rstd*G[1]+B[1]);
            o0.y = pk2((v[2]-mean)*rstd*G[2]+B[2],  (v[3]-mean)*rstd*G[3]+B[3]);
            o0.z = pk2((v[4]-mean)*rstd*G[4]+B[4],  (v[5]-mean)*rstd*G[5]+B[5]);
            o0.w = pk2((v[6]-mean)*rstd*G[6]+B[6],  (v[7]-mean)*rstd*G[7]+B[7]);
            o1.x = pk2((v[8]-mean)*rstd*G[8]+B[8],  (v[9]-mean)*rstd*G[9]+B[9]);
            o1.y = pk2((v[10]-mean)*rstd*G[10]+B[10],(v[11]-mean)*rstd*G[11]+B[11]);
            o1.z = pk2((v[12]-mean)*rstd*G[12]+B[12],(v[13]-mean)*rstd*G[13]+B[13]);
            o1.w = pk2((v[14]-mean)*rstd*G[14]+B[14],(v[15]-mean)*rstd*G[15]+B[15]);
            char* base = (char*)Xl + row * XROW + ln_c * 32;
            *(uint4*)(base) = o0;
            *(uint4*)(base + 16) = o1;
        }
    }
    __syncthreads();

    f32x4 acc2[4][2];
    #pragma unroll
    for (int i = 0; i < 4; i++) { acc2[i][0] = (f32x4){0,0,0,0}; acc2[i][1] = (f32x4){0,0,0,0}; }

    #pragma unroll
    for (int hc = 0; hc < 4; hc++) {
        f32x4 acc1[4][2];
        #pragma unroll
        for (int i = 0; i < 4; i++) { acc1[i][0] = (f32x4){0,0,0,0}; acc1[i][1] = (f32x4){0,0,0,0}; }

        const bf16x8* f1base = f1p + (size_t)((hc * 16 + w * 2) * 8) * 64 + lane;
        bf16x8 wA[2], wB[2];
        #pragma unroll
        for (int n = 0; n < 2; n++) wA[n] = f1base[(n * 8 + 0) * 64];

#define FC1_STEP(WREG, ks_)                                                   \
        {                                                                     \
            bf16x8 af[4];                                                     \
            _Pragma("unroll")                                                 \
            for (int i = 0; i < 4; i++)                                       \
                af[i] = *(const bf16x8*)((char*)Xl + (i * 16 + c) * XROW      \
                                         + g * 16 + (ks_) * 64);             \
            __builtin_amdgcn_s_setprio(1);                                    \
            _Pragma("unroll")                                                 \
            for (int i = 0; i < 4; i++)                                       \
                _Pragma("unroll")                                             \
                for (int n = 0; n < 2; n++)                                   \
                    acc1[i][n] = __builtin_amdgcn_mfma_f32_16x16x32_bf16(     \
                        WREG[n], af[i], acc1[i][n], 0, 0, 0);                 \
            __builtin_amdgcn_s_setprio(0);                                    \
        }

        #pragma unroll
        for (int ks = 0; ks < 8; ks += 2) {
            #pragma unroll
            for (int n = 0; n < 2; n++) wB[n] = f1base[(n * 8 + ks + 1) * 64];
            FC1_STEP(wA, ks)
            if (ks + 2 < 8) {
                #pragma unroll
                for (int n = 0; n < 2; n++) wA[n] = f1base[(n * 8 + ks + 2) * 64];
            }
            FC1_STEP(wB, ks + 1)
        }
#undef FC1_STEP

        #pragma unroll
        for (int i = 0; i < 4; i++) {
            int row = i * 16 + c;
            #pragma unroll
            for (int n = 0; n < 2; n++) {
                float4 b4 = *(const float4*)(f1b + hc * 256 + w * 32 + n * 16 + 4 * g);
                float h0 = gelu_s(acc1[i][n][0] + b4.x);
                float h1 = gelu_s(acc1[i][n][1] + b4.y);
                float h2 = gelu_s(acc1[i][n][2] + b4.z);
                float h3 = gelu_s(acc1[i][n][3] + b4.w);
                uint2 pk = { pk2(h0, h1), pk2(h2, h3) };
                *(uint2*)((char*)Hl + row * XROW + w * 64 + n * 32 + g * 8) = pk;
            }
        }
        __syncthreads();

        const bf16x8* f2base = f2p + (size_t)((w * 2) * 32 + hc * 8) * 64 + lane;
        #pragma unroll
        for (int n = 0; n < 2; n++) wA[n] = f2base[(n * 32 + 0) * 64];

#define FC2_STEP(WREG, ks_)                                                   \
        {                                                                     \
            bf16x8 ah[4];                                                     \
            _Pragma("unroll")                                                 \
            for (int i = 0; i < 4; i++)                                       \
                ah[i] = *(const bf16x8*)((char*)Hl + (i * 16 + c) * XROW      \
                                         + g * 16 + (ks_) * 64);             \
            __builtin_amdgcn_s_setprio(1);                                    \
            _Pragma("unroll")                                                 \
            for (int i = 0; i < 4; i++)                                       \
                _Pragma("unroll")                                             \
                for (int n = 0; n < 2; n++)                                   \
                    acc2[i][n] = __builtin_amdgcn_mfma_f32_16x16x32_bf16(     \
                        WREG[n], ah[i], acc2[i][n], 0, 0, 0);                 \
            __builtin_amdgcn_s_setprio(0);                                    \
        }

        #pragma unroll
        for (int ks = 0; ks < 8; ks += 2) {
            #pragma unroll
            for (int n = 0; n < 2; n++) wB[n] = f2base[(n * 32 + ks + 1) * 64];
            FC2_STEP(wA, ks)
            if (ks + 2 < 8) {
                #pragma unroll
                for (int n = 0; n < 2; n++) wA[n] = f2base[(n * 32 + ks + 2) * 64];
            }
            FC2_STEP(wB, ks + 1)
        }
#undef FC2_STEP
        __syncthreads();
    }

    #pragma unroll
    for (int i = 0; i < 4; i++) {
        int row = m0 + i * 16 + c;
        #pragma unroll
        for (int n = 0; n < 2; n++) {
            int col = w * 32 + n * 16 + 4 * g;
            float4 b4 = *(const float4*)(f2b + col);
            uint2 rr = *(const uint2*)(xb + (size_t)row * 256 + col);
            float4 ov = { acc2[i][n][0] + b4.x + bf2f((u16)rr.x),
                          acc2[i][n][1] + b4.y + bf2f((u16)(rr.x >> 16)),
                          acc2[i][n][2] + b4.z + bf2f((u16)rr.y),
                          acc2[i][n][3] + b4.w + bf2f((u16)(rr.y >> 16)) };
            *(float4*)(out + (size_t)row * 256 + col) = ov;
        }
    }
}

// -------------------------------------------------------------- launch ------
// Workspace (peak ~36 MB):
//   [0,       2.10M)  weights: qp kvp pp f1p f2p biasF
//   [2.10M,  35.65M)  xbw (bf16 x, attn_mega out -> mlp in)
extern "C" void kernel_launch(void* const* d_in, const int* in_sizes, int n_in,
                              void* d_out, int out_size, void* d_ws, size_t ws_size,
                              hipStream_t stream)
{
    const float* x1  = (const float*)d_in[0];
    const float* x2  = (const float*)d_in[1];
    const float* n1g = (const float*)d_in[2];
    const float* n1b = (const float*)d_in[3];
    const float* q_w = (const float*)d_in[4];
    const float* q_b = (const float*)d_in[5];
    const float* kv_w= (const float*)d_in[6];
    const float* kv_b= (const float*)d_in[7];
    const float* p_w = (const float*)d_in[8];
    const float* p_b = (const float*)d_in[9];
    const float* rel = (const float*)d_in[10];
    const float* n3g = (const float*)d_in[11];
    const float* n3b = (const float*)d_in[12];
    const float* f1w = (const float*)d_in[13];
    const float* f1b = (const float*)d_in[14];
    const float* f2w = (const float*)d_in[15];
    const float* f2b = (const float*)d_in[16];

    char* ws = (char*)d_ws;
    u16*   qp    = (u16*)(ws + 0);
    u16*   kvp   = (u16*)(ws + 131072);
    u16*   pp    = (u16*)(ws + 393216);
    u16*   f1p   = (u16*)(ws + 524288);
    u16*   f2p   = (u16*)(ws + 1048576);
    float* biasF = (float*)(ws + 1572864);
    u16*   xbw   = (u16*)(ws + 2097152);

    float* out = (float*)d_out;

    prep_k<<<3200, 256, 0, stream>>>(q_w, kv_w, p_w, f1w, f2w, rel,
                                     qp, kvp, pp, f1p, f2p, biasF);
    attn_mega<<<1024, 512, 0, stream>>>(x1, x2, n1g, n1b, (const bf16x8*)qp,
                                        (const bf16x8*)kvp, q_b, kv_b, biasF,
                                        (const bf16x8*)pp, p_b, xbw);
    mlp_mega<<<1024, 512, 0, stream>>>(xbw, n3g, n3b, (const bf16x8*)f1p,
                                       (const bf16x8*)f2p, f1b, f2b, out);
}

// Round 18
// 202.111 us; speedup vs baseline: 1.6475x; 1.1016x over previous
//
#include <hip/hip_runtime.h>

typedef __bf16 bf16x8 __attribute__((ext_vector_type(8)));
typedef float f32x4 __attribute__((ext_vector_type(4)));
using u16 = unsigned short;

#define SCALE 0.17677669529663689f  // 32^-0.5
#define XROW 528                    // padded LDS row stride (264 u16)

// Native bf16 casts (RTNE) -> compiler fuses pairs into v_cvt_pk_bf16_f32.
__device__ __forceinline__ u16 f2bf(float f) {
    union { __bf16 h; u16 u; } x; x.h = (__bf16)f; return x.u;
}
__device__ __forceinline__ unsigned pk2(float a, float b) {
    union { struct { __bf16 lo, hi; } s; unsigned u; } x;
    x.s.lo = (__bf16)a; x.s.hi = (__bf16)b; return x.u;
}
__device__ __forceinline__ float bf2f(u16 h) {
    union { unsigned u; float f; } x; x.u = ((unsigned)h) << 16; return x.f;
}
// gelu = x * sigmoid(1.5957691*(x+0.044715x^3)); exp folded to native exp2
__device__ __forceinline__ float gelu_s(float x) {
    float u = 2.3022150048054216f * x * (1.f + 0.044715f * x * x); // *log2(e)
    float e = exp2f(-u);
    return x / (1.f + e);
}

// ---------------------------------------------------------------- prep ------
// ALL weights fragment-packed (frag (ng,ks): lane l holds
// W[k=32ks+8(l>>4)+e][n=16ng+(l&15)]). biasF: rel-pos bias, swapped C-frag.
__global__ __launch_bounds__(256) void prep_k(
    const float* __restrict__ q_w, const float* __restrict__ kv_w,
    const float* __restrict__ p_w, const float* __restrict__ f1w,
    const float* __restrict__ f2w, const float* __restrict__ rel,
    u16* __restrict__ qp, u16* __restrict__ kvp, u16* __restrict__ pp,
    u16* __restrict__ f1p, u16* __restrict__ f2p, float* __restrict__ biasF)
{
    int t = blockIdx.x * 256 + threadIdx.x;
    if (t < 65536) {                                   // qp: 256x256
        int u = t;
        int e = u & 7, l = (u >> 3) & 63, ks = (u >> 9) & 7, ng = u >> 12;
        int k = ks * 32 + (l >> 4) * 8 + e;
        int n = ng * 16 + (l & 15);
        qp[u] = f2bf(q_w[k * 256 + n]);
    } else if (t < 196608) {                           // kvp: 256x512
        int u = t - 65536;
        int e = u & 7, l = (u >> 3) & 63, ks = (u >> 9) & 7, ng = u >> 12;
        int k = ks * 32 + (l >> 4) * 8 + e;
        int n = ng * 16 + (l & 15);
        kvp[u] = f2bf(kv_w[k * 512 + n]);
    } else if (t < 262144) {                           // pp: 256x256
        int u = t - 196608;
        int e = u & 7, l = (u >> 3) & 63, ks = (u >> 9) & 7, ng = u >> 12;
        int k = ks * 32 + (l >> 4) * 8 + e;
        int n = ng * 16 + (l & 15);
        pp[u] = f2bf(p_w[k * 256 + n]);
    } else if (t < 524288) {                           // f1p: 256x1024
        int u = t - 262144;
        int e = u & 7, l = (u >> 3) & 63, ks = (u >> 9) & 7, ng = u >> 12;
        int k = ks * 32 + (l >> 4) * 8 + e;
        int n = ng * 16 + (l & 15);
        f1p[u] = f2bf(f1w[k * 1024 + n]);
    } else if (t < 786432) {                           // f2p: 1024x256
        int u = t - 524288;
        int e = u & 7, l = (u >> 3) & 63, ks = (u >> 9) & 31, ng = u >> 14;
        int k = ks * 32 + (l >> 4) * 8 + e;
        int n = ng * 16 + (l & 15);
        f2p[u] = f2bf(f2w[k * 256 + n]);
    } else if (t < 819200) {                           // biasF 8*16*64*4
        int u = t - 786432;
        int r = u & 3, l = (u >> 2) & 63, fr = (u >> 8) & 15, h = u >> 12;
        int fi = fr >> 2, fj = fr & 3;
        int m = fi * 16 + (l & 15);
        int n = fj * 16 + 4 * (l >> 4) + r;
        int idx = ((m >> 3) - (n >> 3) + 7) * 15 + ((m & 7) - (n & 7) + 7);
        biasF[u] = rel[idx * 8 + h];
    }
}

// Fast LN of one 256-col f32 row per 16-lane group (internal temps o0_/o1_).
#define LN_ROW16(SRCP, GG, BB, OUT0, OUT1)                                    \
    {                                                                         \
        float4 v0 = *(const float4*)(SRCP);                                   \
        float4 v1 = *(const float4*)(SRCP + 4);                               \
        float4 v2 = *(const float4*)(SRCP + 8);                               \
        float4 v3 = *(const float4*)(SRCP + 12);                              \
        float s = (v0.x + v0.y + v0.z + v0.w) + (v1.x + v1.y + v1.z + v1.w)   \
                + (v2.x + v2.y + v2.z + v2.w) + (v3.x + v3.y + v3.z + v3.w);  \
        float q = v0.x*v0.x + v0.y*v0.y + v0.z*v0.z + v0.w*v0.w               \
                + v1.x*v1.x + v1.y*v1.y + v1.z*v1.z + v1.w*v1.w               \
                + v2.x*v2.x + v2.y*v2.y + v2.z*v2.z + v2.w*v2.w               \
                + v3.x*v3.x + v3.y*v3.y + v3.z*v3.z + v3.w*v3.w;              \
        _Pragma("unroll")                                                     \
        for (int m_ = 1; m_ <= 8; m_ <<= 1) {                                 \
            s += __shfl_xor(s, m_, 64);                                       \
            q += __shfl_xor(q, m_, 64);                                       \
        }                                                                     \
        float mean = s * (1.0f / 256.0f);                                     \
        float rstd = rsqrtf(q * (1.0f / 256.0f) - mean * mean + 1e-5f);       \
        uint4 o0_, o1_;                                                       \
        o0_.x = pk2((v0.x-mean)*rstd*GG[0].x+BB[0].x, (v0.y-mean)*rstd*GG[0].y+BB[0].y); \
        o0_.y = pk2((v0.z-mean)*rstd*GG[0].z+BB[0].z, (v0.w-mean)*rstd*GG[0].w+BB[0].w); \
        o0_.z = pk2((v1.x-mean)*rstd*GG[1].x+BB[1].x, (v1.y-mean)*rstd*GG[1].y+BB[1].y); \
        o0_.w = pk2((v1.z-mean)*rstd*GG[1].z+BB[1].z, (v1.w-mean)*rstd*GG[1].w+BB[1].w); \
        o1_.x = pk2((v2.x-mean)*rstd*GG[2].x+BB[2].x, (v2.y-mean)*rstd*GG[2].y+BB[2].y); \
        o1_.y = pk2((v2.z-mean)*rstd*GG[2].z+BB[2].z, (v2.w-mean)*rstd*GG[2].w+BB[2].w); \
        o1_.z = pk2((v3.x-mean)*rstd*GG[3].x+BB[3].x, (v3.y-mean)*rstd*GG[3].y+BB[3].y); \
        o1_.w = pk2((v3.z-mean)*rstd*GG[3].z+BB[3].z, (v3.w-mean)*rstd*GG[3].w+BB[3].w); \
        OUT0 = o0_; OUT1 = o1_;                                               \
    }

// ----------------------------------------------------------- block mega -----
// ONE block = ONE window = the ENTIRE layer for its 64 rows.
// Phases: [1] LN1(x1,x2)->Xl0/Xl1  [2] own-head Q/K/V GEMMs + reg repack
// [3] QK^T+bias+softmax+PV -> Olds -> proj -> x (regs, bf16)
// [4] x->Xl4 (LDS), LN3 in place, fc1+gelu->Hl4, fc2, out=acc+f2b+x (f32).
// LDS arena (74752 B): ph1-2 {Xl0,Xl1}; ph3 {VtA,Olds}; ph4 {Xl4 over VtA,
// Hl4 over Olds}. All overlays are write-after-barrier past last read.
__global__ __launch_bounds__(512, 4) void block_mega(
    const float* __restrict__ x1, const float* __restrict__ x2,
    const float* __restrict__ n1g, const float* __restrict__ n1b,
    const bf16x8* __restrict__ qp, const bf16x8* __restrict__ kvp,
    const float* __restrict__ q_b, const float* __restrict__ kv_b,
    const float* __restrict__ biasF, const bf16x8* __restrict__ pp,
    const float* __restrict__ p_b,
    const float* __restrict__ n3g, const float* __restrict__ n3b,
    const bf16x8* __restrict__ f1p, const bf16x8* __restrict__ f2p,
    const float* __restrict__ f1b, const float* __restrict__ f2b,
    float* __restrict__ out)
{
    __shared__ __align__(16) char SMEM[74752];
    u16* Xl0  = (u16*)SMEM;            // phase 1-2
    u16* Xl1  = (u16*)(SMEM + 33792);  // phase 1-2
    u16* VtA  = (u16*)SMEM;            // phase 3 (after bar2)
    u16* Olds = (u16*)(SMEM + 40960);  // phase 3 (after bar2)
    u16* Xl4  = (u16*)SMEM;            // phase 4 (after bar3; over VtA)
    u16* Hl4  = (u16*)(SMEM + 40960);  // phase 4 (after bar4; over Olds)
    const int t = threadIdx.x, lane = t & 63, w = t >> 6;   // w = head
    const int g = lane >> 4, c = lane & 15;
    const int win = blockIdx.x;
    const int b_ = win >> 6, wh = (win >> 3) & 7, ww = win & 7;

    // ---- phase 1: LN1 of both streams; 4 rows/iter (16-lane groups) ----
    {
        const int ln_sub = lane >> 4, ln_c = lane & 15;
        float4 GG[4], BB[4];
        #pragma unroll
        for (int j = 0; j < 4; j++) {
            GG[j] = *(const float4*)(n1g + ln_c * 16 + j * 4);
            BB[j] = *(const float4*)(n1b + ln_c * 16 + j * 4);
        }
        #pragma unroll
        for (int it = 0; it < 4; it++) {
            int idx = w * 16 + it * 4 + ln_sub;    // 0..127
            int st = idx >> 6, n = idx & 63;
            const float* src = st ? x2 : x1;
            size_t srow = (size_t)b_ * 4096 + (wh * 8 + (n >> 3)) * 64 + ww * 8 + (n & 7);
            const float* p = src + srow * 256 + ln_c * 16;
            uint4 o0, o1;
            LN_ROW16(p, GG, BB, o0, o1)
            u16* dst = st ? Xl1 : Xl0;
            char* base = (char*)dst + n * XROW + ln_c * 32;
            *(uint4*)(base) = o0;
            *(uint4*)(base + 16) = o1;
        }
    }
    __syncthreads();   // bar1: Xl ready

    // ---- phase 2: own-head Q/K/V GEMMs (K=256) ----
    const int srcA = c + 16 * ((2 * g) & 3);
    const int srcB = srcA + 16;
    const bool nhi = (g >= 2);

#define GEMM256(acc, WPTR, NGBASE, XSRC)                                      \
    { _Pragma("unroll")                                                       \
      for (int i = 0; i < 4; i++) { acc[i][0] = (f32x4){0,0,0,0};             \
                                    acc[i][1] = (f32x4){0,0,0,0}; }           \
      _Pragma("unroll")                                                       \
      for (int ks = 0; ks < 8; ks++) {                                        \
          bf16x8 wf[2], af[4];                                                \
          _Pragma("unroll")                                                   \
          for (int n = 0; n < 2; n++)                                         \
              wf[n] = WPTR[(size_t)(((NGBASE) + n) * 8 + ks) * 64 + lane];    \
          _Pragma("unroll")                                                   \
          for (int i = 0; i < 4; i++)                                         \
              af[i] = *(const bf16x8*)((char*)XSRC + (i * 16 + c) * XROW      \
                                       + g * 16 + ks * 64);                   \
          __builtin_amdgcn_s_setprio(1);                                      \
          _Pragma("unroll")                                                   \
          for (int i = 0; i < 4; i++)                                         \
              _Pragma("unroll")                                               \
              for (int n = 0; n < 2; n++)                                     \
                  acc[i][n] = __builtin_amdgcn_mfma_f32_16x16x32_bf16(        \
                      wf[n], af[i], acc[i][n], 0, 0, 0);                      \
          __builtin_amdgcn_s_setprio(0);                                      \
      } }

#define ADDBIAS(acc, BPTR, CBASE)                                             \
    { _Pragma("unroll")                                                       \
      for (int i = 0; i < 4; i++)                                             \
          _Pragma("unroll")                                                   \
          for (int n = 0; n < 2; n++) {                                       \
              float4 b4 = *(const float4*)((BPTR) + (CBASE) + n * 16 + 4 * g);\
              acc[i][n][0] += b4.x; acc[i][n][1] += b4.y;                     \
              acc[i][n][2] += b4.z; acc[i][n][3] += b4.w;                     \
          } }

#define REPACK(acc, frag)                                                     \
    { unsigned w0_[4][2], w1_[4][2];                                          \
      _Pragma("unroll")                                                       \
      for (int i = 0; i < 4; i++)                                             \
          _Pragma("unroll")                                                   \
          for (int n = 0; n < 2; n++) {                                       \
              w0_[i][n] = pk2(acc[i][n][0], acc[i][n][1]);                    \
              w1_[i][n] = pk2(acc[i][n][2], acc[i][n][3]);                    \
          }                                                                   \
      _Pragma("unroll")                                                       \
      for (int i = 0; i < 4; i++) {                                           \
          unsigned x0a = __shfl(w0_[i][0], srcA), x0b = __shfl(w0_[i][1], srcA);\
          unsigned y0a = __shfl(w1_[i][0], srcA), y0b = __shfl(w1_[i][1], srcA);\
          unsigned x1a = __shfl(w0_[i][0], srcB), x1b = __shfl(w0_[i][1], srcB);\
          unsigned y1a = __shfl(w1_[i][0], srcB), y1b = __shfl(w1_[i][1], srcB);\
          union { uint4 u; bf16x8 v; } cv;                                    \
          cv.u.x = nhi ? x0b : x0a;                                           \
          cv.u.y = nhi ? y0b : y0a;                                           \
          cv.u.z = nhi ? x1b : x1a;                                           \
          cv.u.w = nhi ? y1b : y1a;                                           \
          frag[i] = cv.v;                                                     \
      } }

    bf16x8 qf[4], kf[4];
    f32x4 av[4][2];
    {
        f32x4 acc[4][2];
        GEMM256(acc, kvp, 2 * w, Xl1)            // K
        ADDBIAS(acc, kv_b, w * 32)
        REPACK(acc, kf)
        GEMM256(acc, qp, 2 * w, Xl0)             // Q
        ADDBIAS(acc, q_b, w * 32)
        REPACK(acc, qf)
        GEMM256(av, kvp, 16 + 2 * w, Xl1)        // V
        ADDBIAS(av, kv_b, 256 + w * 32)
    }
    __syncthreads();   // bar2: Xl reads done -> safe to write VtA/Olds

    // V scatter: Vt[d][key], padded 80
    u16* vt = VtA + w * 32 * 80;
    #pragma unroll
    for (int i = 0; i < 4; i++)
        #pragma unroll
        for (int n = 0; n < 2; n++)
            #pragma unroll
            for (int r = 0; r < 4; r++)
                vt[(n * 16 + 4 * g + r) * 80 + i * 16 + c] = f2bf(av[i][n][r]);

    // QK^T; swapped mfma(K, Q)
    f32x4 s[4][4];
    #pragma unroll
    for (int i = 0; i < 4; i++)
        #pragma unroll
        for (int j = 0; j < 4; j++) {
            s[i][j] = (f32x4){0.f, 0.f, 0.f, 0.f};
            s[i][j] = __builtin_amdgcn_mfma_f32_16x16x32_bf16(kf[j], qf[i], s[i][j], 0, 0, 0);
        }

    // scale + rel-pos bias
    #pragma unroll
    for (int i = 0; i < 4; i++)
        #pragma unroll
        for (int j = 0; j < 4; j++) {
            f32x4 bf4 = *(const f32x4*)(biasF + ((size_t)(w * 16 + i * 4 + j) * 64 + lane) * 4);
            #pragma unroll
            for (int r = 0; r < 4; r++) s[i][j][r] = s[i][j][r] * SCALE + bf4[r];
        }

    // softmax over keys
    #pragma unroll
    for (int i = 0; i < 4; i++) {
        float mx = -1e30f;
        #pragma unroll
        for (int j = 0; j < 4; j++)
            #pragma unroll
            for (int r = 0; r < 4; r++) mx = fmaxf(mx, s[i][j][r]);
        mx = fmaxf(mx, __shfl_xor(mx, 16, 64));
        mx = fmaxf(mx, __shfl_xor(mx, 32, 64));
        float sum = 0.f;
        #pragma unroll
        for (int j = 0; j < 4; j++)
            #pragma unroll
            for (int r = 0; r < 4; r++) {
                float e = __expf(s[i][j][r] - mx);
                s[i][j][r] = e; sum += e;
            }
        sum += __shfl_xor(sum, 16, 64);
        sum += __shfl_xor(sum, 32, 64);
        float inv = 1.f / sum;
        #pragma unroll
        for (int j = 0; j < 4; j++)
            #pragma unroll
            for (int r = 0; r < 4; r++) s[i][j][r] *= inv;
    }

    // P repack + PV
    unsigned pw0[4][4], pw1[4][4];
    #pragma unroll
    for (int i = 0; i < 4; i++)
        #pragma unroll
        for (int j = 0; j < 4; j++) {
            pw0[i][j] = pk2(s[i][j][0], s[i][j][1]);
            pw1[i][j] = pk2(s[i][j][2], s[i][j][3]);
        }
    f32x4 o[4][2];
    #pragma unroll
    for (int i = 0; i < 4; i++) { o[i][0] = (f32x4){0,0,0,0}; o[i][1] = (f32x4){0,0,0,0}; }
    #pragma unroll
    for (int ks = 0; ks < 2; ks++) {
        bf16x8 pa[4], vb[2];
        #pragma unroll
        for (int i = 0; i < 4; i++) {
            unsigned a0 = __shfl(pw0[i][2 * ks], srcA), b0 = __shfl(pw0[i][2 * ks + 1], srcA);
            unsigned a1 = __shfl(pw1[i][2 * ks], srcA), b1 = __shfl(pw1[i][2 * ks + 1], srcA);
            unsigned a2 = __shfl(pw0[i][2 * ks], srcB), b2 = __shfl(pw0[i][2 * ks + 1], srcB);
            unsigned a3 = __shfl(pw1[i][2 * ks], srcB), b3 = __shfl(pw1[i][2 * ks + 1], srcB);
            union { uint4 u; bf16x8 v; } cv;
            cv.u.x = nhi ? b0 : a0;
            cv.u.y = nhi ? b1 : a1;
            cv.u.z = nhi ? b2 : a2;
            cv.u.w = nhi ? b3 : a3;
            pa[i] = cv.v;
        }
        #pragma unroll
        for (int j = 0; j < 2; j++) {
            int d = j * 16 + c;
            vb[j] = *(const bf16x8*)(vt + d * 80 + ks * 32 + 8 * g);
        }
        #pragma unroll
        for (int i = 0; i < 4; i++)
            #pragma unroll
            for (int j = 0; j < 2; j++)
                o[i][j] = __builtin_amdgcn_mfma_f32_16x16x32_bf16(vb[j], pa[i], o[i][j], 0, 0, 0);
    }

    // O -> Olds
    #pragma unroll
    for (int i = 0; i < 4; i++) {
        int row = i * 16 + c;
        #pragma unroll
        for (int j = 0; j < 2; j++) {
            uint2 pk = { pk2(o[i][j][0], o[i][j][1]), pk2(o[i][j][2], o[i][j][3]) };
            *(uint2*)((char*)Olds + row * XROW + w * 64 + j * 32 + g * 8) = pk;
        }
    }
    __syncthreads();   // bar3: all heads' O in Olds; all Vt reads done

    // proj: wave w -> out cols w*32..+32, K=256 from Olds
    f32x4 ap[4][2];
    #pragma unroll
    for (int i = 0; i < 4; i++) { ap[i][0] = (f32x4){0,0,0,0}; ap[i][1] = (f32x4){0,0,0,0}; }
    #pragma unroll
    for (int ks = 0; ks < 8; ks++) {
        bf16x8 wf[2], ah[4];
        #pragma unroll
        for (int n = 0; n < 2; n++)
            wf[n] = pp[(size_t)((w * 2 + n) * 8 + ks) * 64 + lane];
        #pragma unroll
        for (int i = 0; i < 4; i++)
            ah[i] = *(const bf16x8*)((char*)Olds + (i * 16 + c) * XROW
                                     + g * 16 + ks * 64);
        __builtin_amdgcn_s_setprio(1);
        #pragma unroll
        for (int i = 0; i < 4; i++)
            #pragma unroll
            for (int n = 0; n < 2; n++)
                ap[i][n] = __builtin_amdgcn_mfma_f32_16x16x32_bf16(
                    wf[n], ah[i], ap[i][n], 0, 0, 0);
        __builtin_amdgcn_s_setprio(0);
    }

    // x = proj + p_b + f32 residual -> bf16 packed regs, and write Xl4
    // (Xl4 overlays VtA: all Vt reads finished before bar3).
    uint2 xs[4][2];
    #pragma unroll
    for (int i = 0; i < 4; i++) {
        int n = i * 16 + c;
        size_t nrow = (size_t)b_ * 4096 + (wh * 8 + (n >> 3)) * 64 + ww * 8 + (n & 7);
        #pragma unroll
        for (int j = 0; j < 2; j++) {
            int col = w * 32 + j * 16 + 4 * g;
            float4 b4 = *(const float4*)(p_b + col);
            float4 r4 = *(const float4*)(x1 + nrow * 256 + col);
            uint2 pk = { pk2(ap[i][j][0] + b4.x + r4.x, ap[i][j][1] + b4.y + r4.y),
                         pk2(ap[i][j][2] + b4.z + r4.z, ap[i][j][3] + b4.w + r4.w) };
            xs[i][j] = pk;
            *(uint2*)((char*)Xl4 + (i * 16 + c) * XROW + w * 64 + j * 32 + g * 8) = pk;
        }
    }
    __syncthreads();   // bar4: full x in Xl4; all Olds reads done (proj above)

    // ---- phase 4a: LN3 in place on Xl4 (16-lane groups, 2 iters) ----
    {
        const int ln_sub = lane >> 4, ln_c = lane & 15;
        float4 G3[4], B3[4];
        #pragma unroll
        for (int j = 0; j < 4; j++) {
            G3[j] = *(const float4*)(n3g + ln_c * 16 + j * 4);
            B3[j] = *(const float4*)(n3b + ln_c * 16 + j * 4);
        }
        const float* G = (const float*)G3;
        const float* B = (const float*)B3;
        #pragma unroll
        for (int it = 0; it < 2; it++) {
            int row = w * 8 + it * 4 + ln_sub;
            char* base = (char*)Xl4 + row * XROW + ln_c * 32;
            uint4 rv = *(const uint4*)(base);
            uint4 rw = *(const uint4*)(base + 16);
            float v[16];
            v[0] = bf2f((u16)rv.x);  v[1] = bf2f((u16)(rv.x >> 16));
            v[2] = bf2f((u16)rv.y);  v[3] = bf2f((u16)(rv.y >> 16));
            v[4] = bf2f((u16)rv.z);  v[5] = bf2f((u16)(rv.z >> 16));
            v[6] = bf2f((u16)rv.w);  v[7] = bf2f((u16)(rv.w >> 16));
            v[8] = bf2f((u16)rw.x);  v[9] = bf2f((u16)(rw.x >> 16));
            v[10] = bf2f((u16)rw.y); v[11] = bf2f((u16)(rw.y >> 16));
            v[12] = bf2f((u16)rw.z); v[13] = bf2f((u16)(rw.z >> 16));
            v[14] = bf2f((u16)rw.w); v[15] = bf2f((u16)(rw.w >> 16));
            float sm = 0.f, qm = 0.f;
            #pragma unroll
            for (int e = 0; e < 16; e++) { sm += v[e]; qm += v[e] * v[e]; }
            #pragma unroll
            for (int m_ = 1; m_ <= 8; m_ <<= 1) {
                sm += __shfl_xor(sm, m_, 64);
                qm += __shfl_xor(qm, m_, 64);
            }
            float mean = sm * (1.0f / 256.0f);
            float rstd = rsqrtf(qm * (1.0f / 256.0f) - mean * mean + 1e-5f);
            uint4 o0, o1;
            o0.x = pk2((v[0]-mean)*rstd*G[0]+B[0],  (v[1]-mean)*rstd*G[1]+B[1]);
            o0.y = pk2((v[2]-mean)*rstd*G[2]+B[2],  (v[3]-mean)*rstd*G[3]+B[3]);
            o0.z = pk2((v[4]-mean)*rstd*G[4]+B[4],  (v[5]-mean)*rstd*G[5]+B[5]);
            o0.w = pk2((v[6]-mean)*rstd*G[6]+B[6],  (v[7]-mean)*rstd*G[7]+B[7]);
            o1.x = pk2((v[8]-mean)*rstd*G[8]+B[8],  (v[9]-mean)*rstd*G[9]+B[9]);
            o1.y = pk2((v[10]-mean)*rstd*G[10]+B[10],(v[11]-mean)*rstd*G[11]+B[11]);
            o1.z = pk2((v[12]-mean)*rstd*G[12]+B[12],(v[13]-mean)*rstd*G[13]+B[13]);
            o1.w = pk2((v[14]-mean)*rstd*G[14]+B[14],(v[15]-mean)*rstd*G[15]+B[15]);
            *(uint4*)(base) = o0;
            *(uint4*)(base + 16) = o1;
        }
    }
    __syncthreads();   // bar5: LN3(x) in Xl4

    // ---- phase 4b: MLP (fc1+gelu -> Hl4 over Olds; fc2 accumulate) ----
    f32x4 acc2[4][2];
    #pragma unroll
    for (int i = 0; i < 4; i++) { acc2[i][0] = (f32x4){0,0,0,0}; acc2[i][1] = (f32x4){0,0,0,0}; }

    #pragma unroll
    for (int hc = 0; hc < 4; hc++) {
        f32x4 acc1[4][2];
        #pragma unroll
        for (int i = 0; i < 4; i++) { acc1[i][0] = (f32x4){0,0,0,0}; acc1[i][1] = (f32x4){0,0,0,0}; }

        const bf16x8* f1base = f1p + (size_t)((hc * 16 + w * 2) * 8) * 64 + lane;
        bf16x8 wA[2], wB[2];
        #pragma unroll
        for (int n = 0; n < 2; n++) wA[n] = f1base[(n * 8 + 0) * 64];

#define FC1_STEP(WREG, ks_)                                                   \
        {                                                                     \
            bf16x8 af[4];                                                     \
            _Pragma("unroll")                                                 \
            for (int i = 0; i < 4; i++)                                       \
                af[i] = *(const bf16x8*)((char*)Xl4 + (i * 16 + c) * XROW     \
                                         + g * 16 + (ks_) * 64);             \
            __builtin_amdgcn_s_setprio(1);                                    \
            _Pragma("unroll")                                                 \
            for (int i = 0; i < 4; i++)                                       \
                _Pragma("unroll")                                             \
                for (int n = 0; n < 2; n++)                                   \
                    acc1[i][n] = __builtin_amdgcn_mfma_f32_16x16x32_bf16(     \
                        WREG[n], af[i], acc1[i][n], 0, 0, 0);                 \
            __builtin_amdgcn_s_setprio(0);                                    \
        }

        #pragma unroll
        for (int ks = 0; ks < 8; ks += 2) {
            #pragma unroll
            for (int n = 0; n < 2; n++) wB[n] = f1base[(n * 8 + ks + 1) * 64];
            FC1_STEP(wA, ks)
            if (ks + 2 < 8) {
                #pragma unroll
                for (int n = 0; n < 2; n++) wA[n] = f1base[(n * 8 + ks + 2) * 64];
            }
            FC1_STEP(wB, ks + 1)
        }
#undef FC1_STEP

        #pragma unroll
        for (int i = 0; i < 4; i++) {
            int row = i * 16 + c;
            #pragma unroll
            for (int n = 0; n < 2; n++) {
                float4 b4 = *(const float4*)(f1b + hc * 256 + w * 32 + n * 16 + 4 * g);
                float h0 = gelu_s(acc1[i][n][0] + b4.x);
                float h1 = gelu_s(acc1[i][n][1] + b4.y);
                float h2 = gelu_s(acc1[i][n][2] + b4.z);
                float h3 = gelu_s(acc1[i][n][3] + b4.w);
                uint2 pk = { pk2(h0, h1), pk2(h2, h3) };
                *(uint2*)((char*)Hl4 + row * XROW + w * 64 + n * 32 + g * 8) = pk;
            }
        }
        __syncthreads();

        const bf16x8* f2base = f2p + (size_t)((w * 2) * 32 + hc * 8) * 64 + lane;
        #pragma unroll
        for (int n = 0; n < 2; n++) wA[n] = f2base[(n * 32 + 0) * 64];

#define FC2_STEP(WREG, ks_)                                                   \
        {                                                                     \
            bf16x8 ah[4];                                                     \
            _Pragma("unroll")                                                 \
            for (int i = 0; i < 4; i++)                                       \
                ah[i] = *(const bf16x8*)((char*)Hl4 + (i * 16 + c) * XROW     \
                                         + g * 16 + (ks_) * 64);             \
            __builtin_amdgcn_s_setprio(1);                                    \
            _Pragma("unroll")                                                 \
            for (int i = 0; i < 4; i++)                                       \
                _Pragma("unroll")                                             \
                for (int n = 0; n < 2; n++)                                   \
                    acc2[i][n] = __builtin_amdgcn_mfma_f32_16x16x32_bf16(     \
                        WREG[n], ah[i], acc2[i][n], 0, 0, 0);                 \
            __builtin_amdgcn_s_setprio(0);                                    \
        }

        #pragma unroll
        for (int ks = 0; ks < 8; ks += 2) {
            #pragma unroll
            for (int n = 0; n < 2; n++) wB[n] = f2base[(n * 32 + ks + 1) * 64];
            FC2_STEP(wA, ks)
            if (ks + 2 < 8) {
                #pragma unroll
                for (int n = 0; n < 2; n++) wA[n] = f2base[(n * 32 + ks + 2) * 64];
            }
            FC2_STEP(wB, ks + 1)
        }
#undef FC2_STEP
        __syncthreads();
    }

    // ---- epilogue: out = acc2 + f2b + x (bf16 regs), f32, window rows ----
    #pragma unroll
    for (int i = 0; i < 4; i++) {
        int n = i * 16 + c;
        size_t nrow = (size_t)b_ * 4096 + (wh * 8 + (n >> 3)) * 64 + ww * 8 + (n & 7);
        #pragma unroll
        for (int j = 0; j < 2; j++) {
            int col = w * 32 + j * 16 + 4 * g;
            float4 b4 = *(const float4*)(f2b + col);
            uint2 rr = xs[i][j];
            float4 ov = { acc2[i][j][0] + b4.x + bf2f((u16)rr.x),
                          acc2[i][j][1] + b4.y + bf2f((u16)(rr.x >> 16)),
                          acc2[i][j][2] + b4.z + bf2f((u16)rr.y),
                          acc2[i][j][3] + b4.w + bf2f((u16)(rr.y >> 16)) };
            *(float4*)(out + nrow * 256 + col) = ov;
        }
    }
#undef GEMM256
#undef ADDBIAS
#undef REPACK
}

// -------------------------------------------------------------- launch ------
// Workspace (peak ~2.1 MB): weights only.
extern "C" void kernel_launch(void* const* d_in, const int* in_sizes, int n_in,
                              void* d_out, int out_size, void* d_ws, size_t ws_size,
                              hipStream_t stream)
{
    const float* x1  = (const float*)d_in[0];
    const float* x2  = (const float*)d_in[1];
    const float* n1g = (const float*)d_in[2];
    const float* n1b = (const float*)d_in[3];
    const float* q_w = (const float*)d_in[4];
    const float* q_b = (const float*)d_in[5];
    const float* kv_w= (const float*)d_in[6];
    const float* kv_b= (const float*)d_in[7];
    const float* p_w = (const float*)d_in[8];
    const float* p_b = (const float*)d_in[9];
    const float* rel = (const float*)d_in[10];
    const float* n3g = (const float*)d_in[11];
    const float* n3b = (const float*)d_in[12];
    const float* f1w = (const float*)d_in[13];
    const float* f1b = (const float*)d_in[14];
    const float* f2w = (const float*)d_in[15];
    const float* f2b = (const float*)d_in[16];

    char* ws = (char*)d_ws;
    u16*   qp    = (u16*)(ws + 0);
    u16*   kvp   = (u16*)(ws + 131072);
    u16*   pp    = (u16*)(ws + 393216);
    u16*   f1p   = (u16*)(ws + 524288);
    u16*   f2p   = (u16*)(ws + 1048576);
    float* biasF = (float*)(ws + 1572864);

    float* out = (float*)d_out;

    prep_k<<<3200, 256, 0, stream>>>(q_w, kv_w, p_w, f1w, f2w, rel,
                                     qp, kvp, pp, f1p, f2p, biasF);
    block_mega<<<1024, 512, 0, stream>>>(x1, x2, n1g, n1b, (const bf16x8*)qp,
                                         (const bf16x8*)kvp, q_b, kv_b, biasF,
                                         (const bf16x8*)pp, p_b, n3g, n3b,
                                         (const bf16x8*)f1p, (const bf16x8*)f2p,
                                         f1b, f2b, out);
}

// Round 19
// 199.175 us; speedup vs baseline: 1.6718x; 1.0147x over previous
//
#include <hip/hip_runtime.h>

typedef __bf16 bf16x8 __attribute__((ext_vector_type(8)));
typedef float f32x4 __attribute__((ext_vector_type(4)));
using u16 = unsigned short;

#define SCALE2 (0.17677669529663689f * 1.4426950408889634f)  // 32^-0.5 * log2(e)
#define XROW 528                    // padded LDS row stride (264 u16)

// Native bf16 casts (RTNE) -> compiler fuses pairs into v_cvt_pk_bf16_f32.
__device__ __forceinline__ u16 f2bf(float f) {
    union { __bf16 h; u16 u; } x; x.h = (__bf16)f; return x.u;
}
__device__ __forceinline__ unsigned pk2(float a, float b) {
    union { struct { __bf16 lo, hi; } s; unsigned u; } x;
    x.s.lo = (__bf16)a; x.s.hi = (__bf16)b; return x.u;
}
__device__ __forceinline__ float bf2f(u16 h) {
    union { unsigned u; float f; } x; x.u = ((unsigned)h) << 16; return x.f;
}
// gelu = x * sigmoid(1.5957691*(x+0.044715x^3)); exp folded to native exp2
__device__ __forceinline__ float gelu_s(float x) {
    float u = 2.3022150048054216f * x * (1.f + 0.044715f * x * x); // *log2(e)
    float e = exp2f(-u);
    return x / (1.f + e);
}

// ---------------------------------------------------------------- prep ------
// ALL weights fragment-packed (frag (ng,ks): lane l holds
// W[k=32ks+8(l>>4)+e][n=16ng+(l&15)]). biasF: rel-pos bias, swapped C-frag,
// PRE-SCALED by log2(e) so softmax uses native exp2.
__global__ __launch_bounds__(256) void prep_k(
    const float* __restrict__ q_w, const float* __restrict__ kv_w,
    const float* __restrict__ p_w, const float* __restrict__ f1w,
    const float* __restrict__ f2w, const float* __restrict__ rel,
    u16* __restrict__ qp, u16* __restrict__ kvp, u16* __restrict__ pp,
    u16* __restrict__ f1p, u16* __restrict__ f2p, float* __restrict__ biasF)
{
    int t = blockIdx.x * 256 + threadIdx.x;
    if (t < 65536) {                                   // qp: 256x256
        int u = t;
        int e = u & 7, l = (u >> 3) & 63, ks = (u >> 9) & 7, ng = u >> 12;
        int k = ks * 32 + (l >> 4) * 8 + e;
        int n = ng * 16 + (l & 15);
        qp[u] = f2bf(q_w[k * 256 + n]);
    } else if (t < 196608) {                           // kvp: 256x512
        int u = t - 65536;
        int e = u & 7, l = (u >> 3) & 63, ks = (u >> 9) & 7, ng = u >> 12;
        int k = ks * 32 + (l >> 4) * 8 + e;
        int n = ng * 16 + (l & 15);
        kvp[u] = f2bf(kv_w[k * 512 + n]);
    } else if (t < 262144) {                           // pp: 256x256
        int u = t - 196608;
        int e = u & 7, l = (u >> 3) & 63, ks = (u >> 9) & 7, ng = u >> 12;
        int k = ks * 32 + (l >> 4) * 8 + e;
        int n = ng * 16 + (l & 15);
        pp[u] = f2bf(p_w[k * 256 + n]);
    } else if (t < 524288) {                           // f1p: 256x1024
        int u = t - 262144;
        int e = u & 7, l = (u >> 3) & 63, ks = (u >> 9) & 7, ng = u >> 12;
        int k = ks * 32 + (l >> 4) * 8 + e;
        int n = ng * 16 + (l & 15);
        f1p[u] = f2bf(f1w[k * 1024 + n]);
    } else if (t < 786432) {                           // f2p: 1024x256
        int u = t - 524288;
        int e = u & 7, l = (u >> 3) & 63, ks = (u >> 9) & 31, ng = u >> 14;
        int k = ks * 32 + (l >> 4) * 8 + e;
        int n = ng * 16 + (l & 15);
        f2p[u] = f2bf(f2w[k * 256 + n]);
    } else if (t < 819200) {                           // biasF 8*16*64*4 (*log2e)
        int u = t - 786432;
        int r = u & 3, l = (u >> 2) & 63, fr = (u >> 8) & 15, h = u >> 12;
        int fi = fr >> 2, fj = fr & 3;
        int m = fi * 16 + (l & 15);
        int n = fj * 16 + 4 * (l >> 4) + r;
        int idx = ((m >> 3) - (n >> 3) + 7) * 15 + ((m & 7) - (n & 7) + 7);
        biasF[u] = rel[idx * 8 + h] * 1.4426950408889634f;
    }
}

// Fast LN of one 256-col f32 row per 16-lane group (internal temps o0_/o1_).
#define LN_ROW16(SRCP, GG, BB, OUT0, OUT1)                                    \
    {                                                                         \
        float4 v0 = *(const float4*)(SRCP);                                   \
        float4 v1 = *(const float4*)(SRCP + 4);                               \
        float4 v2 = *(const float4*)(SRCP + 8);                               \
        float4 v3 = *(const float4*)(SRCP + 12);                              \
        float s = (v0.x + v0.y + v0.z + v0.w) + (v1.x + v1.y + v1.z + v1.w)   \
                + (v2.x + v2.y + v2.z + v2.w) + (v3.x + v3.y + v3.z + v3.w);  \
        float q = v0.x*v0.x + v0.y*v0.y + v0.z*v0.z + v0.w*v0.w               \
                + v1.x*v1.x + v1.y*v1.y + v1.z*v1.z + v1.w*v1.w               \
                + v2.x*v2.x + v2.y*v2.y + v2.z*v2.z + v2.w*v2.w               \
                + v3.x*v3.x + v3.y*v3.y + v3.z*v3.z + v3.w*v3.w;              \
        _Pragma("unroll")                                                     \
        for (int m_ = 1; m_ <= 8; m_ <<= 1) {                                 \
            s += __shfl_xor(s, m_, 64);                                       \
            q += __shfl_xor(q, m_, 64);                                       \
        }                                                                     \
        float mean = s * (1.0f / 256.0f);                                     \
        float rstd = rsqrtf(q * (1.0f / 256.0f) - mean * mean + 1e-5f);       \
        uint4 o0_, o1_;                                                       \
        o0_.x = pk2((v0.x-mean)*rstd*GG[0].x+BB[0].x, (v0.y-mean)*rstd*GG[0].y+BB[0].y); \
        o0_.y = pk2((v0.z-mean)*rstd*GG[0].z+BB[0].z, (v0.w-mean)*rstd*GG[0].w+BB[0].w); \
        o0_.z = pk2((v1.x-mean)*rstd*GG[1].x+BB[1].x, (v1.y-mean)*rstd*GG[1].y+BB[1].y); \
        o0_.w = pk2((v1.z-mean)*rstd*GG[1].z+BB[1].z, (v1.w-mean)*rstd*GG[1].w+BB[1].w); \
        o1_.x = pk2((v2.x-mean)*rstd*GG[2].x+BB[2].x, (v2.y-mean)*rstd*GG[2].y+BB[2].y); \
        o1_.y = pk2((v2.z-mean)*rstd*GG[2].z+BB[2].z, (v2.w-mean)*rstd*GG[2].w+BB[2].w); \
        o1_.z = pk2((v3.x-mean)*rstd*GG[3].x+BB[3].x, (v3.y-mean)*rstd*GG[3].y+BB[3].y); \
        o1_.w = pk2((v3.z-mean)*rstd*GG[3].z+BB[3].z, (v3.w-mean)*rstd*GG[3].w+BB[3].w); \
        OUT0 = o0_; OUT1 = o1_;                                               \
    }

// ----------------------------------------------------------- block mega -----
// ONE block = ONE window = the ENTIRE layer for its 64 rows. Phases as R18.
// NEW: weight-fragment double-buffering in GEMM256 and proj (L2 latency
// hidden under MFMA clusters); softmax on pre-scaled logits via exp2.
__global__ __launch_bounds__(512, 4) void block_mega(
    const float* __restrict__ x1, const float* __restrict__ x2,
    const float* __restrict__ n1g, const float* __restrict__ n1b,
    const bf16x8* __restrict__ qp, const bf16x8* __restrict__ kvp,
    const float* __restrict__ q_b, const float* __restrict__ kv_b,
    const float* __restrict__ biasF, const bf16x8* __restrict__ pp,
    const float* __restrict__ p_b,
    const float* __restrict__ n3g, const float* __restrict__ n3b,
    const bf16x8* __restrict__ f1p, const bf16x8* __restrict__ f2p,
    const float* __restrict__ f1b, const float* __restrict__ f2b,
    float* __restrict__ out)
{
    __shared__ __align__(16) char SMEM[74752];
    u16* Xl0  = (u16*)SMEM;            // phase 1-2
    u16* Xl1  = (u16*)(SMEM + 33792);  // phase 1-2
    u16* VtA  = (u16*)SMEM;            // phase 3 (after bar2)
    u16* Olds = (u16*)(SMEM + 40960);  // phase 3 (after bar2)
    u16* Xl4  = (u16*)SMEM;            // phase 4 (after bar3; over VtA)
    u16* Hl4  = (u16*)(SMEM + 40960);  // phase 4 (after bar4; over Olds)
    const int t = threadIdx.x, lane = t & 63, w = t >> 6;   // w = head
    const int g = lane >> 4, c = lane & 15;
    const int win = blockIdx.x;
    const int b_ = win >> 6, wh = (win >> 3) & 7, ww = win & 7;

    // ---- phase 1: LN1 of both streams; 4 rows/iter (16-lane groups) ----
    {
        const int ln_sub = lane >> 4, ln_c = lane & 15;
        float4 GG[4], BB[4];
        #pragma unroll
        for (int j = 0; j < 4; j++) {
            GG[j] = *(const float4*)(n1g + ln_c * 16 + j * 4);
            BB[j] = *(const float4*)(n1b + ln_c * 16 + j * 4);
        }
        #pragma unroll
        for (int it = 0; it < 4; it++) {
            int idx = w * 16 + it * 4 + ln_sub;    // 0..127
            int st = idx >> 6, n = idx & 63;
            const float* src = st ? x2 : x1;
            size_t srow = (size_t)b_ * 4096 + (wh * 8 + (n >> 3)) * 64 + ww * 8 + (n & 7);
            const float* p = src + srow * 256 + ln_c * 16;
            uint4 o0, o1;
            LN_ROW16(p, GG, BB, o0, o1)
            u16* dst = st ? Xl1 : Xl0;
            char* base = (char*)dst + n * XROW + ln_c * 32;
            *(uint4*)(base) = o0;
            *(uint4*)(base + 16) = o1;
        }
    }
    __syncthreads();   // bar1: Xl ready

    // ---- phase 2: own-head Q/K/V GEMMs (K=256), weight dbuf ----
    const int srcA = c + 16 * ((2 * g) & 3);
    const int srcB = srcA + 16;
    const bool nhi = (g >= 2);

#define GEMM256(acc, WPTR, NGBASE, XSRC)                                      \
    { _Pragma("unroll")                                                       \
      for (int i = 0; i < 4; i++) { acc[i][0] = (f32x4){0,0,0,0};             \
                                    acc[i][1] = (f32x4){0,0,0,0}; }           \
      bf16x8 wcur[2], wnxt[2];                                                \
      _Pragma("unroll")                                                       \
      for (int n = 0; n < 2; n++)                                             \
          wcur[n] = WPTR[(size_t)(((NGBASE) + n) * 8 + 0) * 64 + lane];       \
      _Pragma("unroll")                                                       \
      for (int ks = 0; ks < 8; ks++) {                                        \
          if (ks + 1 < 8) {                                                   \
              _Pragma("unroll")                                               \
              for (int n = 0; n < 2; n++)                                     \
                  wnxt[n] = WPTR[(size_t)(((NGBASE) + n) * 8 + ks + 1) * 64 + lane]; \
          }                                                                   \
          bf16x8 af[4];                                                       \
          _Pragma("unroll")                                                   \
          for (int i = 0; i < 4; i++)                                         \
              af[i] = *(const bf16x8*)((char*)XSRC + (i * 16 + c) * XROW      \
                                       + g * 16 + ks * 64);                   \
          __builtin_amdgcn_s_setprio(1);                                      \
          _Pragma("unroll")                                                   \
          for (int i = 0; i < 4; i++)                                         \
              _Pragma("unroll")                                               \
              for (int n = 0; n < 2; n++)                                     \
                  acc[i][n] = __builtin_amdgcn_mfma_f32_16x16x32_bf16(        \
                      wcur[n], af[i], acc[i][n], 0, 0, 0);                    \
          __builtin_amdgcn_s_setprio(0);                                      \
          _Pragma("unroll")                                                   \
          for (int n = 0; n < 2; n++) wcur[n] = wnxt[n];                      \
      } }

#define ADDBIAS(acc, BPTR, CBASE)                                             \
    { _Pragma("unroll")                                                       \
      for (int i = 0; i < 4; i++)                                             \
          _Pragma("unroll")                                                   \
          for (int n = 0; n < 2; n++) {                                       \
              float4 b4 = *(const float4*)((BPTR) + (CBASE) + n * 16 + 4 * g);\
              acc[i][n][0] += b4.x; acc[i][n][1] += b4.y;                     \
              acc[i][n][2] += b4.z; acc[i][n][3] += b4.w;                     \
          } }

#define REPACK(acc, frag)                                                     \
    { unsigned w0_[4][2], w1_[4][2];                                          \
      _Pragma("unroll")                                                       \
      for (int i = 0; i < 4; i++)                                             \
          _Pragma("unroll")                                                   \
          for (int n = 0; n < 2; n++) {                                       \
              w0_[i][n] = pk2(acc[i][n][0], acc[i][n][1]);                    \
              w1_[i][n] = pk2(acc[i][n][2], acc[i][n][3]);                    \
          }                                                                   \
      _Pragma("unroll")                                                       \
      for (int i = 0; i < 4; i++) {                                           \
          unsigned x0a = __shfl(w0_[i][0], srcA), x0b = __shfl(w0_[i][1], srcA);\
          unsigned y0a = __shfl(w1_[i][0], srcA), y0b = __shfl(w1_[i][1], srcA);\
          unsigned x1a = __shfl(w0_[i][0], srcB), x1b = __shfl(w0_[i][1], srcB);\
          unsigned y1a = __shfl(w1_[i][0], srcB), y1b = __shfl(w1_[i][1], srcB);\
          union { uint4 u; bf16x8 v; } cv;                                    \
          cv.u.x = nhi ? x0b : x0a;                                           \
          cv.u.y = nhi ? y0b : y0a;                                           \
          cv.u.z = nhi ? x1b : x1a;                                           \
          cv.u.w = nhi ? y1b : y1a;                                           \
          frag[i] = cv.v;                                                     \
      } }

    bf16x8 qf[4], kf[4];
    f32x4 av[4][2];
    {
        f32x4 acc[4][2];
        GEMM256(acc, kvp, 2 * w, Xl1)            // K
        ADDBIAS(acc, kv_b, w * 32)
        REPACK(acc, kf)
        GEMM256(acc, qp, 2 * w, Xl0)             // Q
        ADDBIAS(acc, q_b, w * 32)
        REPACK(acc, qf)
        GEMM256(av, kvp, 16 + 2 * w, Xl1)        // V
        ADDBIAS(av, kv_b, 256 + w * 32)
    }
    __syncthreads();   // bar2: Xl reads done -> safe to write VtA/Olds

    // V scatter: Vt[d][key], padded 80
    u16* vt = VtA + w * 32 * 80;
    #pragma unroll
    for (int i = 0; i < 4; i++)
        #pragma unroll
        for (int n = 0; n < 2; n++)
            #pragma unroll
            for (int r = 0; r < 4; r++)
                vt[(n * 16 + 4 * g + r) * 80 + i * 16 + c] = f2bf(av[i][n][r]);

    // QK^T; swapped mfma(K, Q)
    f32x4 s[4][4];
    #pragma unroll
    for (int i = 0; i < 4; i++)
        #pragma unroll
        for (int j = 0; j < 4; j++) {
            s[i][j] = (f32x4){0.f, 0.f, 0.f, 0.f};
            s[i][j] = __builtin_amdgcn_mfma_f32_16x16x32_bf16(kf[j], qf[i], s[i][j], 0, 0, 0);
        }

    // scale*log2e + pre-scaled rel-pos bias (logits in log2 domain)
    #pragma unroll
    for (int i = 0; i < 4; i++)
        #pragma unroll
        for (int j = 0; j < 4; j++) {
            f32x4 bf4 = *(const f32x4*)(biasF + ((size_t)(w * 16 + i * 4 + j) * 64 + lane) * 4);
            #pragma unroll
            for (int r = 0; r < 4; r++) s[i][j][r] = s[i][j][r] * SCALE2 + bf4[r];
        }

    // softmax over keys (exp2 on log2-domain logits)
    #pragma unroll
    for (int i = 0; i < 4; i++) {
        float mx = -1e30f;
        #pragma unroll
        for (int j = 0; j < 4; j++)
            #pragma unroll
            for (int r = 0; r < 4; r++) mx = fmaxf(mx, s[i][j][r]);
        mx = fmaxf(mx, __shfl_xor(mx, 16, 64));
        mx = fmaxf(mx, __shfl_xor(mx, 32, 64));
        float sum = 0.f;
        #pragma unroll
        for (int j = 0; j < 4; j++)
            #pragma unroll
            for (int r = 0; r < 4; r++) {
                float e = exp2f(s[i][j][r] - mx);
                s[i][j][r] = e; sum += e;
            }
        sum += __shfl_xor(sum, 16, 64);
        sum += __shfl_xor(sum, 32, 64);
        float inv = 1.f / sum;
        #pragma unroll
        for (int j = 0; j < 4; j++)
            #pragma unroll
            for (int r = 0; r < 4; r++) s[i][j][r] *= inv;
    }

    // P repack + PV
    unsigned pw0[4][4], pw1[4][4];
    #pragma unroll
    for (int i = 0; i < 4; i++)
        #pragma unroll
        for (int j = 0; j < 4; j++) {
            pw0[i][j] = pk2(s[i][j][0], s[i][j][1]);
            pw1[i][j] = pk2(s[i][j][2], s[i][j][3]);
        }
    f32x4 o[4][2];
    #pragma unroll
    for (int i = 0; i < 4; i++) { o[i][0] = (f32x4){0,0,0,0}; o[i][1] = (f32x4){0,0,0,0}; }
    #pragma unroll
    for (int ks = 0; ks < 2; ks++) {
        bf16x8 pa[4], vb[2];
        #pragma unroll
        for (int i = 0; i < 4; i++) {
            unsigned a0 = __shfl(pw0[i][2 * ks], srcA), b0 = __shfl(pw0[i][2 * ks + 1], srcA);
            unsigned a1 = __shfl(pw1[i][2 * ks], srcA), b1 = __shfl(pw1[i][2 * ks + 1], srcA);
            unsigned a2 = __shfl(pw0[i][2 * ks], srcB), b2 = __shfl(pw0[i][2 * ks + 1], srcB);
            unsigned a3 = __shfl(pw1[i][2 * ks], srcB), b3 = __shfl(pw1[i][2 * ks + 1], srcB);
            union { uint4 u; bf16x8 v; } cv;
            cv.u.x = nhi ? b0 : a0;
            cv.u.y = nhi ? b1 : a1;
            cv.u.z = nhi ? b2 : a2;
            cv.u.w = nhi ? b3 : a3;
            pa[i] = cv.v;
        }
        #pragma unroll
        for (int j = 0; j < 2; j++) {
            int d = j * 16 + c;
            vb[j] = *(const bf16x8*)(vt + d * 80 + ks * 32 + 8 * g);
        }
        #pragma unroll
        for (int i = 0; i < 4; i++)
            #pragma unroll
            for (int j = 0; j < 2; j++)
                o[i][j] = __builtin_amdgcn_mfma_f32_16x16x32_bf16(vb[j], pa[i], o[i][j], 0, 0, 0);
    }

    // O -> Olds
    #pragma unroll
    for (int i = 0; i < 4; i++) {
        int row = i * 16 + c;
        #pragma unroll
        for (int j = 0; j < 2; j++) {
            uint2 pk = { pk2(o[i][j][0], o[i][j][1]), pk2(o[i][j][2], o[i][j][3]) };
            *(uint2*)((char*)Olds + row * XROW + w * 64 + j * 32 + g * 8) = pk;
        }
    }
    __syncthreads();   // bar3: all heads' O in Olds; all Vt reads done

    // proj: wave w -> out cols w*32..+32, K=256 from Olds (weight dbuf)
    f32x4 ap[4][2];
    #pragma unroll
    for (int i = 0; i < 4; i++) { ap[i][0] = (f32x4){0,0,0,0}; ap[i][1] = (f32x4){0,0,0,0}; }
    {
        bf16x8 wcur[2], wnxt[2];
        #pragma unroll
        for (int n = 0; n < 2; n++)
            wcur[n] = pp[(size_t)((w * 2 + n) * 8 + 0) * 64 + lane];
        #pragma unroll
        for (int ks = 0; ks < 8; ks++) {
            if (ks + 1 < 8) {
                #pragma unroll
                for (int n = 0; n < 2; n++)
                    wnxt[n] = pp[(size_t)((w * 2 + n) * 8 + ks + 1) * 64 + lane];
            }
            bf16x8 ah[4];
            #pragma unroll
            for (int i = 0; i < 4; i++)
                ah[i] = *(const bf16x8*)((char*)Olds + (i * 16 + c) * XROW
                                         + g * 16 + ks * 64);
            __builtin_amdgcn_s_setprio(1);
            #pragma unroll
            for (int i = 0; i < 4; i++)
                #pragma unroll
                for (int n = 0; n < 2; n++)
                    ap[i][n] = __builtin_amdgcn_mfma_f32_16x16x32_bf16(
                        wcur[n], ah[i], ap[i][n], 0, 0, 0);
            __builtin_amdgcn_s_setprio(0);
            #pragma unroll
            for (int n = 0; n < 2; n++) wcur[n] = wnxt[n];
        }
    }

    // x = proj + p_b + f32 residual -> bf16 packed regs, and write Xl4
    uint2 xs[4][2];
    #pragma unroll
    for (int i = 0; i < 4; i++) {
        int n = i * 16 + c;
        size_t nrow = (size_t)b_ * 4096 + (wh * 8 + (n >> 3)) * 64 + ww * 8 + (n & 7);
        #pragma unroll
        for (int j = 0; j < 2; j++) {
            int col = w * 32 + j * 16 + 4 * g;
            float4 b4 = *(const float4*)(p_b + col);
            float4 r4 = *(const float4*)(x1 + nrow * 256 + col);
            uint2 pk = { pk2(ap[i][j][0] + b4.x + r4.x, ap[i][j][1] + b4.y + r4.y),
                         pk2(ap[i][j][2] + b4.z + r4.z, ap[i][j][3] + b4.w + r4.w) };
            xs[i][j] = pk;
            *(uint2*)((char*)Xl4 + (i * 16 + c) * XROW + w * 64 + j * 32 + g * 8) = pk;
        }
    }
    __syncthreads();   // bar4: full x in Xl4; all Olds reads done

    // ---- phase 4a: LN3 in place on Xl4 (16-lane groups, 2 iters) ----
    {
        const int ln_sub = lane >> 4, ln_c = lane & 15;
        float4 G3[4], B3[4];
        #pragma unroll
        for (int j = 0; j < 4; j++) {
            G3[j] = *(const float4*)(n3g + ln_c * 16 + j * 4);
            B3[j] = *(const float4*)(n3b + ln_c * 16 + j * 4);
        }
        const float* G = (const float*)G3;
        const float* B = (const float*)B3;
        #pragma unroll
        for (int it = 0; it < 2; it++) {
            int row = w * 8 + it * 4 + ln_sub;
            char* base = (char*)Xl4 + row * XROW + ln_c * 32;
            uint4 rv = *(const uint4*)(base);
            uint4 rw = *(const uint4*)(base + 16);
            float v[16];
            v[0] = bf2f((u16)rv.x);  v[1] = bf2f((u16)(rv.x >> 16));
            v[2] = bf2f((u16)rv.y);  v[3] = bf2f((u16)(rv.y >> 16));
            v[4] = bf2f((u16)rv.z);  v[5] = bf2f((u16)(rv.z >> 16));
            v[6] = bf2f((u16)rv.w);  v[7] = bf2f((u16)(rv.w >> 16));
            v[8] = bf2f((u16)rw.x);  v[9] = bf2f((u16)(rw.x >> 16));
            v[10] = bf2f((u16)rw.y); v[11] = bf2f((u16)(rw.y >> 16));
            v[12] = bf2f((u16)rw.z); v[13] = bf2f((u16)(rw.z >> 16));
            v[14] = bf2f((u16)rw.w); v[15] = bf2f((u16)(rw.w >> 16));
            float sm = 0.f, qm = 0.f;
            #pragma unroll
            for (int e = 0; e < 16; e++) { sm += v[e]; qm += v[e] * v[e]; }
            #pragma unroll
            for (int m_ = 1; m_ <= 8; m_ <<= 1) {
                sm += __shfl_xor(sm, m_, 64);
                qm += __shfl_xor(qm, m_, 64);
            }
            float mean = sm * (1.0f / 256.0f);
            float rstd = rsqrtf(qm * (1.0f / 256.0f) - mean * mean + 1e-5f);
            uint4 o0, o1;
            o0.x = pk2((v[0]-mean)*rstd*G[0]+B[0],  (v[1]-mean)*rstd*G[1]+B[1]);
            o0.y = pk2((v[2]-mean)*rstd*G[2]+B[2],  (v[3]-mean)*rstd*G[3]+B[3]);
            o0.z = pk2((v[4]-mean)*rstd*G[4]+B[4],  (v[5]-mean)*rstd*G[5]+B[5]);
            o0.w = pk2((v[6]-mean)*rstd*G[6]+B[6],  (v[7]-mean)*rstd*G[7]+B[7]);
            o1.x = pk2((v[8]-mean)*rstd*G[8]+B[8],  (v[9]-mean)*rstd*G[9]+B[9]);
            o1.y = pk2((v[10]-mean)*rstd*G[10]+B[10],(v[11]-mean)*rstd*G[11]+B[11]);
            o1.z = pk2((v[12]-mean)*rstd*G[12]+B[12],(v[13]-mean)*rstd*G[13]+B[13]);
            o1.w = pk2((v[14]-mean)*rstd*G[14]+B[14],(v[15]-mean)*rstd*G[15]+B[15]);
            *(uint4*)(base) = o0;
            *(uint4*)(base + 16) = o1;
        }
    }
    __syncthreads();   // bar5: LN3(x) in Xl4

    // ---- phase 4b: MLP (fc1+gelu -> Hl4; fc2 accumulate) ----
    f32x4 acc2[4][2];
    #pragma unroll
    for (int i = 0; i < 4; i++) { acc2[i][0] = (f32x4){0,0,0,0}; acc2[i][1] = (f32x4){0,0,0,0}; }

    #pragma unroll
    for (int hc = 0; hc < 4; hc++) {
        f32x4 acc1[4][2];
        #pragma unroll
        for (int i = 0; i < 4; i++) { acc1[i][0] = (f32x4){0,0,0,0}; acc1[i][1] = (f32x4){0,0,0,0}; }

        const bf16x8* f1base = f1p + (size_t)((hc * 16 + w * 2) * 8) * 64 + lane;
        bf16x8 wA[2], wB[2];
        #pragma unroll
        for (int n = 0; n < 2; n++) wA[n] = f1base[(n * 8 + 0) * 64];

#define FC1_STEP(WREG, ks_)                                                   \
        {                                                                     \
            bf16x8 af[4];                                                     \
            _Pragma("unroll")                                                 \
            for (int i = 0; i < 4; i++)                                       \
                af[i] = *(const bf16x8*)((char*)Xl4 + (i * 16 + c) * XROW     \
                                         + g * 16 + (ks_) * 64);             \
            __builtin_amdgcn_s_setprio(1);                                    \
            _Pragma("unroll")                                                 \
            for (int i = 0; i < 4; i++)                                       \
                _Pragma("unroll")                                             \
                for (int n = 0; n < 2; n++)                                   \
                    acc1[i][n] = __builtin_amdgcn_mfma_f32_16x16x32_bf16(     \
                        WREG[n], af[i], acc1[i][n], 0, 0, 0);                 \
            __builtin_amdgcn_s_setprio(0);                                    \
        }

        #pragma unroll
        for (int ks = 0; ks < 8; ks += 2) {
            #pragma unroll
            for (int n = 0; n < 2; n++) wB[n] = f1base[(n * 8 + ks + 1) * 64];
            FC1_STEP(wA, ks)
            if (ks + 2 < 8) {
                #pragma unroll
                for (int n = 0; n < 2; n++) wA[n] = f1base[(n * 8 + ks + 2) * 64];
            }
            FC1_STEP(wB, ks + 1)
        }
#undef FC1_STEP

        #pragma unroll
        for (int i = 0; i < 4; i++) {
            int row = i * 16 + c;
            #pragma unroll
            for (int n = 0; n < 2; n++) {
                float4 b4 = *(const float4*)(f1b + hc * 256 + w * 32 + n * 16 + 4 * g);
                float h0 = gelu_s(acc1[i][n][0] + b4.x);
                float h1 = gelu_s(acc1[i][n][1] + b4.y);
                float h2 = gelu_s(acc1[i][n][2] + b4.z);
                float h3 = gelu_s(acc1[i][n][3] + b4.w);
                uint2 pk = { pk2(h0, h1), pk2(h2, h3) };
                *(uint2*)((char*)Hl4 + row * XROW + w * 64 + n * 32 + g * 8) = pk;
            }
        }
        __syncthreads();

        const bf16x8* f2base = f2p + (size_t)((w * 2) * 32 + hc * 8) * 64 + lane;
        #pragma unroll
        for (int n = 0; n < 2; n++) wA[n] = f2base[(n * 32 + 0) * 64];

#define FC2_STEP(WREG, ks_)                                                   \
        {                                                                     \
            bf16x8 ah[4];                                                     \
            _Pragma("unroll")                                                 \
            for (int i = 0; i < 4; i++)                                       \
                ah[i] = *(const bf16x8*)((char*)Hl4 + (i * 16 + c) * XROW     \
                                         + g * 16 + (ks_) * 64);             \
            __builtin_amdgcn_s_setprio(1);                                    \
            _Pragma("unroll")                                                 \
            for (int i = 0; i < 4; i++)                                       \
                _Pragma("unroll")                                             \
                for (int n = 0; n < 2; n++)                                   \
                    acc2[i][n] = __builtin_amdgcn_mfma_f32_16x16x32_bf16(     \
                        WREG[n], ah[i], acc2[i][n], 0, 0, 0);                 \
            __builtin_amdgcn_s_setprio(0);                                    \
        }

        #pragma unroll
        for (int ks = 0; ks < 8; ks += 2) {
            #pragma unroll
            for (int n = 0; n < 2; n++) wB[n] = f2base[(n * 32 + ks + 1) * 64];
            FC2_STEP(wA, ks)
            if (ks + 2 < 8) {
                #pragma unroll
                for (int n = 0; n < 2; n++) wA[n] = f2base[(n * 32 + ks + 2) * 64];
            }
            FC2_STEP(wB, ks + 1)
        }
#undef FC2_STEP
        __syncthreads();
    }

    // ---- epilogue: out = acc2 + f2b + x (bf16 regs), f32, window rows ----
    #pragma unroll
    for (int i = 0; i < 4; i++) {
        int n = i * 16 + c;
        size_t nrow = (size_t)b_ * 4096 + (wh * 8 + (n >> 3)) * 64 + ww * 8 + (n & 7);
        #pragma unroll
        for (int j = 0; j < 2; j++) {
            int col = w * 32 + j * 16 + 4 * g;
            float4 b4 = *(const float4*)(f2b + col);
            uint2 rr = xs[i][j];
            float4 ov = { acc2[i][j][0] + b4.x + bf2f((u16)rr.x),
                          acc2[i][j][1] + b4.y + bf2f((u16)(rr.x >> 16)),
                          acc2[i][j][2] + b4.z + bf2f((u16)rr.y),
                          acc2[i][j][3] + b4.w + bf2f((u16)(rr.y >> 16)) };
            *(float4*)(out + nrow * 256 + col) = ov;
        }
    }
#undef GEMM256
#undef ADDBIAS
#undef REPACK
}

// -------------------------------------------------------------- launch ------
// Workspace (peak ~2.1 MB): weights only.
extern "C" void kernel_launch(void* const* d_in, const int* in_sizes, int n_in,
                              void* d_out, int out_size, void* d_ws, size_t ws_size,
                              hipStream_t stream)
{
    const float* x1  = (const float*)d_in[0];
    const float* x2  = (const float*)d_in[1];
    const float* n1g = (const float*)d_in[2];
    const float* n1b = (const float*)d_in[3];
    const float* q_w = (const float*)d_in[4];
    const float* q_b = (const float*)d_in[5];
    const float* kv_w= (const float*)d_in[6];
    const float* kv_b= (const float*)d_in[7];
    const float* p_w = (const float*)d_in[8];
    const float* p_b = (const float*)d_in[9];
    const float* rel = (const float*)d_in[10];
    const float* n3g = (const float*)d_in[11];
    const float* n3b = (const float*)d_in[12];
    const float* f1w = (const float*)d_in[13];
    const float* f1b = (const float*)d_in[14];
    const float* f2w = (const float*)d_in[15];
    const float* f2b = (const float*)d_in[16];

    char* ws = (char*)d_ws;
    u16*   qp    = (u16*)(ws + 0);
    u16*   kvp   = (u16*)(ws + 131072);
    u16*   pp    = (u16*)(ws + 393216);
    u16*   f1p   = (u16*)(ws + 524288);
    u16*   f2p   = (u16*)(ws + 1048576);
    float* biasF = (float*)(ws + 1572864);

    float* out = (float*)d_out;

    prep_k<<<3200, 256, 0, stream>>>(q_w, kv_w, p_w, f1w, f2w, rel,
                                     qp, kvp, pp, f1p, f2p, biasF);
    block_mega<<<1024, 512, 0, stream>>>(x1, x2, n1g, n1b, (const bf16x8*)qp,
                                         (const bf16x8*)kvp, q_b, kv_b, biasF,
                                         (const bf16x8*)pp, p_b, n3g, n3b,
                                         (const bf16x8*)f1p, (const bf16x8*)f2p,
                                         f1b, f2b, out);
}